// Round 2
// baseline (420.864 us; speedup 1.0000x reference)
//
#include <hip/hip_runtime.h>
#include <hip/hip_bf16.h>

#define NROW 50000
#define NCOL 50000
#define DDIM 128
#define CAP  32   // slots per destination row

typedef __bf16 bf16_t;
typedef __bf16 bf16x2 __attribute__((ext_vector_type(2)));
typedef __bf16 bf16x8 __attribute__((ext_vector_type(8)));
typedef float  f32x4  __attribute__((ext_vector_type(4)));

__device__ __forceinline__ float lrelu(float v) { return v >= 0.f ? v : 0.01f * v; }

// adaptive scalar load: f ? f32 : bf16
__device__ __forceinline__ float ldf(const void* p, size_t i, bool f) {
    return f ? ((const float*)p)[i] : (float)((const bf16_t*)p)[i];
}

// ---------------- dtype detector (proven in rounds 4/5 — unchanged) --------
struct TensorTab { const void* p[18]; int n[18]; };

__global__ __launch_bounds__(256) void detect_dtypes(TensorTab T, int* flags)
{
    __shared__ int vb, vf;
    const int tid = threadIdx.x;
    for (int t = 0; t < 18; ++t) {
        if (tid == 0) { vb = 0; vf = 0; }
        __syncthreads();
        const int n = T.n[t];
        const bool isFloatArr = (t != 2 && t != 3 && t != 5 && t != 6) && n >= 2;
        if (isFloatArr) {
            int nw = n / 2;
            int wi = (int)(((long long)tid * nw) >> 8);
            unsigned w = ((const unsigned*)T.p[t])[wi];
            unsigned low = w & 0xffffu;
            if (low) {
                int e = (int)((low >> 7) & 0xffu);
                if (e >= 90 && e <= 141) atomicAdd(&vb, 1);
                else                     atomicAdd(&vf, 1);
            }
        }
        __syncthreads();
        if (tid == 0) flags[t] = (isFloatArr && vf > vb) ? 1 : 0; // 1 = f32
        __syncthreads();
    }
}

// ---------------- weight prep: rearrange 4 DxD matrices into MFMA B-frag
// order (slot sIdx -> 8 contiguous bf16). One-time, tiny.
struct WPtrs { const void* W[4]; int fi[4]; };

__global__ __launch_bounds__(256) void prep_weights(WPtrs P, const int* flags,
                                                    __bf16* outp)
{
    int slot = blockIdx.x * 256 + threadIdx.x;     // 4 * 2048
    if (slot >= 4 * 2048) return;
    int m = slot >> 11, sIdx = slot & 2047;
    bool f = flags[P.fi[m]] != 0;
    int l = sIdx & 63, combo = sIdx >> 6;
    int ct = combo >> 2, kk = combo & 3;
    int col  = ct * 16 + (l & 15);
    int krow = kk * 32 + (l >> 4) * 8;
    bf16x8 v;
#pragma unroll
    for (int j = 0; j < 8; ++j)
        v[j] = (__bf16)ldf(P.W[m], (size_t)(krow + j) * DDIM + col, f);
    ((bf16x8*)outp)[slot] = v;
}

// ---------------- bucket fill: one thread per edge --------------------------
__global__ __launch_bounds__(256) void fill_slots(
    const int* __restrict__ dst, int nE, int* __restrict__ counts,
    int* __restrict__ slots, int* __restrict__ ovCount, int* __restrict__ ovList,
    const void* __restrict__ feat, const int* __restrict__ srcArr,
    const void* __restrict__ wArr, float* __restrict__ agg,
    const int* __restrict__ flags, int fiFeat, int fiW)
{
    int e = blockIdx.x * 256 + threadIdx.x;
    if (e >= nE) return;
    int d = dst[e];
    int pos = atomicAdd(&counts[d], 1);
    if (pos < CAP) {
        slots[(size_t)d * CAP + pos] = e;
    } else if (ovList) {
        int k = atomicAdd(ovCount, 1);   // capacity == nE, cannot overflow
        ovList[k] = e;
    } else {  // legacy fallback: exact direct atomic accumulation
        const bool fF = (fiFeat == -1) ? true : (flags[fiFeat] != 0);
        const bool fW = (fiW   == -1) ? true : (flags[fiW]   != 0);
        int s = srcArr[e];
        float wf = ldf(wArr, e, fW);
        for (int c = 0; c < DDIM; ++c)
            unsafeAtomicAdd(&agg[(size_t)d * DDIM + c],
                            ldf(feat, (size_t)s * DDIM + c, fF) * wf);
    }
}

// ---------------- overflow apply: grid-stride over ovList -------------------
__global__ __launch_bounds__(256) void scatter_overflow(
    const void* __restrict__ feat, const int* __restrict__ srcArr,
    const int* __restrict__ dstArr, const void* __restrict__ wArr,
    const int* __restrict__ ovList, const int* __restrict__ ovCount,
    float* __restrict__ agg, const int* __restrict__ flags, int fiFeat, int fiW)
{
    const bool fF = (fiFeat == -1) ? true : (flags[fiFeat] != 0);
    const bool fW = (fiW   == -1) ? true : (flags[fiW]   != 0);
    const int nOv = *ovCount;
    const int stride = gridDim.x * 256;
    for (int g = blockIdx.x * 256 + threadIdx.x; (g >> 5) < nOv; g += stride) {
        int idx = g >> 5;                 // 32 threads per edge
        int e = ovList[idx];
        int c = (g & 31) << 2;            // 4 floats per thread
        int s = srcArr[e], d = dstArr[e];
        float wf = ldf(wArr, e, fW);
        size_t base = (size_t)s * DDIM + c;
        float* ap = agg + (size_t)d * DDIM + c;
        unsafeAtomicAdd(ap + 0, ldf(feat, base + 0, fF) * wf);
        unsafeAtomicAdd(ap + 1, ldf(feat, base + 1, fF) * wf);
        unsafeAtomicAdd(ap + 2, ldf(feat, base + 2, fF) * wf);
        unsafeAtomicAdd(ap + 3, ldf(feat, base + 3, fF) * wf);
    }
}

// ---------------- segment sum: one wave per destination row ----------------
// Deep-pipelined gather: lanes 0..31 prefetch ALL slot/src/w of this row in
// three lane-parallel loads; main loop keeps 8 independent 512B row-gathers
// in flight per wave (4 accumulators), remainder 4/1.
template <bool ZINIT>
__global__ __launch_bounds__(256) void segsum(
    const void* __restrict__ feat, const int* __restrict__ srcArr,
    const void* __restrict__ wArr, const int* __restrict__ counts,
    const int* __restrict__ slots, float* __restrict__ agg, int nRows,
    const int* __restrict__ flags, int fiFeat, int fiW)
{
    const bool fF = (fiFeat == -1) ? true : (flags[fiFeat] != 0);
    const bool fW = (fiW   == -1) ? true : (flags[fiW]   != 0);
    int row = blockIdx.x * 4 + (threadIdx.x >> 6);
    if (row >= nRows) return;
    int lane = threadIdx.x & 63;

    int cnt = counts[row]; if (cnt > CAP) cnt = CAP;

    // lane-parallel index/weight prefetch (lanes 0..cnt-1; cnt <= 32)
    int sr = 0; float wv = 0.f;
    if (lane < cnt) {
        int e = slots[(size_t)row * CAP + lane];
        sr = srcArr[e];
        wv = ldf(wArr, e, fW);
    }

    float2* ap = (float2*)(agg + (size_t)row * DDIM) + lane;
    float2 acc0 = {0.f, 0.f}, acc1 = {0.f, 0.f};
    float2 acc2 = {0.f, 0.f}, acc3 = {0.f, 0.f};
    if (!ZINIT) acc0 = *ap;   // overflow contributions already accumulated

    if (fF) {
        const float2* fb = (const float2*)feat;
        int i = 0;
        for (; i + 8 <= cnt; i += 8) {
            int   a0 = __shfl(sr, i),     a1 = __shfl(sr, i + 1);
            int   a2 = __shfl(sr, i + 2), a3 = __shfl(sr, i + 3);
            int   a4 = __shfl(sr, i + 4), a5 = __shfl(sr, i + 5);
            int   a6 = __shfl(sr, i + 6), a7 = __shfl(sr, i + 7);
            float w0 = __shfl(wv, i),     w1 = __shfl(wv, i + 1);
            float w2 = __shfl(wv, i + 2), w3 = __shfl(wv, i + 3);
            float w4 = __shfl(wv, i + 4), w5 = __shfl(wv, i + 5);
            float w6 = __shfl(wv, i + 6), w7 = __shfl(wv, i + 7);
            float2 v0 = fb[(size_t)a0 * 64 + lane];
            float2 v1 = fb[(size_t)a1 * 64 + lane];
            float2 v2 = fb[(size_t)a2 * 64 + lane];
            float2 v3 = fb[(size_t)a3 * 64 + lane];
            float2 v4 = fb[(size_t)a4 * 64 + lane];
            float2 v5 = fb[(size_t)a5 * 64 + lane];
            float2 v6 = fb[(size_t)a6 * 64 + lane];
            float2 v7 = fb[(size_t)a7 * 64 + lane];
            acc0.x += v0.x * w0; acc0.y += v0.y * w0;
            acc1.x += v1.x * w1; acc1.y += v1.y * w1;
            acc2.x += v2.x * w2; acc2.y += v2.y * w2;
            acc3.x += v3.x * w3; acc3.y += v3.y * w3;
            acc0.x += v4.x * w4; acc0.y += v4.y * w4;
            acc1.x += v5.x * w5; acc1.y += v5.y * w5;
            acc2.x += v6.x * w6; acc2.y += v6.y * w6;
            acc3.x += v7.x * w7; acc3.y += v7.y * w7;
        }
        if (i + 4 <= cnt) {
            int   a0 = __shfl(sr, i),     a1 = __shfl(sr, i + 1);
            int   a2 = __shfl(sr, i + 2), a3 = __shfl(sr, i + 3);
            float w0 = __shfl(wv, i),     w1 = __shfl(wv, i + 1);
            float w2 = __shfl(wv, i + 2), w3 = __shfl(wv, i + 3);
            float2 v0 = fb[(size_t)a0 * 64 + lane];
            float2 v1 = fb[(size_t)a1 * 64 + lane];
            float2 v2 = fb[(size_t)a2 * 64 + lane];
            float2 v3 = fb[(size_t)a3 * 64 + lane];
            acc0.x += v0.x * w0; acc0.y += v0.y * w0;
            acc1.x += v1.x * w1; acc1.y += v1.y * w1;
            acc2.x += v2.x * w2; acc2.y += v2.y * w2;
            acc3.x += v3.x * w3; acc3.y += v3.y * w3;
            i += 4;
        }
        for (; i < cnt; ++i) {
            int   a0 = __shfl(sr, i);
            float w0 = __shfl(wv, i);
            float2 v0 = fb[(size_t)a0 * 64 + lane];
            acc0.x += v0.x * w0; acc0.y += v0.y * w0;
        }
    } else {
        const bf16x2* fb = (const bf16x2*)feat;
        int i = 0;
        for (; i + 8 <= cnt; i += 8) {
            int   a0 = __shfl(sr, i),     a1 = __shfl(sr, i + 1);
            int   a2 = __shfl(sr, i + 2), a3 = __shfl(sr, i + 3);
            int   a4 = __shfl(sr, i + 4), a5 = __shfl(sr, i + 5);
            int   a6 = __shfl(sr, i + 6), a7 = __shfl(sr, i + 7);
            float w0 = __shfl(wv, i),     w1 = __shfl(wv, i + 1);
            float w2 = __shfl(wv, i + 2), w3 = __shfl(wv, i + 3);
            float w4 = __shfl(wv, i + 4), w5 = __shfl(wv, i + 5);
            float w6 = __shfl(wv, i + 6), w7 = __shfl(wv, i + 7);
            bf16x2 v0 = fb[(size_t)a0 * 64 + lane];
            bf16x2 v1 = fb[(size_t)a1 * 64 + lane];
            bf16x2 v2 = fb[(size_t)a2 * 64 + lane];
            bf16x2 v3 = fb[(size_t)a3 * 64 + lane];
            bf16x2 v4 = fb[(size_t)a4 * 64 + lane];
            bf16x2 v5 = fb[(size_t)a5 * 64 + lane];
            bf16x2 v6 = fb[(size_t)a6 * 64 + lane];
            bf16x2 v7 = fb[(size_t)a7 * 64 + lane];
            acc0.x += (float)v0[0] * w0; acc0.y += (float)v0[1] * w0;
            acc1.x += (float)v1[0] * w1; acc1.y += (float)v1[1] * w1;
            acc2.x += (float)v2[0] * w2; acc2.y += (float)v2[1] * w2;
            acc3.x += (float)v3[0] * w3; acc3.y += (float)v3[1] * w3;
            acc0.x += (float)v4[0] * w4; acc0.y += (float)v4[1] * w4;
            acc1.x += (float)v5[0] * w5; acc1.y += (float)v5[1] * w5;
            acc2.x += (float)v6[0] * w6; acc2.y += (float)v6[1] * w6;
            acc3.x += (float)v7[0] * w7; acc3.y += (float)v7[1] * w7;
        }
        if (i + 4 <= cnt) {
            int   a0 = __shfl(sr, i),     a1 = __shfl(sr, i + 1);
            int   a2 = __shfl(sr, i + 2), a3 = __shfl(sr, i + 3);
            float w0 = __shfl(wv, i),     w1 = __shfl(wv, i + 1);
            float w2 = __shfl(wv, i + 2), w3 = __shfl(wv, i + 3);
            bf16x2 v0 = fb[(size_t)a0 * 64 + lane];
            bf16x2 v1 = fb[(size_t)a1 * 64 + lane];
            bf16x2 v2 = fb[(size_t)a2 * 64 + lane];
            bf16x2 v3 = fb[(size_t)a3 * 64 + lane];
            acc0.x += (float)v0[0] * w0; acc0.y += (float)v0[1] * w0;
            acc1.x += (float)v1[0] * w1; acc1.y += (float)v1[1] * w1;
            acc2.x += (float)v2[0] * w2; acc2.y += (float)v2[1] * w2;
            acc3.x += (float)v3[0] * w3; acc3.y += (float)v3[1] * w3;
            i += 4;
        }
        for (; i < cnt; ++i) {
            int   a0 = __shfl(sr, i);
            float w0 = __shfl(wv, i);
            bf16x2 v0 = fb[(size_t)a0 * 64 + lane];
            acc0.x += (float)v0[0] * w0; acc0.y += (float)v0[1] * w0;
        }
    }
    acc0.x += acc1.x; acc0.y += acc1.y;
    acc2.x += acc3.x; acc2.y += acc3.y;
    acc0.x += acc2.x; acc0.y += acc2.y;
    *ap = acc0;
}

// ---------------- legacy atomic scatter (ws-too-small fallback) -------------
__global__ __launch_bounds__(256) void scatter_any(
    const void* __restrict__ feat, const int* __restrict__ src,
    const int* __restrict__ dst, const void* __restrict__ w,
    float* __restrict__ agg, int nE,
    const int* __restrict__ flags, int fiFeat, int fiW)
{
    const bool fF = (fiFeat == -1) ? true : (flags[fiFeat] != 0);
    const bool fW = (fiW   == -1) ? true : (flags[fiW]   != 0);
    int g = blockIdx.x * 256 + threadIdx.x;
    int e = g >> 5;
    if (e >= nE) return;
    int c = (g & 31) << 2;
    int s = src[e], d = dst[e];
    float wf = ldf(w, e, fW);
    size_t base = (size_t)s * DDIM + c;
    float* ap = agg + (size_t)d * DDIM + c;
    unsafeAtomicAdd(ap + 0, ldf(feat, base + 0, fF) * wf);
    unsafeAtomicAdd(ap + 1, ldf(feat, base + 1, fF) * wf);
    unsafeAtomicAdd(ap + 2, ldf(feat, base + 2, fF) * wf);
    unsafeAtomicAdd(ap + 3, ldf(feat, base + 3, fF) * wf);
}

// ---------------- residual: out(f32) += feat (adaptive) --------------------
__global__ __launch_bounds__(256) void residual_add(
    float* __restrict__ out, const void* __restrict__ feat, int n4,
    const int* __restrict__ flags, int fiFeat)
{
    const bool fF = flags[fiFeat] != 0;
    int i = blockIdx.x * 256 + threadIdx.x;
    if (i >= n4) return;
    f32x4 o = ((const f32x4*)out)[i];
    f32x4 r;
#pragma unroll
    for (int j = 0; j < 4; ++j) r[j] = o[j] + ldf(feat, (size_t)i * 4 + j, fF);
    ((f32x4*)out)[i] = r;
}

// ---------------- fused MLP ------------------------------------------------
__device__ __forceinline__ void fill_wfrag(const void* __restrict__ W, bool f,
                                           __bf16* wf, int tid)
{
#pragma unroll
    for (int i = 0; i < 8; ++i) {
        int sIdx  = tid + i * 256;
        int l     = sIdx & 63;
        int combo = sIdx >> 6;
        int ct = combo >> 2, kk = combo & 3;
        int col  = ct * 16 + (l & 15);
        int krow = kk * 32 + (l >> 4) * 8;
        __bf16* dp = wf + (size_t)sIdx * 8;
#pragma unroll
        for (int j = 0; j < 8; ++j)
            dp[j] = (__bf16)ldf(W, (size_t)(krow + j) * DDIM + col, f);
    }
}

__device__ __forceinline__ void copy_wfrag(const __bf16* __restrict__ prep,
                                           __bf16* wf, int tid)
{
    const f32x4* sp = (const f32x4*)prep;
    f32x4* dp = (f32x4*)wf;
#pragma unroll
    for (int i = 0; i < 8; ++i) dp[tid + i * 256] = sp[tid + i * 256];
}

// hout != nullptr: also write the PRE-residual activation there (stage-2
// gather source), while out gets the residual-added value.
template <bool RESIDUAL, bool PREP>
__global__ __launch_bounds__(256) void mlp_kernel(
    const void* __restrict__ feat, const float* __restrict__ agg,
    const void* __restrict__ W1, const void* __restrict__ b1,
    const void* __restrict__ W2, const void* __restrict__ b2,
    const void* __restrict__ epsp, float* __restrict__ out, int N,
    const int* __restrict__ flags,
    int fiFeat, int fiW1, int fiB1, int fiW2, int fiB2, int fiEps,
    const __bf16* __restrict__ pW1, const __bf16* __restrict__ pW2,
    float* __restrict__ hout)
{
    __shared__ alignas(16) __bf16 wf[32 * 64 * 8];  // 32 KB weight B-frags
    __shared__ alignas(16) __bf16 h1t[64 * 136];    // 17 KB h1 tile (+8 pad)

    const bool fF  = flags[fiFeat] != 0;
    const bool fB1 = flags[fiB1] != 0;
    const bool fB2 = flags[fiB2] != 0;
    const bool fE  = flags[fiEps] != 0;

    const int tid  = threadIdx.x;
    const int lane = tid & 63;
    const int wave = tid >> 6;
    const int quad = lane >> 4;
    const int r    = lane & 15;

    if (PREP) copy_wfrag(pW1, wf, tid);
    else      fill_wfrag(W1, flags[fiW1] != 0, wf, tid);

    const float eps1 = 1.f + ldf(epsp, 0, fE);
    const int rowBase = blockIdx.x * 64 + wave * 16;

    // A-fragments for layer 1: x[rowBase+r][k], k = kk*32 + quad*8 + j
    bf16x8 a[4];
    {
        int rowA = rowBase + r;
        if (rowA < N) {
            size_t fb = (size_t)rowA * DDIM + quad * 8;
            const f32x4* gp = (const f32x4*)(agg + fb);
            if (fF) {
                const f32x4* fp = (const f32x4*)((const float*)feat + fb);
#pragma unroll
                for (int kk = 0; kk < 4; ++kk) {
                    f32x4 f0 = fp[kk * 8], f1 = fp[kk * 8 + 1];
                    f32x4 g0 = gp[kk * 8], g1 = gp[kk * 8 + 1];
                    bf16x8 av;
#pragma unroll
                    for (int j = 0; j < 4; ++j) {
                        av[j]     = (__bf16)(f0[j] * eps1 + g0[j]);
                        av[j + 4] = (__bf16)(f1[j] * eps1 + g1[j]);
                    }
                    a[kk] = av;
                }
            } else {
                const bf16x8* fp = (const bf16x8*)((const bf16_t*)feat + fb);
#pragma unroll
                for (int kk = 0; kk < 4; ++kk) {
                    bf16x8 fv = fp[kk * 4];
                    f32x4 g0 = gp[kk * 8], g1 = gp[kk * 8 + 1];
                    bf16x8 av;
#pragma unroll
                    for (int j = 0; j < 4; ++j) {
                        av[j]     = (__bf16)((float)fv[j]     * eps1 + g0[j]);
                        av[j + 4] = (__bf16)((float)fv[j + 4] * eps1 + g1[j]);
                    }
                    a[kk] = av;
                }
            }
        } else {
#pragma unroll
            for (int kk = 0; kk < 4; ++kk)
#pragma unroll
                for (int j = 0; j < 8; ++j) a[kk][j] = (__bf16)0.f;
        }
    }

    __syncthreads();  // weights ready; all agg reads above are complete

    const bf16x8* wv = (const bf16x8*)wf;
#pragma unroll
    for (int ct = 0; ct < 8; ++ct) {
        f32x4 acc = {0.f, 0.f, 0.f, 0.f};
#pragma unroll
        for (int kk = 0; kk < 4; ++kk)
            acc = __builtin_amdgcn_mfma_f32_16x16x32_bf16(
                a[kk], wv[(ct * 4 + kk) * 64 + lane], acc, 0, 0, 0);
        float bias = ldf(b1, ct * 16 + r, fB1);
#pragma unroll
        for (int gg = 0; gg < 4; ++gg)   // D: m = quad*4+gg, n = ct*16+r
            h1t[(wave * 16 + quad * 4 + gg) * 136 + ct * 16 + r] =
                (__bf16)lrelu(acc[gg] + bias);
    }
    __syncthreads();  // h1 complete; wf free to reuse

    bf16x8 a2[4];
#pragma unroll
    for (int kk = 0; kk < 4; ++kk)
        a2[kk] = *(const bf16x8*)&h1t[(wave * 16 + r) * 136 + kk * 32 + quad * 8];

    if (PREP) copy_wfrag(pW2, wf, tid);
    else      fill_wfrag(W2, flags[fiW2] != 0, wf, tid);
    __syncthreads();  // W2 frags ready

#pragma unroll
    for (int ct = 0; ct < 8; ++ct) {
        f32x4 acc = {0.f, 0.f, 0.f, 0.f};
#pragma unroll
        for (int kk = 0; kk < 4; ++kk)
            acc = __builtin_amdgcn_mfma_f32_16x16x32_bf16(
                a2[kk], wv[(ct * 4 + kk) * 64 + lane], acc, 0, 0, 0);
        float bias = ldf(b2, ct * 16 + r, fB2);
#pragma unroll
        for (int gg = 0; gg < 4; ++gg) {
            int row = rowBase + quad * 4 + gg;
            if (row < N) {
                int col = ct * 16 + r;
                float v = lrelu(acc[gg] + bias);
                if (hout) hout[(size_t)row * DDIM + col] = v;
                if (RESIDUAL) v += ldf(feat, (size_t)row * DDIM + col, fF);
                out[(size_t)row * DDIM + col] = v;
            }
        }
    }
}

extern "C" void kernel_launch(void* const* d_in, const int* in_sizes, int n_in,
                              void* d_out, int out_size, void* d_ws, size_t ws_size,
                              hipStream_t stream)
{
    const int* src_c2r = (const int*)d_in[2];
    const int* dst_c2r = (const int*)d_in[3];
    const int* src_r2c = (const int*)d_in[5];
    const int* dst_r2c = (const int*)d_in[6];
    const int nE = in_sizes[2];

    // ws layout
    int*    flags  = (int*)d_ws;                                   // 32 ints
    __bf16* wfprep = (__bf16*)((char*)d_ws + 128);                 // 128 KB
    int*    counts = (int*)((char*)d_ws + 128 + 131072);           // NROW ints
    int*    ovCnt  = counts + NROW;                                // 1 int (+pad)
    int*    slots  = counts + NROW + 8;                            // NROW*CAP ints
    int*    ovList = slots + (size_t)NROW * CAP;                   // nE ints
    float*  hrow   = (float*)(ovList + nE);                        // NROW*DDIM f32
    const size_t NEED_BASE = 128 + 131072 + ((size_t)NROW + 8) * 4
                           + (size_t)NROW * CAP * 4;
    const size_t NEED_OV = NEED_BASE + (size_t)nE * 4;
    const size_t NEED_H  = NEED_OV + (size_t)NROW * DDIM * sizeof(float);
    const bool big    = ws_size >= NEED_BASE;
    const bool haveOv = ws_size >= NEED_OV;
    const bool haveH  = ws_size >= NEED_H;

    TensorTab T;
    for (int i = 0; i < 18; ++i) { T.p[i] = d_in[i]; T.n[i] = in_sizes[i]; }

    // OUTPUT IS F32. out_col half doubles as the f32 agg buffer.
    float* out_row = (float*)d_out;
    float* out_col = out_row + (size_t)NROW * DDIM;
    const size_t aggBytes = (size_t)NROW * DDIM * sizeof(float);   // 25.6 MB

    const int eblocks  = (nE + 255) / 256;
    const int sblocks  = (nE * 32 + 255) / 256;
    const int mblocksR = (NROW + 63) / 64;
    const int mblocksC = (NCOL + 63) / 64;
    const int gblocksR = (NROW + 3) / 4;
    const int gblocksC = (NCOL + 3) / 4;

    detect_dtypes<<<1, 256, 0, stream>>>(T, flags);

    if (big) {
        WPtrs P;
        P.W[0] = d_in[8];  P.fi[0] = 8;    // W1_c2r
        P.W[1] = d_in[10]; P.fi[1] = 10;   // W2_c2r
        P.W[2] = d_in[12]; P.fi[2] = 12;   // W1_r2c
        P.W[3] = d_in[14]; P.fi[3] = 14;   // W2_r2c
        prep_weights<<<32, 256, 0, stream>>>(P, flags, wfprep);

        // ---- stage 1: col -> row ----
        hipMemsetAsync(counts, 0, ((size_t)NROW + 8) * 4, stream);  // + ovCnt
        if (!haveOv) hipMemsetAsync(out_col, 0, aggBytes, stream);
        fill_slots<<<eblocks, 256, 0, stream>>>(dst_c2r, nE, counts, slots,
            ovCnt, haveOv ? ovList : nullptr,
            d_in[1], src_c2r, d_in[4], out_col, flags, 1, 4);
        if (haveOv) {
            segsum<true><<<gblocksR, 256, 0, stream>>>(d_in[1], src_c2r,
                d_in[4], counts, slots, out_col, NROW, flags, 1, 4);
            scatter_overflow<<<256, 256, 0, stream>>>(d_in[1], src_c2r,
                dst_c2r, d_in[4], ovList, ovCnt, out_col, flags, 1, 4);
        } else {
            segsum<false><<<gblocksR, 256, 0, stream>>>(d_in[1], src_c2r,
                d_in[4], counts, slots, out_col, NROW, flags, 1, 4);
        }
        if (haveH) {
            // fused residual: out_row = h+feat, hrow = h (stage-2 source)
            mlp_kernel<true, true><<<mblocksR, 256, 0, stream>>>(
                d_in[0], out_col, d_in[8], d_in[9], d_in[10], d_in[11], d_in[16],
                out_row, NROW, flags, 0, 8, 9, 10, 11, 16,
                wfprep + 0 * 16384, wfprep + 1 * 16384, hrow);
        } else {
            mlp_kernel<false, true><<<mblocksR, 256, 0, stream>>>(
                d_in[0], out_col, d_in[8], d_in[9], d_in[10], d_in[11], d_in[16],
                out_row, NROW, flags, 0, 8, 9, 10, 11, 16,
                wfprep + 0 * 16384, wfprep + 1 * 16384, nullptr);
        }

        // ---- stage 2: row -> col ----
        const float* gsrc = haveH ? hrow : out_row;   // pre-residual h_row
        hipMemsetAsync(counts, 0, ((size_t)NROW + 8) * 4, stream);
        if (!haveOv) hipMemsetAsync(out_col, 0, aggBytes, stream);
        fill_slots<<<eblocks, 256, 0, stream>>>(dst_r2c, nE, counts, slots,
            ovCnt, haveOv ? ovList : nullptr,
            gsrc, src_r2c, d_in[7], out_col, flags, -1, 7);
        if (haveOv) {
            segsum<true><<<gblocksC, 256, 0, stream>>>(gsrc, src_r2c,
                d_in[7], counts, slots, out_col, NCOL, flags, -1, 7);
            scatter_overflow<<<256, 256, 0, stream>>>(gsrc, src_r2c,
                dst_r2c, d_in[7], ovList, ovCnt, out_col, flags, -1, 7);
        } else {
            segsum<false><<<gblocksC, 256, 0, stream>>>(gsrc, src_r2c,
                d_in[7], counts, slots, out_col, NCOL, flags, -1, 7);
        }
        if (!haveH) {
            // residual AFTER all gathers of pre-residual out_row
            residual_add<<<(NROW * DDIM / 4 + 255) / 256, 256, 0, stream>>>(
                out_row, d_in[0], NROW * DDIM / 4, flags, 0);
        }
        mlp_kernel<true, true><<<mblocksC, 256, 0, stream>>>(
            d_in[1], out_col, d_in[12], d_in[13], d_in[14], d_in[15], d_in[17],
            out_col, NCOL, flags, 1, 12, 13, 14, 15, 17,
            wfprep + 2 * 16384, wfprep + 3 * 16384, nullptr);
    } else {
        // legacy round-5 path (atomic scatter, internal weight fill)
        hipMemsetAsync(out_col, 0, aggBytes, stream);
        scatter_any<<<sblocks, 256, 0, stream>>>(d_in[1], src_c2r, dst_c2r,
            d_in[4], out_col, nE, flags, 1, 4);
        mlp_kernel<false, false><<<mblocksR, 256, 0, stream>>>(
            d_in[0], out_col, d_in[8], d_in[9], d_in[10], d_in[11], d_in[16],
            out_row, NROW, flags, 0, 8, 9, 10, 11, 16, nullptr, nullptr, nullptr);

        hipMemsetAsync(out_col, 0, aggBytes, stream);
        scatter_any<<<sblocks, 256, 0, stream>>>(out_row, src_r2c, dst_r2c,
            d_in[7], out_col, nE, flags, -1, 7);
        residual_add<<<(NROW * DDIM / 4 + 255) / 256, 256, 0, stream>>>(
            out_row, d_in[0], NROW * DDIM / 4, flags, 0);
        mlp_kernel<true, false><<<mblocksC, 256, 0, stream>>>(
            d_in[1], out_col, d_in[12], d_in[13], d_in[14], d_in[15], d_in[17],
            out_col, NCOL, flags, 1, 12, 13, 14, 15, 17, nullptr, nullptr, nullptr);
    }
}

// Round 3
// 371.028 us; speedup vs baseline: 1.1343x; 1.1343x over previous
//
#include <hip/hip_runtime.h>
#include <hip/hip_bf16.h>

#define NROW 50000
#define NCOL 50000
#define DDIM 128
#define CAP  32   // slots per destination row

typedef __bf16 bf16_t;
typedef __bf16 bf16x2 __attribute__((ext_vector_type(2)));
typedef __bf16 bf16x8 __attribute__((ext_vector_type(8)));
typedef float  f32x4  __attribute__((ext_vector_type(4)));

__device__ __forceinline__ float lrelu(float v) { return v >= 0.f ? v : 0.01f * v; }

// adaptive scalar load: f ? f32 : bf16
__device__ __forceinline__ float ldf(const void* p, size_t i, bool f) {
    return f ? ((const float*)p)[i] : (float)((const bf16_t*)p)[i];
}

// fiFeat: >=0 -> flags[fiFeat]; -1 -> forced f32; -2 -> forced bf16
__device__ __forceinline__ bool dtf(const int* flags, int fi) {
    return (fi == -1) ? true : (fi == -2) ? false : (flags[fi] != 0);
}

// ---------------- dtype detector (proven — unchanged) ----------------------
struct TensorTab { const void* p[18]; int n[18]; };

__global__ __launch_bounds__(256) void detect_dtypes(TensorTab T, int* flags)
{
    __shared__ int vb, vf;
    const int tid = threadIdx.x;
    for (int t = 0; t < 18; ++t) {
        if (tid == 0) { vb = 0; vf = 0; }
        __syncthreads();
        const int n = T.n[t];
        const bool isFloatArr = (t != 2 && t != 3 && t != 5 && t != 6) && n >= 2;
        if (isFloatArr) {
            int nw = n / 2;
            int wi = (int)(((long long)tid * nw) >> 8);
            unsigned w = ((const unsigned*)T.p[t])[wi];
            unsigned low = w & 0xffffu;
            if (low) {
                int e = (int)((low >> 7) & 0xffu);
                if (e >= 90 && e <= 141) atomicAdd(&vb, 1);
                else                     atomicAdd(&vf, 1);
            }
        }
        __syncthreads();
        if (tid == 0) flags[t] = (isFloatArr && vf > vb) ? 1 : 0; // 1 = f32
        __syncthreads();
    }
}

// ---------------- weight prep (unchanged) ----------------------------------
struct WPtrs { const void* W[4]; int fi[4]; };

__global__ __launch_bounds__(256) void prep_weights(WPtrs P, const int* flags,
                                                    __bf16* outp)
{
    int slot = blockIdx.x * 256 + threadIdx.x;     // 4 * 2048
    if (slot >= 4 * 2048) return;
    int m = slot >> 11, sIdx = slot & 2047;
    bool f = flags[P.fi[m]] != 0;
    int l = sIdx & 63, combo = sIdx >> 6;
    int ct = combo >> 2, kk = combo & 3;
    int col  = ct * 16 + (l & 15);
    int krow = kk * 32 + (l >> 4) * 8;
    bf16x8 v;
#pragma unroll
    for (int j = 0; j < 8; ++j)
        v[j] = (__bf16)ldf(P.W[m], (size_t)(krow + j) * DDIM + col, f);
    ((bf16x8*)outp)[slot] = v;
}

// ---------------- convert feature table to bf16 (gather-source shrink) -----
__global__ __launch_bounds__(256) void convert_bf16(
    const void* __restrict__ in, __bf16* __restrict__ out, int n8,
    const int* __restrict__ flags, int fi)
{
    const bool f = dtf(flags, fi);
    int i = blockIdx.x * 256 + threadIdx.x;
    if (i >= n8) return;
    bf16x8 v;
    if (f) {
        f32x4 a = ((const f32x4*)in)[i * 2];
        f32x4 b = ((const f32x4*)in)[i * 2 + 1];
#pragma unroll
        for (int j = 0; j < 4; ++j) { v[j] = (__bf16)a[j]; v[j + 4] = (__bf16)b[j]; }
    } else {
        v = ((const bf16x8*)in)[i];
    }
    ((bf16x8*)out)[i] = v;
}

// ---------------- bucket fill, packed (src,w) slots -------------------------
__global__ __launch_bounds__(256) void fill_slots_packed(
    const int* __restrict__ dst, const int* __restrict__ srcArr,
    const void* __restrict__ wArr, int nE, int* __restrict__ counts,
    int2* __restrict__ slots2, int* __restrict__ ovCount,
    int* __restrict__ ovList, const int* __restrict__ flags, int fiW)
{
    int e = blockIdx.x * 256 + threadIdx.x;
    if (e >= nE) return;
    const bool fW = dtf(flags, fiW);
    int d = dst[e];
    int pos = atomicAdd(&counts[d], 1);
    if (pos < CAP) {
        int2 pk;
        pk.x = srcArr[e];
        pk.y = __float_as_int(ldf(wArr, e, fW));
        slots2[(size_t)d * CAP + pos] = pk;
    } else {
        int k = atomicAdd(ovCount, 1);   // capacity == nE, cannot overflow
        ovList[k] = e;
    }
}

// ---------------- overflow apply: grid-stride over ovList -------------------
__global__ __launch_bounds__(256) void scatter_overflow(
    const void* __restrict__ feat, const int* __restrict__ srcArr,
    const int* __restrict__ dstArr, const void* __restrict__ wArr,
    const int* __restrict__ ovList, const int* __restrict__ ovCount,
    float* __restrict__ agg, const int* __restrict__ flags, int fiFeat, int fiW)
{
    const bool fF = dtf(flags, fiFeat);
    const bool fW = dtf(flags, fiW);
    const int nOv = *ovCount;
    const int stride = gridDim.x * 256;
    for (int g = blockIdx.x * 256 + threadIdx.x; (g >> 5) < nOv; g += stride) {
        int idx = g >> 5;                 // 32 threads per edge
        int e = ovList[idx];
        int c = (g & 31) << 2;            // 4 floats per thread
        int s = srcArr[e], d = dstArr[e];
        float wf = ldf(wArr, e, fW);
        size_t base = (size_t)s * DDIM + c;
        float* ap = agg + (size_t)d * DDIM + c;
        unsafeAtomicAdd(ap + 0, ldf(feat, base + 0, fF) * wf);
        unsafeAtomicAdd(ap + 1, ldf(feat, base + 1, fF) * wf);
        unsafeAtomicAdd(ap + 2, ldf(feat, base + 2, fF) * wf);
        unsafeAtomicAdd(ap + 3, ldf(feat, base + 3, fF) * wf);
    }
}

// ---------------- segment sum, bf16 source + packed slots -------------------
// One wave per destination row. Lanes 0..31 read the packed (src,w) slots in
// ONE coalesced 8B load; 4-deep gather pipeline (round-1 proven structure).
// Stores result (ZINIT semantics): doubles as the zero-fill for empty rows.
__global__ __launch_bounds__(256) void segsum_b(
    const __bf16* __restrict__ gsrc, const int* __restrict__ counts,
    const int2* __restrict__ slots2, float* __restrict__ agg, int nRows)
{
    int row = blockIdx.x * 4 + (threadIdx.x >> 6);
    if (row >= nRows) return;
    int lane = threadIdx.x & 63;

    int cnt = counts[row]; if (cnt > CAP) cnt = CAP;

    int sr = 0; float wv = 0.f;
    if (lane < cnt) {
        int2 pk = slots2[(size_t)row * CAP + lane];
        sr = pk.x;
        wv = __int_as_float(pk.y);
    }

    float2* ap = (float2*)(agg + (size_t)row * DDIM) + lane;
    float2 acc0 = {0.f, 0.f}, acc1 = {0.f, 0.f};

    const bf16x2* fb = (const bf16x2*)gsrc;
    int i = 0;
    for (; i + 4 <= cnt; i += 4) {
        int   a0 = __shfl(sr, i),     a1 = __shfl(sr, i + 1);
        int   a2 = __shfl(sr, i + 2), a3 = __shfl(sr, i + 3);
        float w0 = __shfl(wv, i),     w1 = __shfl(wv, i + 1);
        float w2 = __shfl(wv, i + 2), w3 = __shfl(wv, i + 3);
        bf16x2 v0 = fb[(size_t)a0 * 64 + lane];
        bf16x2 v1 = fb[(size_t)a1 * 64 + lane];
        bf16x2 v2 = fb[(size_t)a2 * 64 + lane];
        bf16x2 v3 = fb[(size_t)a3 * 64 + lane];
        acc0.x += (float)v0[0] * w0; acc0.y += (float)v0[1] * w0;
        acc1.x += (float)v1[0] * w1; acc1.y += (float)v1[1] * w1;
        acc0.x += (float)v2[0] * w2; acc0.y += (float)v2[1] * w2;
        acc1.x += (float)v3[0] * w3; acc1.y += (float)v3[1] * w3;
    }
    for (; i < cnt; ++i) {
        int   a0 = __shfl(sr, i);
        float w0 = __shfl(wv, i);
        bf16x2 v0 = fb[(size_t)a0 * 64 + lane];
        acc0.x += (float)v0[0] * w0; acc0.y += (float)v0[1] * w0;
    }
    acc0.x += acc1.x; acc0.y += acc1.y;
    *ap = acc0;
}

// ---------------- Tier-B: round-1 bucket fill (edge ids) --------------------
__global__ __launch_bounds__(256) void fill_slots(
    const int* __restrict__ dst, int nE, int* __restrict__ counts,
    int* __restrict__ slots, int* __restrict__ ovCount, int* __restrict__ ovList,
    const void* __restrict__ feat, const int* __restrict__ srcArr,
    const void* __restrict__ wArr, float* __restrict__ agg,
    const int* __restrict__ flags, int fiFeat, int fiW)
{
    int e = blockIdx.x * 256 + threadIdx.x;
    if (e >= nE) return;
    int d = dst[e];
    int pos = atomicAdd(&counts[d], 1);
    if (pos < CAP) {
        slots[(size_t)d * CAP + pos] = e;
    } else if (ovList) {
        int k = atomicAdd(ovCount, 1);
        ovList[k] = e;
    } else {
        const bool fF = dtf(flags, fiFeat);
        const bool fW = dtf(flags, fiW);
        int s = srcArr[e];
        float wf = ldf(wArr, e, fW);
        for (int c = 0; c < DDIM; ++c)
            unsafeAtomicAdd(&agg[(size_t)d * DDIM + c],
                            ldf(feat, (size_t)s * DDIM + c, fF) * wf);
    }
}

// ---------------- Tier-B: round-1 segsum (4-deep, adaptive dtype) -----------
template <bool ZINIT>
__global__ __launch_bounds__(256) void segsum(
    const void* __restrict__ feat, const int* __restrict__ srcArr,
    const void* __restrict__ wArr, const int* __restrict__ counts,
    const int* __restrict__ slots, float* __restrict__ agg, int nRows,
    const int* __restrict__ flags, int fiFeat, int fiW)
{
    const bool fF = dtf(flags, fiFeat);
    const bool fW = dtf(flags, fiW);
    int row = blockIdx.x * 4 + (threadIdx.x >> 6);
    if (row >= nRows) return;
    int lane = threadIdx.x & 63;

    int cnt = counts[row]; if (cnt > CAP) cnt = CAP;

    int sr = 0; float wv = 0.f;
    if (lane < cnt) {
        int e = slots[(size_t)row * CAP + lane];
        sr = srcArr[e];
        wv = ldf(wArr, e, fW);
    }

    float2* ap = (float2*)(agg + (size_t)row * DDIM) + lane;
    float2 acc0 = {0.f, 0.f}, acc1 = {0.f, 0.f};
    if (!ZINIT) acc0 = *ap;

    if (fF) {
        const float2* fb = (const float2*)feat;
        int i = 0;
        for (; i + 4 <= cnt; i += 4) {
            int   a0 = __shfl(sr, i),     a1 = __shfl(sr, i + 1);
            int   a2 = __shfl(sr, i + 2), a3 = __shfl(sr, i + 3);
            float w0 = __shfl(wv, i),     w1 = __shfl(wv, i + 1);
            float w2 = __shfl(wv, i + 2), w3 = __shfl(wv, i + 3);
            float2 v0 = fb[(size_t)a0 * 64 + lane];
            float2 v1 = fb[(size_t)a1 * 64 + lane];
            float2 v2 = fb[(size_t)a2 * 64 + lane];
            float2 v3 = fb[(size_t)a3 * 64 + lane];
            acc0.x += v0.x * w0; acc0.y += v0.y * w0;
            acc1.x += v1.x * w1; acc1.y += v1.y * w1;
            acc0.x += v2.x * w2; acc0.y += v2.y * w2;
            acc1.x += v3.x * w3; acc1.y += v3.y * w3;
        }
        for (; i < cnt; ++i) {
            int   a0 = __shfl(sr, i);
            float w0 = __shfl(wv, i);
            float2 v0 = fb[(size_t)a0 * 64 + lane];
            acc0.x += v0.x * w0; acc0.y += v0.y * w0;
        }
    } else {
        const bf16x2* fb = (const bf16x2*)feat;
        int i = 0;
        for (; i + 4 <= cnt; i += 4) {
            int   a0 = __shfl(sr, i),     a1 = __shfl(sr, i + 1);
            int   a2 = __shfl(sr, i + 2), a3 = __shfl(sr, i + 3);
            float w0 = __shfl(wv, i),     w1 = __shfl(wv, i + 1);
            float w2 = __shfl(wv, i + 2), w3 = __shfl(wv, i + 3);
            bf16x2 v0 = fb[(size_t)a0 * 64 + lane];
            bf16x2 v1 = fb[(size_t)a1 * 64 + lane];
            bf16x2 v2 = fb[(size_t)a2 * 64 + lane];
            bf16x2 v3 = fb[(size_t)a3 * 64 + lane];
            acc0.x += (float)v0[0] * w0; acc0.y += (float)v0[1] * w0;
            acc1.x += (float)v1[0] * w1; acc1.y += (float)v1[1] * w1;
            acc0.x += (float)v2[0] * w2; acc0.y += (float)v2[1] * w2;
            acc1.x += (float)v3[0] * w3; acc1.y += (float)v3[1] * w3;
        }
        for (; i < cnt; ++i) {
            int   a0 = __shfl(sr, i);
            float w0 = __shfl(wv, i);
            bf16x2 v0 = fb[(size_t)a0 * 64 + lane];
            acc0.x += (float)v0[0] * w0; acc0.y += (float)v0[1] * w0;
        }
    }
    acc0.x += acc1.x; acc0.y += acc1.y;
    *ap = acc0;
}

// ---------------- legacy atomic scatter (ws-too-small fallback) -------------
__global__ __launch_bounds__(256) void scatter_any(
    const void* __restrict__ feat, const int* __restrict__ src,
    const int* __restrict__ dst, const void* __restrict__ w,
    float* __restrict__ agg, int nE,
    const int* __restrict__ flags, int fiFeat, int fiW)
{
    const bool fF = dtf(flags, fiFeat);
    const bool fW = dtf(flags, fiW);
    int g = blockIdx.x * 256 + threadIdx.x;
    int e = g >> 5;
    if (e >= nE) return;
    int c = (g & 31) << 2;
    int s = src[e], d = dst[e];
    float wf = ldf(w, e, fW);
    size_t base = (size_t)s * DDIM + c;
    float* ap = agg + (size_t)d * DDIM + c;
    unsafeAtomicAdd(ap + 0, ldf(feat, base + 0, fF) * wf);
    unsafeAtomicAdd(ap + 1, ldf(feat, base + 1, fF) * wf);
    unsafeAtomicAdd(ap + 2, ldf(feat, base + 2, fF) * wf);
    unsafeAtomicAdd(ap + 3, ldf(feat, base + 3, fF) * wf);
}

// ---------------- residual: out(f32) += feat (adaptive) --------------------
__global__ __launch_bounds__(256) void residual_add(
    float* __restrict__ out, const void* __restrict__ feat, int n4,
    const int* __restrict__ flags, int fiFeat)
{
    const bool fF = flags[fiFeat] != 0;
    int i = blockIdx.x * 256 + threadIdx.x;
    if (i >= n4) return;
    f32x4 o = ((const f32x4*)out)[i];
    f32x4 r;
#pragma unroll
    for (int j = 0; j < 4; ++j) r[j] = o[j] + ldf(feat, (size_t)i * 4 + j, fF);
    ((f32x4*)out)[i] = r;
}

// ---------------- fused MLP ------------------------------------------------
__device__ __forceinline__ void fill_wfrag(const void* __restrict__ W, bool f,
                                           __bf16* wf, int tid)
{
#pragma unroll
    for (int i = 0; i < 8; ++i) {
        int sIdx  = tid + i * 256;
        int l     = sIdx & 63;
        int combo = sIdx >> 6;
        int ct = combo >> 2, kk = combo & 3;
        int col  = ct * 16 + (l & 15);
        int krow = kk * 32 + (l >> 4) * 8;
        __bf16* dp = wf + (size_t)sIdx * 8;
#pragma unroll
        for (int j = 0; j < 8; ++j)
            dp[j] = (__bf16)ldf(W, (size_t)(krow + j) * DDIM + col, f);
    }
}

__device__ __forceinline__ void copy_wfrag(const __bf16* __restrict__ prep,
                                           __bf16* wf, int tid)
{
    const f32x4* sp = (const f32x4*)prep;
    f32x4* dp = (f32x4*)wf;
#pragma unroll
    for (int i = 0; i < 8; ++i) dp[tid + i * 256] = sp[tid + i * 256];
}

// hout != nullptr: also write PRE-residual activation as BF16 there (stage-2
// gather source), while out gets the residual-added f32 value.
template <bool RESIDUAL, bool PREP>
__global__ __launch_bounds__(256) void mlp_kernel(
    const void* __restrict__ feat, const float* __restrict__ agg,
    const void* __restrict__ W1, const void* __restrict__ b1,
    const void* __restrict__ W2, const void* __restrict__ b2,
    const void* __restrict__ epsp, float* __restrict__ out, int N,
    const int* __restrict__ flags,
    int fiFeat, int fiW1, int fiB1, int fiW2, int fiB2, int fiEps,
    const __bf16* __restrict__ pW1, const __bf16* __restrict__ pW2,
    __bf16* __restrict__ hout)
{
    __shared__ alignas(16) __bf16 wf[32 * 64 * 8];  // 32 KB weight B-frags
    __shared__ alignas(16) __bf16 h1t[64 * 136];    // 17 KB h1 tile (+8 pad)

    const bool fF  = flags[fiFeat] != 0;
    const bool fB1 = flags[fiB1] != 0;
    const bool fB2 = flags[fiB2] != 0;
    const bool fE  = flags[fiEps] != 0;

    const int tid  = threadIdx.x;
    const int lane = tid & 63;
    const int wave = tid >> 6;
    const int quad = lane >> 4;
    const int r    = lane & 15;

    if (PREP) copy_wfrag(pW1, wf, tid);
    else      fill_wfrag(W1, flags[fiW1] != 0, wf, tid);

    const float eps1 = 1.f + ldf(epsp, 0, fE);
    const int rowBase = blockIdx.x * 64 + wave * 16;

    // A-fragments for layer 1: x[rowBase+r][k], k = kk*32 + quad*8 + j
    bf16x8 a[4];
    {
        int rowA = rowBase + r;
        if (rowA < N) {
            size_t fb = (size_t)rowA * DDIM + quad * 8;
            const f32x4* gp = (const f32x4*)(agg + fb);
            if (fF) {
                const f32x4* fp = (const f32x4*)((const float*)feat + fb);
#pragma unroll
                for (int kk = 0; kk < 4; ++kk) {
                    f32x4 f0 = fp[kk * 8], f1 = fp[kk * 8 + 1];
                    f32x4 g0 = gp[kk * 8], g1 = gp[kk * 8 + 1];
                    bf16x8 av;
#pragma unroll
                    for (int j = 0; j < 4; ++j) {
                        av[j]     = (__bf16)(f0[j] * eps1 + g0[j]);
                        av[j + 4] = (__bf16)(f1[j] * eps1 + g1[j]);
                    }
                    a[kk] = av;
                }
            } else {
                const bf16x8* fp = (const bf16x8*)((const bf16_t*)feat + fb);
#pragma unroll
                for (int kk = 0; kk < 4; ++kk) {
                    bf16x8 fv = fp[kk * 4];
                    f32x4 g0 = gp[kk * 8], g1 = gp[kk * 8 + 1];
                    bf16x8 av;
#pragma unroll
                    for (int j = 0; j < 4; ++j) {
                        av[j]     = (__bf16)((float)fv[j]     * eps1 + g0[j]);
                        av[j + 4] = (__bf16)((float)fv[j + 4] * eps1 + g1[j]);
                    }
                    a[kk] = av;
                }
            }
        } else {
#pragma unroll
            for (int kk = 0; kk < 4; ++kk)
#pragma unroll
                for (int j = 0; j < 8; ++j) a[kk][j] = (__bf16)0.f;
        }
    }

    __syncthreads();  // weights ready; all agg reads above are complete

    const bf16x8* wv = (const bf16x8*)wf;
#pragma unroll
    for (int ct = 0; ct < 8; ++ct) {
        f32x4 acc = {0.f, 0.f, 0.f, 0.f};
#pragma unroll
        for (int kk = 0; kk < 4; ++kk)
            acc = __builtin_amdgcn_mfma_f32_16x16x32_bf16(
                a[kk], wv[(ct * 4 + kk) * 64 + lane], acc, 0, 0, 0);
        float bias = ldf(b1, ct * 16 + r, fB1);
#pragma unroll
        for (int gg = 0; gg < 4; ++gg)   // D: m = quad*4+gg, n = ct*16+r
            h1t[(wave * 16 + quad * 4 + gg) * 136 + ct * 16 + r] =
                (__bf16)lrelu(acc[gg] + bias);
    }
    __syncthreads();  // h1 complete; wf free to reuse

    bf16x8 a2[4];
#pragma unroll
    for (int kk = 0; kk < 4; ++kk)
        a2[kk] = *(const bf16x8*)&h1t[(wave * 16 + r) * 136 + kk * 32 + quad * 8];

    if (PREP) copy_wfrag(pW2, wf, tid);
    else      fill_wfrag(W2, flags[fiW2] != 0, wf, tid);
    __syncthreads();  // W2 frags ready

#pragma unroll
    for (int ct = 0; ct < 8; ++ct) {
        f32x4 acc = {0.f, 0.f, 0.f, 0.f};
#pragma unroll
        for (int kk = 0; kk < 4; ++kk)
            acc = __builtin_amdgcn_mfma_f32_16x16x32_bf16(
                a2[kk], wv[(ct * 4 + kk) * 64 + lane], acc, 0, 0, 0);
        float bias = ldf(b2, ct * 16 + r, fB2);
#pragma unroll
        for (int gg = 0; gg < 4; ++gg) {
            int row = rowBase + quad * 4 + gg;
            if (row < N) {
                int col = ct * 16 + r;
                float v = lrelu(acc[gg] + bias);
                if (hout) hout[(size_t)row * DDIM + col] = (__bf16)v;
                if (RESIDUAL) v += ldf(feat, (size_t)row * DDIM + col, fF);
                out[(size_t)row * DDIM + col] = v;
            }
        }
    }
}

extern "C" void kernel_launch(void* const* d_in, const int* in_sizes, int n_in,
                              void* d_out, int out_size, void* d_ws, size_t ws_size,
                              hipStream_t stream)
{
    const int* src_c2r = (const int*)d_in[2];
    const int* dst_c2r = (const int*)d_in[3];
    const int* src_r2c = (const int*)d_in[5];
    const int* dst_r2c = (const int*)d_in[6];
    const int nE = in_sizes[2];

    // ---- workspace layout (Tier A) ----
    // flags(128B) | wfprep(128KB) | counts(NROW) | ovCnt(8) | slots2(NROW*CAP*8)
    // | ovList(nE) | cbuf(max(NROW,NCOL)*DDIM bf16, SHARED by stage1 src copy
    //   and stage2 h_row)
    char* wsb = (char*)d_ws;
    int*    flags  = (int*)wsb;
    __bf16* wfprep = (__bf16*)(wsb + 128);
    int*    counts = (int*)(wsb + 128 + 131072);
    int*    ovCnt  = counts + NROW;
    size_t  ofs    = 128 + 131072 + ((size_t)NROW + 8) * 4;
    ofs = (ofs + 15) & ~(size_t)15;
    int2*   slots2 = (int2*)(wsb + ofs);                 // Tier A packed slots
    int*    slots  = (int*)(wsb + ofs);                  // Tier B edge-id slots
    size_t  ofsOvA = ofs + (size_t)NROW * CAP * 8;       // after slots2
    size_t  ofsOvB = ofs + (size_t)NROW * CAP * 4;       // after slots (TierB)
    int*    ovListA = (int*)(wsb + ofsOvA);
    int*    ovListB = (int*)(wsb + ofsOvB);
    size_t  ofsCb  = (ofsOvA + (size_t)nE * 4 + 15) & ~(size_t)15;
    __bf16* cbuf   = (__bf16*)(wsb + ofsCb);

    const size_t NEED_A = ofsCb + (size_t)NROW * DDIM * 2;      // ~28.4 MB
    const size_t NEED_B = ofsOvB + (size_t)nE * 4;              // ~9.1 MB
    const size_t NEED_B0 = ofsOvB;                              // ~6.7 MB
    const bool tierA  = ws_size >= NEED_A;
    const bool tierB  = ws_size >= NEED_B;
    const bool tierB0 = ws_size >= NEED_B0;

    TensorTab T;
    for (int i = 0; i < 18; ++i) { T.p[i] = d_in[i]; T.n[i] = in_sizes[i]; }

    // OUTPUT IS F32. out_col half doubles as the f32 agg buffer.
    float* out_row = (float*)d_out;
    float* out_col = out_row + (size_t)NROW * DDIM;
    const size_t aggBytes = (size_t)NROW * DDIM * sizeof(float);   // 25.6 MB

    const int eblocks  = (nE + 255) / 256;
    const int sblocks  = (nE * 32 + 255) / 256;
    const int mblocksR = (NROW + 63) / 64;
    const int mblocksC = (NCOL + 63) / 64;
    const int gblocksR = (NROW + 3) / 4;
    const int gblocksC = (NCOL + 3) / 4;
    const int cblocks  = (NROW * DDIM / 8 + 255) / 256;

    detect_dtypes<<<1, 256, 0, stream>>>(T, flags);

    if (tierA) {
        WPtrs P;
        P.W[0] = d_in[8];  P.fi[0] = 8;
        P.W[1] = d_in[10]; P.fi[1] = 10;
        P.W[2] = d_in[12]; P.fi[2] = 12;
        P.W[3] = d_in[14]; P.fi[3] = 14;
        prep_weights<<<32, 256, 0, stream>>>(P, flags, wfprep);

        // ---- stage 1: col -> row ----
        convert_bf16<<<cblocks, 256, 0, stream>>>(d_in[1], cbuf,
            NCOL * DDIM / 8, flags, 1);
        hipMemsetAsync(counts, 0, ((size_t)NROW + 8) * 4, stream);
        fill_slots_packed<<<eblocks, 256, 0, stream>>>(dst_c2r, src_c2r,
            d_in[4], nE, counts, slots2, ovCnt, ovListA, flags, 4);
        segsum_b<<<gblocksR, 256, 0, stream>>>(cbuf, counts, slots2,
            out_col, NROW);
        scatter_overflow<<<256, 256, 0, stream>>>(d_in[1], src_c2r,
            dst_c2r, d_in[4], ovListA, ovCnt, out_col, flags, 1, 4);
        // fused residual: out_row = h+feat_row (f32), cbuf = h (bf16)
        mlp_kernel<true, true><<<mblocksR, 256, 0, stream>>>(
            d_in[0], out_col, d_in[8], d_in[9], d_in[10], d_in[11], d_in[16],
            out_row, NROW, flags, 0, 8, 9, 10, 11, 16,
            wfprep + 0 * 16384, wfprep + 1 * 16384, cbuf);

        // ---- stage 2: row -> col ----
        hipMemsetAsync(counts, 0, ((size_t)NROW + 8) * 4, stream);
        fill_slots_packed<<<eblocks, 256, 0, stream>>>(dst_r2c, src_r2c,
            d_in[7], nE, counts, slots2, ovCnt, ovListA, flags, 7);
        segsum_b<<<gblocksC, 256, 0, stream>>>(cbuf, counts, slots2,
            out_col, NCOL);
        scatter_overflow<<<256, 256, 0, stream>>>(cbuf, src_r2c,
            dst_r2c, d_in[7], ovListA, ovCnt, out_col, flags, -2, 7);
        mlp_kernel<true, true><<<mblocksC, 256, 0, stream>>>(
            d_in[1], out_col, d_in[12], d_in[13], d_in[14], d_in[15], d_in[17],
            out_col, NCOL, flags, 1, 12, 13, 14, 15, 17,
            wfprep + 2 * 16384, wfprep + 3 * 16384, nullptr);
    } else if (tierB0) {
        WPtrs P;
        P.W[0] = d_in[8];  P.fi[0] = 8;
        P.W[1] = d_in[10]; P.fi[1] = 10;
        P.W[2] = d_in[12]; P.fi[2] = 12;
        P.W[3] = d_in[14]; P.fi[3] = 14;
        prep_weights<<<32, 256, 0, stream>>>(P, flags, wfprep);

        // ---- stage 1 ----
        hipMemsetAsync(counts, 0, ((size_t)NROW + 8) * 4, stream);
        if (!tierB) hipMemsetAsync(out_col, 0, aggBytes, stream);
        fill_slots<<<eblocks, 256, 0, stream>>>(dst_c2r, nE, counts, slots,
            ovCnt, tierB ? ovListB : nullptr,
            d_in[1], src_c2r, d_in[4], out_col, flags, 1, 4);
        if (tierB) {
            segsum<true><<<gblocksR, 256, 0, stream>>>(d_in[1], src_c2r,
                d_in[4], counts, slots, out_col, NROW, flags, 1, 4);
            scatter_overflow<<<256, 256, 0, stream>>>(d_in[1], src_c2r,
                dst_c2r, d_in[4], ovListB, ovCnt, out_col, flags, 1, 4);
        } else {
            segsum<false><<<gblocksR, 256, 0, stream>>>(d_in[1], src_c2r,
                d_in[4], counts, slots, out_col, NROW, flags, 1, 4);
        }
        mlp_kernel<false, true><<<mblocksR, 256, 0, stream>>>(
            d_in[0], out_col, d_in[8], d_in[9], d_in[10], d_in[11], d_in[16],
            out_row, NROW, flags, 0, 8, 9, 10, 11, 16,
            wfprep + 0 * 16384, wfprep + 1 * 16384, nullptr);

        // ---- stage 2 ----
        hipMemsetAsync(counts, 0, ((size_t)NROW + 8) * 4, stream);
        if (!tierB) hipMemsetAsync(out_col, 0, aggBytes, stream);
        fill_slots<<<eblocks, 256, 0, stream>>>(dst_r2c, nE, counts, slots,
            ovCnt, tierB ? ovListB : nullptr,
            out_row, src_r2c, d_in[7], out_col, flags, -1, 7);
        if (tierB) {
            segsum<true><<<gblocksC, 256, 0, stream>>>(out_row, src_r2c,
                d_in[7], counts, slots, out_col, NCOL, flags, -1, 7);
            scatter_overflow<<<256, 256, 0, stream>>>(out_row, src_r2c,
                dst_r2c, d_in[7], ovListB, ovCnt, out_col, flags, -1, 7);
        } else {
            segsum<false><<<gblocksC, 256, 0, stream>>>(out_row, src_r2c,
                d_in[7], counts, slots, out_col, NCOL, flags, -1, 7);
        }
        residual_add<<<(NROW * DDIM / 4 + 255) / 256, 256, 0, stream>>>(
            out_row, d_in[0], NROW * DDIM / 4, flags, 0);
        mlp_kernel<true, true><<<mblocksC, 256, 0, stream>>>(
            d_in[1], out_col, d_in[12], d_in[13], d_in[14], d_in[15], d_in[17],
            out_col, NCOL, flags, 1, 12, 13, 14, 15, 17,
            wfprep + 2 * 16384, wfprep + 3 * 16384, nullptr);
    } else {
        // legacy path (atomic scatter, internal weight fill)
        hipMemsetAsync(out_col, 0, aggBytes, stream);
        scatter_any<<<sblocks, 256, 0, stream>>>(d_in[1], src_c2r, dst_c2r,
            d_in[4], out_col, nE, flags, 1, 4);
        mlp_kernel<false, false><<<mblocksR, 256, 0, stream>>>(
            d_in[0], out_col, d_in[8], d_in[9], d_in[10], d_in[11], d_in[16],
            out_row, NROW, flags, 0, 8, 9, 10, 11, 16, nullptr, nullptr, nullptr);

        hipMemsetAsync(out_col, 0, aggBytes, stream);
        scatter_any<<<sblocks, 256, 0, stream>>>(out_row, src_r2c, dst_r2c,
            d_in[7], out_col, nE, flags, -1, 7);
        residual_add<<<(NROW * DDIM / 4 + 255) / 256, 256, 0, stream>>>(
            out_row, d_in[0], NROW * DDIM / 4, flags, 0);
        mlp_kernel<true, false><<<mblocksC, 256, 0, stream>>>(
            d_in[1], out_col, d_in[12], d_in[13], d_in[14], d_in[15], d_in[17],
            out_col, NCOL, flags, 1, 12, 13, 14, 15, 17, nullptr, nullptr, nullptr);
    }
}

// Round 4
// 340.001 us; speedup vs baseline: 1.2378x; 1.0913x over previous
//
#include <hip/hip_runtime.h>
#include <hip/hip_bf16.h>

#define NROW 50000
#define NCOL 50000
#define DDIM 128
#define CAP  32   // slots per destination row

typedef __bf16 bf16_t;
typedef __bf16 bf16x2 __attribute__((ext_vector_type(2)));
typedef __bf16 bf16x8 __attribute__((ext_vector_type(8)));
typedef float  f32x4  __attribute__((ext_vector_type(4)));

__device__ __forceinline__ float lrelu(float v) { return v >= 0.f ? v : 0.01f * v; }

// adaptive scalar load: f ? f32 : bf16
__device__ __forceinline__ float ldf(const void* p, size_t i, bool f) {
    return f ? ((const float*)p)[i] : (float)((const bf16_t*)p)[i];
}

// fi: >=0 -> flags[fi]; -1 -> forced f32; -2 -> forced bf16
__device__ __forceinline__ bool dtf(const int* flags, int fi) {
    return (fi == -1) ? true : (fi == -2) ? false : (flags[fi] != 0);
}

// ---------------- dtype detector: one block per tensor ----------------------
struct TensorTab { const void* p[18]; int n[18]; };

__global__ __launch_bounds__(256) void detect_dtypes(TensorTab T, int* flags)
{
    __shared__ int vb, vf;
    const int tid = threadIdx.x;
    const int t = blockIdx.x;
    if (tid == 0) { vb = 0; vf = 0; }
    __syncthreads();
    const int n = T.n[t];
    const bool isFloatArr = (t != 2 && t != 3 && t != 5 && t != 6) && n >= 2;
    if (isFloatArr) {
        int nw = n / 2;
        int wi = (int)(((long long)tid * nw) >> 8);
        unsigned w = ((const unsigned*)T.p[t])[wi];
        unsigned low = w & 0xffffu;
        if (low) {
            int e = (int)((low >> 7) & 0xffu);
            if (e >= 90 && e <= 141) atomicAdd(&vb, 1);
            else                     atomicAdd(&vf, 1);
        }
    }
    __syncthreads();
    if (tid == 0) flags[t] = (isFloatArr && vf > vb) ? 1 : 0; // 1 = f32
}

// ---------------- fused prep: convert feat->bf16 | zero counts | weight prep
struct WPtrs { const void* W[4]; int fi[4]; };

__global__ __launch_bounds__(256) void prep_all(
    WPtrs P, const int* __restrict__ flags, __bf16* __restrict__ wfp,
    const void* __restrict__ feat, __bf16* __restrict__ cbuf, int n8, int fiFeat,
    int* __restrict__ zc, int zn, int cblocks, int zblocks)
{
    const int b = blockIdx.x;
    const int tid = threadIdx.x;
    if (b < cblocks) {                       // convert feat table to bf16
        int i = b * 256 + tid;
        if (i >= n8) return;
        const bool f = dtf(flags, fiFeat);
        bf16x8 v;
        if (f) {
            f32x4 a = ((const f32x4*)feat)[i * 2];
            f32x4 c = ((const f32x4*)feat)[i * 2 + 1];
#pragma unroll
            for (int j = 0; j < 4; ++j) { v[j] = (__bf16)a[j]; v[j + 4] = (__bf16)c[j]; }
        } else {
            v = ((const bf16x8*)feat)[i];
        }
        ((bf16x8*)cbuf)[i] = v;
    } else if (b < cblocks + zblocks) {      // zero counts + ovCnt
        int i = (b - cblocks) * 256 + tid;
        if (i < zn) zc[i] = 0;
    } else {                                 // weight B-frag prep (4 matrices)
        int slot = (b - cblocks - zblocks) * 256 + tid;   // 4 * 2048
        if (slot >= 4 * 2048) return;
        int m = slot >> 11, sIdx = slot & 2047;
        bool f = flags[P.fi[m]] != 0;
        int l = sIdx & 63, combo = sIdx >> 6;
        int ct = combo >> 2, kk = combo & 3;
        int col  = ct * 16 + (l & 15);
        int krow = kk * 32 + (l >> 4) * 8;
        bf16x8 v;
#pragma unroll
        for (int j = 0; j < 8; ++j)
            v[j] = (__bf16)ldf(P.W[m], (size_t)(krow + j) * DDIM + col, f);
        ((bf16x8*)wfp)[slot] = v;
    }
}

// ---------------- bucket fill, packed (src,w) slots -------------------------
// pos == CAP (first overflower of a row): zero that agg row here, so the
// next dispatch (segsum_ov) can use pure atomic accumulation for it.
__global__ __launch_bounds__(256) void fill_slots_packed(
    const int* __restrict__ dst, const int* __restrict__ srcArr,
    const void* __restrict__ wArr, int nE, int* __restrict__ counts,
    int2* __restrict__ slots2, int* __restrict__ ovCount,
    int* __restrict__ ovList, float* __restrict__ agg,
    const int* __restrict__ flags, int fiW)
{
    int e = blockIdx.x * 256 + threadIdx.x;
    if (e >= nE) return;
    const bool fW = dtf(flags, fiW);
    int d = dst[e];
    int pos = atomicAdd(&counts[d], 1);
    if (pos < CAP) {
        int2 pk;
        pk.x = srcArr[e];
        pk.y = __float_as_int(ldf(wArr, e, fW));
        slots2[(size_t)d * CAP + pos] = pk;
    } else {
        if (pos == CAP) {                    // first overflow: init the row
            f32x4 z = {0.f, 0.f, 0.f, 0.f};
            f32x4* rp = (f32x4*)(agg + (size_t)d * DDIM);
#pragma unroll 4
            for (int c = 0; c < DDIM / 4; ++c) rp[c] = z;
        }
        int k = atomicAdd(ovCount, 1);       // capacity == nE, cannot overflow
        ovList[k] = e;
    }
}

// ---------------- segment sum + fused overflow apply ------------------------
// Blocks < gblocks: one wave per destination row; lanes 0..31 read packed
// (src,w) in ONE coalesced 8B load; 4-deep gather pipeline. Rows with
// cnt<=CAP: plain store (doubles as zero-fill). Rows with cnt>CAP: atomic
// accumulate (row pre-zeroed by fill_slots_packed).
// Blocks >= gblocks: grid-stride overflow edges, one wave per edge.
__global__ __launch_bounds__(256) void segsum_ov(
    const __bf16* __restrict__ gsrc, const int* __restrict__ counts,
    const int2* __restrict__ slots2, float* __restrict__ agg, int nRows,
    const int* __restrict__ srcArr, const int* __restrict__ dstArr,
    const void* __restrict__ wArr, const int* __restrict__ ovList,
    const int* __restrict__ ovCount, const int* __restrict__ flags, int fiW,
    int gblocks)
{
    const int tid  = threadIdx.x;
    const int lane = tid & 63;

    if ((int)blockIdx.x >= gblocks) {        // ---- overflow applier ----
        const bool fW = dtf(flags, fiW);
        const int nOv = *ovCount;
        const int wv_ = tid >> 6;
        const int nWaves = 64 * 4;           // 64 extra blocks * 4 waves
        for (int k = (blockIdx.x - gblocks) * 4 + wv_; k < nOv; k += nWaves) {
            int e = ovList[k];
            int s = srcArr[e], d = dstArr[e];
            float wf = ldf(wArr, e, fW);
            bf16x2 v = ((const bf16x2*)gsrc)[(size_t)s * 64 + lane];
            float* ap = agg + (size_t)d * DDIM + lane * 2;
            unsafeAtomicAdd(ap + 0, (float)v[0] * wf);
            unsafeAtomicAdd(ap + 1, (float)v[1] * wf);
        }
        return;
    }

    int row = blockIdx.x * 4 + (tid >> 6);
    if (row >= nRows) return;

    int cntRaw = counts[row];
    int cnt = cntRaw > CAP ? CAP : cntRaw;

    int sr = 0; float wv = 0.f;
    if (lane < cnt) {
        int2 pk = slots2[(size_t)row * CAP + lane];
        sr = pk.x;
        wv = __int_as_float(pk.y);
    }

    float2* ap = (float2*)(agg + (size_t)row * DDIM) + lane;
    float2 acc0 = {0.f, 0.f}, acc1 = {0.f, 0.f};

    const bf16x2* fb = (const bf16x2*)gsrc;
    int i = 0;
    for (; i + 4 <= cnt; i += 4) {
        int   a0 = __shfl(sr, i),     a1 = __shfl(sr, i + 1);
        int   a2 = __shfl(sr, i + 2), a3 = __shfl(sr, i + 3);
        float w0 = __shfl(wv, i),     w1 = __shfl(wv, i + 1);
        float w2 = __shfl(wv, i + 2), w3 = __shfl(wv, i + 3);
        bf16x2 v0 = fb[(size_t)a0 * 64 + lane];
        bf16x2 v1 = fb[(size_t)a1 * 64 + lane];
        bf16x2 v2 = fb[(size_t)a2 * 64 + lane];
        bf16x2 v3 = fb[(size_t)a3 * 64 + lane];
        acc0.x += (float)v0[0] * w0; acc0.y += (float)v0[1] * w0;
        acc1.x += (float)v1[0] * w1; acc1.y += (float)v1[1] * w1;
        acc0.x += (float)v2[0] * w2; acc0.y += (float)v2[1] * w2;
        acc1.x += (float)v3[0] * w3; acc1.y += (float)v3[1] * w3;
    }
    for (; i < cnt; ++i) {
        int   a0 = __shfl(sr, i);
        float w0 = __shfl(wv, i);
        bf16x2 v0 = fb[(size_t)a0 * 64 + lane];
        acc0.x += (float)v0[0] * w0; acc0.y += (float)v0[1] * w0;
    }
    acc0.x += acc1.x; acc0.y += acc1.y;
    if (cntRaw > CAP) {                      // row pre-zeroed; atomics only
        unsafeAtomicAdd(&ap->x, acc0.x);
        unsafeAtomicAdd(&ap->y, acc0.y);
    } else {
        *ap = acc0;
    }
}

// ---------------- register-weight fused MLP (Tier A) ------------------------
// Weights live in VGPRs (32 x bf16x8 per lane per matrix, loaded from the
// L2-hot prepped frags). LDS holds only the h1 transpose tile; each wave
// touches ONLY its own 16-row stripe -> no __syncthreads needed except one
// before the cooperative hout store. Optionally zeroes zc[0..zn) (fused
// counts reset for the next stage).
template <bool RESIDUAL, bool HOUT>
__global__ __launch_bounds__(256) void mlp_reg(
    const void* __restrict__ feat, const float* __restrict__ agg,
    const void* __restrict__ b1, const void* __restrict__ b2,
    const void* __restrict__ epsp, float* __restrict__ out, int N,
    const int* __restrict__ flags, int fiFeat, int fiB1, int fiB2, int fiEps,
    const __bf16* __restrict__ pW1, const __bf16* __restrict__ pW2,
    __bf16* __restrict__ hout, int* __restrict__ zc, int zn)
{
    __shared__ alignas(16) __bf16 h1t[64 * 136];    // 17 KB, per-wave stripes

    const int tid  = threadIdx.x;
    if (zc) {
        int gi = blockIdx.x * 256 + tid;
        if (gi < zn) zc[gi] = 0;
    }

    const bool fF  = flags[fiFeat] != 0;
    const bool fB1 = flags[fiB1] != 0;
    const bool fB2 = flags[fiB2] != 0;
    const bool fE  = flags[fiEps] != 0;

    const int lane = tid & 63;
    const int wave = tid >> 6;
    const int quad = lane >> 4;
    const int r    = lane & 15;
    const int rowBase = blockIdx.x * 64 + wave * 16;

    // ---- W1 B-frags into registers (coalesced: 64 lanes x 16B contiguous)
    const bf16x8* pw1v = (const bf16x8*)pW1;
    bf16x8 w1f[32];
#pragma unroll
    for (int i = 0; i < 32; ++i) w1f[i] = pw1v[i * 64 + lane];

    float bias1[8];
#pragma unroll
    for (int ct = 0; ct < 8; ++ct) bias1[ct] = ldf(b1, ct * 16 + r, fB1);
    const float eps1 = 1.f + ldf(epsp, 0, fE);

    // ---- A-fragments for layer 1: x[rowBase+r][k], k = kk*32 + quad*8 + j
    bf16x8 a[4];
    {
        int rowA = rowBase + r;
        if (rowA < N) {
            size_t fb = (size_t)rowA * DDIM + quad * 8;
            const f32x4* gp = (const f32x4*)(agg + fb);
            if (fF) {
                const f32x4* fp = (const f32x4*)((const float*)feat + fb);
#pragma unroll
                for (int kk = 0; kk < 4; ++kk) {
                    f32x4 f0 = fp[kk * 8], f1 = fp[kk * 8 + 1];
                    f32x4 g0 = gp[kk * 8], g1 = gp[kk * 8 + 1];
                    bf16x8 av;
#pragma unroll
                    for (int j = 0; j < 4; ++j) {
                        av[j]     = (__bf16)(f0[j] * eps1 + g0[j]);
                        av[j + 4] = (__bf16)(f1[j] * eps1 + g1[j]);
                    }
                    a[kk] = av;
                }
            } else {
                const bf16x8* fp = (const bf16x8*)((const bf16_t*)feat + fb);
#pragma unroll
                for (int kk = 0; kk < 4; ++kk) {
                    bf16x8 fv = fp[kk * 4];
                    f32x4 g0 = gp[kk * 8], g1 = gp[kk * 8 + 1];
                    bf16x8 av;
#pragma unroll
                    for (int j = 0; j < 4; ++j) {
                        av[j]     = (__bf16)((float)fv[j]     * eps1 + g0[j]);
                        av[j + 4] = (__bf16)((float)fv[j + 4] * eps1 + g1[j]);
                    }
                    a[kk] = av;
                }
            }
        } else {
#pragma unroll
            for (int kk = 0; kk < 4; ++kk)
#pragma unroll
                for (int j = 0; j < 8; ++j) a[kk][j] = (__bf16)0.f;
        }
    }

    // ---- layer 1 MFMAs -> h1 stripe (own wave's rows only, no sync needed)
#pragma unroll
    for (int ct = 0; ct < 8; ++ct) {
        f32x4 acc = {0.f, 0.f, 0.f, 0.f};
#pragma unroll
        for (int kk = 0; kk < 4; ++kk)
            acc = __builtin_amdgcn_mfma_f32_16x16x32_bf16(
                a[kk], w1f[ct * 4 + kk], acc, 0, 0, 0);
#pragma unroll
        for (int gg = 0; gg < 4; ++gg)   // D: m = quad*4+gg, n = ct*16+r
            h1t[(wave * 16 + quad * 4 + gg) * 136 + ct * 16 + r] =
                (__bf16)lrelu(acc[gg] + bias1[ct]);
    }

    // ---- a2 from own stripe (intra-wave lgkmcnt ordering suffices)
    bf16x8 a2[4];
#pragma unroll
    for (int kk = 0; kk < 4; ++kk)
        a2[kk] = *(const bf16x8*)&h1t[(wave * 16 + r) * 136 + kk * 32 + quad * 8];

    // ---- W2 B-frags into registers (w1f dead -> regs reused)
    const bf16x8* pw2v = (const bf16x8*)pW2;
    bf16x8 w2f[32];
#pragma unroll
    for (int i = 0; i < 32; ++i) w2f[i] = pw2v[i * 64 + lane];
    float bias2[8];
#pragma unroll
    for (int ct = 0; ct < 8; ++ct) bias2[ct] = ldf(b2, ct * 16 + r, fB2);

    // ---- layer 2 MFMAs -> out (+residual); HOUT: stage bf16 h in h1t
#pragma unroll
    for (int ct = 0; ct < 8; ++ct) {
        f32x4 acc = {0.f, 0.f, 0.f, 0.f};
#pragma unroll
        for (int kk = 0; kk < 4; ++kk)
            acc = __builtin_amdgcn_mfma_f32_16x16x32_bf16(
                a2[kk], w2f[ct * 4 + kk], acc, 0, 0, 0);
#pragma unroll
        for (int gg = 0; gg < 4; ++gg) {
            int row = rowBase + quad * 4 + gg;
            float v = lrelu(acc[gg] + bias2[ct]);
            if (HOUT)
                h1t[(wave * 16 + quad * 4 + gg) * 136 + ct * 16 + r] = (__bf16)v;
            if (row < N) {
                int col = ct * 16 + r;
                if (RESIDUAL) v += ldf(feat, (size_t)row * DDIM + col, fF);
                out[(size_t)row * DDIM + col] = v;
            }
        }
    }

    // ---- cooperative coalesced hout store (bf16x8 per lane)
    if (HOUT) {
        __syncthreads();
        const int blockBase = blockIdx.x * 64;
#pragma unroll
        for (int c = 0; c < 4; ++c) {
            int chunk = tid + c * 256;            // 1024 chunks: 64 rows x 16
            int row = chunk >> 4;
            int k   = (chunk & 15) * 8;
            if (blockBase + row < N) {
                bf16x8 v = *(const bf16x8*)&h1t[row * 136 + k];
                *(bf16x8*)&hout[(size_t)(blockBase + row) * DDIM + k] = v;
            }
        }
    }
}

// ======================= Tier-B / legacy kernels (proven) ===================
__global__ __launch_bounds__(256) void fill_slots(
    const int* __restrict__ dst, int nE, int* __restrict__ counts,
    int* __restrict__ slots, int* __restrict__ ovCount, int* __restrict__ ovList,
    const void* __restrict__ feat, const int* __restrict__ srcArr,
    const void* __restrict__ wArr, float* __restrict__ agg,
    const int* __restrict__ flags, int fiFeat, int fiW)
{
    int e = blockIdx.x * 256 + threadIdx.x;
    if (e >= nE) return;
    int d = dst[e];
    int pos = atomicAdd(&counts[d], 1);
    if (pos < CAP) {
        slots[(size_t)d * CAP + pos] = e;
    } else if (ovList) {
        int k = atomicAdd(ovCount, 1);
        ovList[k] = e;
    } else {
        const bool fF = dtf(flags, fiFeat);
        const bool fW = dtf(flags, fiW);
        int s = srcArr[e];
        float wf = ldf(wArr, e, fW);
        for (int c = 0; c < DDIM; ++c)
            unsafeAtomicAdd(&agg[(size_t)d * DDIM + c],
                            ldf(feat, (size_t)s * DDIM + c, fF) * wf);
    }
}

__global__ __launch_bounds__(256) void scatter_overflow(
    const void* __restrict__ feat, const int* __restrict__ srcArr,
    const int* __restrict__ dstArr, const void* __restrict__ wArr,
    const int* __restrict__ ovList, const int* __restrict__ ovCount,
    float* __restrict__ agg, const int* __restrict__ flags, int fiFeat, int fiW)
{
    const bool fF = dtf(flags, fiFeat);
    const bool fW = dtf(flags, fiW);
    const int nOv = *ovCount;
    const int stride = gridDim.x * 256;
    for (int g = blockIdx.x * 256 + threadIdx.x; (g >> 5) < nOv; g += stride) {
        int idx = g >> 5;
        int e = ovList[idx];
        int c = (g & 31) << 2;
        int s = srcArr[e], d = dstArr[e];
        float wf = ldf(wArr, e, fW);
        size_t base = (size_t)s * DDIM + c;
        float* ap = agg + (size_t)d * DDIM + c;
        unsafeAtomicAdd(ap + 0, ldf(feat, base + 0, fF) * wf);
        unsafeAtomicAdd(ap + 1, ldf(feat, base + 1, fF) * wf);
        unsafeAtomicAdd(ap + 2, ldf(feat, base + 2, fF) * wf);
        unsafeAtomicAdd(ap + 3, ldf(feat, base + 3, fF) * wf);
    }
}

template <bool ZINIT>
__global__ __launch_bounds__(256) void segsum(
    const void* __restrict__ feat, const int* __restrict__ srcArr,
    const void* __restrict__ wArr, const int* __restrict__ counts,
    const int* __restrict__ slots, float* __restrict__ agg, int nRows,
    const int* __restrict__ flags, int fiFeat, int fiW)
{
    const bool fF = dtf(flags, fiFeat);
    const bool fW = dtf(flags, fiW);
    int row = blockIdx.x * 4 + (threadIdx.x >> 6);
    if (row >= nRows) return;
    int lane = threadIdx.x & 63;

    int cnt = counts[row]; if (cnt > CAP) cnt = CAP;

    int sr = 0; float wv = 0.f;
    if (lane < cnt) {
        int e = slots[(size_t)row * CAP + lane];
        sr = srcArr[e];
        wv = ldf(wArr, e, fW);
    }

    float2* ap = (float2*)(agg + (size_t)row * DDIM) + lane;
    float2 acc0 = {0.f, 0.f}, acc1 = {0.f, 0.f};
    if (!ZINIT) acc0 = *ap;

    if (fF) {
        const float2* fb = (const float2*)feat;
        int i = 0;
        for (; i + 4 <= cnt; i += 4) {
            int   a0 = __shfl(sr, i),     a1 = __shfl(sr, i + 1);
            int   a2 = __shfl(sr, i + 2), a3 = __shfl(sr, i + 3);
            float w0 = __shfl(wv, i),     w1 = __shfl(wv, i + 1);
            float w2 = __shfl(wv, i + 2), w3 = __shfl(wv, i + 3);
            float2 v0 = fb[(size_t)a0 * 64 + lane];
            float2 v1 = fb[(size_t)a1 * 64 + lane];
            float2 v2 = fb[(size_t)a2 * 64 + lane];
            float2 v3 = fb[(size_t)a3 * 64 + lane];
            acc0.x += v0.x * w0; acc0.y += v0.y * w0;
            acc1.x += v1.x * w1; acc1.y += v1.y * w1;
            acc0.x += v2.x * w2; acc0.y += v2.y * w2;
            acc1.x += v3.x * w3; acc1.y += v3.y * w3;
        }
        for (; i < cnt; ++i) {
            int   a0 = __shfl(sr, i);
            float w0 = __shfl(wv, i);
            float2 v0 = fb[(size_t)a0 * 64 + lane];
            acc0.x += v0.x * w0; acc0.y += v0.y * w0;
        }
    } else {
        const bf16x2* fb = (const bf16x2*)feat;
        int i = 0;
        for (; i + 4 <= cnt; i += 4) {
            int   a0 = __shfl(sr, i),     a1 = __shfl(sr, i + 1);
            int   a2 = __shfl(sr, i + 2), a3 = __shfl(sr, i + 3);
            float w0 = __shfl(wv, i),     w1 = __shfl(wv, i + 1);
            float w2 = __shfl(wv, i + 2), w3 = __shfl(wv, i + 3);
            bf16x2 v0 = fb[(size_t)a0 * 64 + lane];
            bf16x2 v1 = fb[(size_t)a1 * 64 + lane];
            bf16x2 v2 = fb[(size_t)a2 * 64 + lane];
            bf16x2 v3 = fb[(size_t)a3 * 64 + lane];
            acc0.x += (float)v0[0] * w0; acc0.y += (float)v0[1] * w0;
            acc1.x += (float)v1[0] * w1; acc1.y += (float)v1[1] * w1;
            acc0.x += (float)v2[0] * w2; acc0.y += (float)v2[1] * w2;
            acc1.x += (float)v3[0] * w3; acc1.y += (float)v3[1] * w3;
        }
        for (; i < cnt; ++i) {
            int   a0 = __shfl(sr, i);
            float w0 = __shfl(wv, i);
            bf16x2 v0 = fb[(size_t)a0 * 64 + lane];
            acc0.x += (float)v0[0] * w0; acc0.y += (float)v0[1] * w0;
        }
    }
    acc0.x += acc1.x; acc0.y += acc1.y;
    *ap = acc0;
}

__global__ __launch_bounds__(256) void scatter_any(
    const void* __restrict__ feat, const int* __restrict__ src,
    const int* __restrict__ dst, const void* __restrict__ w,
    float* __restrict__ agg, int nE,
    const int* __restrict__ flags, int fiFeat, int fiW)
{
    const bool fF = dtf(flags, fiFeat);
    const bool fW = dtf(flags, fiW);
    int g = blockIdx.x * 256 + threadIdx.x;
    int e = g >> 5;
    if (e >= nE) return;
    int c = (g & 31) << 2;
    int s = src[e], d = dst[e];
    float wf = ldf(w, e, fW);
    size_t base = (size_t)s * DDIM + c;
    float* ap = agg + (size_t)d * DDIM + c;
    unsafeAtomicAdd(ap + 0, ldf(feat, base + 0, fF) * wf);
    unsafeAtomicAdd(ap + 1, ldf(feat, base + 1, fF) * wf);
    unsafeAtomicAdd(ap + 2, ldf(feat, base + 2, fF) * wf);
    unsafeAtomicAdd(ap + 3, ldf(feat, base + 3, fF) * wf);
}

__global__ __launch_bounds__(256) void residual_add(
    float* __restrict__ out, const void* __restrict__ feat, int n4,
    const int* __restrict__ flags, int fiFeat)
{
    const bool fF = flags[fiFeat] != 0;
    int i = blockIdx.x * 256 + threadIdx.x;
    if (i >= n4) return;
    f32x4 o = ((const f32x4*)out)[i];
    f32x4 r;
#pragma unroll
    for (int j = 0; j < 4; ++j) r[j] = o[j] + ldf(feat, (size_t)i * 4 + j, fF);
    ((f32x4*)out)[i] = r;
}

__device__ __forceinline__ void fill_wfrag(const void* __restrict__ W, bool f,
                                           __bf16* wf, int tid)
{
#pragma unroll
    for (int i = 0; i < 8; ++i) {
        int sIdx  = tid + i * 256;
        int l     = sIdx & 63;
        int combo = sIdx >> 6;
        int ct = combo >> 2, kk = combo & 3;
        int col  = ct * 16 + (l & 15);
        int krow = kk * 32 + (l >> 4) * 8;
        __bf16* dp = wf + (size_t)sIdx * 8;
#pragma unroll
        for (int j = 0; j < 8; ++j)
            dp[j] = (__bf16)ldf(W, (size_t)(krow + j) * DDIM + col, f);
    }
}

__device__ __forceinline__ void copy_wfrag(const __bf16* __restrict__ prep,
                                           __bf16* wf, int tid)
{
    const f32x4* sp = (const f32x4*)prep;
    f32x4* dp = (f32x4*)wf;
#pragma unroll
    for (int i = 0; i < 8; ++i) dp[tid + i * 256] = sp[tid + i * 256];
}

template <bool RESIDUAL, bool PREP>
__global__ __launch_bounds__(256) void mlp_kernel(
    const void* __restrict__ feat, const float* __restrict__ agg,
    const void* __restrict__ W1, const void* __restrict__ b1,
    const void* __restrict__ W2, const void* __restrict__ b2,
    const void* __restrict__ epsp, float* __restrict__ out, int N,
    const int* __restrict__ flags,
    int fiFeat, int fiW1, int fiB1, int fiW2, int fiB2, int fiEps,
    const __bf16* __restrict__ pW1, const __bf16* __restrict__ pW2)
{
    __shared__ alignas(16) __bf16 wf[32 * 64 * 8];
    __shared__ alignas(16) __bf16 h1t[64 * 136];

    const bool fF  = flags[fiFeat] != 0;
    const bool fB1 = flags[fiB1] != 0;
    const bool fB2 = flags[fiB2] != 0;
    const bool fE  = flags[fiEps] != 0;

    const int tid  = threadIdx.x;
    const int lane = tid & 63;
    const int wave = tid >> 6;
    const int quad = lane >> 4;
    const int r    = lane & 15;

    if (PREP) copy_wfrag(pW1, wf, tid);
    else      fill_wfrag(W1, flags[fiW1] != 0, wf, tid);

    const float eps1 = 1.f + ldf(epsp, 0, fE);
    const int rowBase = blockIdx.x * 64 + wave * 16;

    bf16x8 a[4];
    {
        int rowA = rowBase + r;
        if (rowA < N) {
            size_t fb = (size_t)rowA * DDIM + quad * 8;
            const f32x4* gp = (const f32x4*)(agg + fb);
            if (fF) {
                const f32x4* fp = (const f32x4*)((const float*)feat + fb);
#pragma unroll
                for (int kk = 0; kk < 4; ++kk) {
                    f32x4 f0 = fp[kk * 8], f1 = fp[kk * 8 + 1];
                    f32x4 g0 = gp[kk * 8], g1 = gp[kk * 8 + 1];
                    bf16x8 av;
#pragma unroll
                    for (int j = 0; j < 4; ++j) {
                        av[j]     = (__bf16)(f0[j] * eps1 + g0[j]);
                        av[j + 4] = (__bf16)(f1[j] * eps1 + g1[j]);
                    }
                    a[kk] = av;
                }
            } else {
                const bf16x8* fp = (const bf16x8*)((const bf16_t*)feat + fb);
#pragma unroll
                for (int kk = 0; kk < 4; ++kk) {
                    bf16x8 fv = fp[kk * 4];
                    f32x4 g0 = gp[kk * 8], g1 = gp[kk * 8 + 1];
                    bf16x8 av;
#pragma unroll
                    for (int j = 0; j < 4; ++j) {
                        av[j]     = (__bf16)((float)fv[j]     * eps1 + g0[j]);
                        av[j + 4] = (__bf16)((float)fv[j + 4] * eps1 + g1[j]);
                    }
                    a[kk] = av;
                }
            }
        } else {
#pragma unroll
            for (int kk = 0; kk < 4; ++kk)
#pragma unroll
                for (int j = 0; j < 8; ++j) a[kk][j] = (__bf16)0.f;
        }
    }

    __syncthreads();

    const bf16x8* wv = (const bf16x8*)wf;
#pragma unroll
    for (int ct = 0; ct < 8; ++ct) {
        f32x4 acc = {0.f, 0.f, 0.f, 0.f};
#pragma unroll
        for (int kk = 0; kk < 4; ++kk)
            acc = __builtin_amdgcn_mfma_f32_16x16x32_bf16(
                a[kk], wv[(ct * 4 + kk) * 64 + lane], acc, 0, 0, 0);
        float bias = ldf(b1, ct * 16 + r, fB1);
#pragma unroll
        for (int gg = 0; gg < 4; ++gg)
            h1t[(wave * 16 + quad * 4 + gg) * 136 + ct * 16 + r] =
                (__bf16)lrelu(acc[gg] + bias);
    }
    __syncthreads();

    bf16x8 a2[4];
#pragma unroll
    for (int kk = 0; kk < 4; ++kk)
        a2[kk] = *(const bf16x8*)&h1t[(wave * 16 + r) * 136 + kk * 32 + quad * 8];

    if (PREP) copy_wfrag(pW2, wf, tid);
    else      fill_wfrag(W2, flags[fiW2] != 0, wf, tid);
    __syncthreads();

#pragma unroll
    for (int ct = 0; ct < 8; ++ct) {
        f32x4 acc = {0.f, 0.f, 0.f, 0.f};
#pragma unroll
        for (int kk = 0; kk < 4; ++kk)
            acc = __builtin_amdgcn_mfma_f32_16x16x32_bf16(
                a2[kk], wv[(ct * 4 + kk) * 64 + lane], acc, 0, 0, 0);
        float bias = ldf(b2, ct * 16 + r, fB2);
#pragma unroll
        for (int gg = 0; gg < 4; ++gg) {
            int row = rowBase + quad * 4 + gg;
            if (row < N) {
                int col = ct * 16 + r;
                float v = lrelu(acc[gg] + bias);
                if (RESIDUAL) v += ldf(feat, (size_t)row * DDIM + col, fF);
                out[(size_t)row * DDIM + col] = v;
            }
        }
    }
}

extern "C" void kernel_launch(void* const* d_in, const int* in_sizes, int n_in,
                              void* d_out, int out_size, void* d_ws, size_t ws_size,
                              hipStream_t stream)
{
    const int* src_c2r = (const int*)d_in[2];
    const int* dst_c2r = (const int*)d_in[3];
    const int* src_r2c = (const int*)d_in[5];
    const int* dst_r2c = (const int*)d_in[6];
    const int nE = in_sizes[2];

    // ---- workspace layout ----
    char* wsb = (char*)d_ws;
    int*    flags  = (int*)wsb;
    __bf16* wfprep = (__bf16*)(wsb + 128);
    int*    counts = (int*)(wsb + 128 + 131072);
    int*    ovCnt  = counts + NROW;
    size_t  ofs    = 128 + 131072 + ((size_t)NROW + 8) * 4;
    ofs = (ofs + 15) & ~(size_t)15;
    int2*   slots2 = (int2*)(wsb + ofs);                 // Tier A packed slots
    int*    slots  = (int*)(wsb + ofs);                  // Tier B edge-id slots
    size_t  ofsOvA = ofs + (size_t)NROW * CAP * 8;
    size_t  ofsOvB = ofs + (size_t)NROW * CAP * 4;
    int*    ovListA = (int*)(wsb + ofsOvA);
    int*    ovListB = (int*)(wsb + ofsOvB);
    size_t  ofsCb  = (ofsOvA + (size_t)nE * 4 + 15) & ~(size_t)15;
    __bf16* cbuf   = (__bf16*)(wsb + ofsCb);

    const size_t NEED_A  = ofsCb + (size_t)NROW * DDIM * 2;
    const size_t NEED_B  = ofsOvB + (size_t)nE * 4;
    const size_t NEED_B0 = ofsOvB;
    const bool tierA  = ws_size >= NEED_A;
    const bool tierB  = ws_size >= NEED_B;
    const bool tierB0 = ws_size >= NEED_B0;

    TensorTab T;
    for (int i = 0; i < 18; ++i) { T.p[i] = d_in[i]; T.n[i] = in_sizes[i]; }

    // OUTPUT IS F32. out_col half doubles as the f32 agg buffer.
    float* out_row = (float*)d_out;
    float* out_col = out_row + (size_t)NROW * DDIM;
    const size_t aggBytes = (size_t)NROW * DDIM * sizeof(float);

    const int eblocks  = (nE + 255) / 256;
    const int sblocks  = (nE * 32 + 255) / 256;
    const int mblocksR = (NROW + 63) / 64;
    const int mblocksC = (NCOL + 63) / 64;
    const int gblocksR = (NROW + 3) / 4;
    const int gblocksC = (NCOL + 3) / 4;
    const int cblocks  = (NCOL * DDIM / 8 + 255) / 256;
    const int zblocks  = ((NROW + 8) + 255) / 256;
    const int zn       = NROW + 8;

    detect_dtypes<<<18, 256, 0, stream>>>(T, flags);

    if (tierA) {
        WPtrs P;
        P.W[0] = d_in[8];  P.fi[0] = 8;
        P.W[1] = d_in[10]; P.fi[1] = 10;
        P.W[2] = d_in[12]; P.fi[2] = 12;
        P.W[3] = d_in[14]; P.fi[3] = 14;

        // ---- fused prep: convert feat_col->bf16 | zero counts | weight prep
        prep_all<<<cblocks + zblocks + 32, 256, 0, stream>>>(
            P, flags, wfprep, d_in[1], cbuf, NCOL * DDIM / 8, 1,
            counts, zn, cblocks, zblocks);

        // ---- stage 1: col -> row ----
        fill_slots_packed<<<eblocks, 256, 0, stream>>>(dst_c2r, src_c2r,
            d_in[4], nE, counts, slots2, ovCnt, ovListA, out_col, flags, 4);
        segsum_ov<<<gblocksR + 64, 256, 0, stream>>>(cbuf, counts, slots2,
            out_col, NROW, src_c2r, dst_c2r, d_in[4], ovListA, ovCnt,
            flags, 4, gblocksR);
        // fused: out_row = h+feat_row (f32), cbuf = h (bf16), counts zeroed
        mlp_reg<true, true><<<mblocksR, 256, 0, stream>>>(
            d_in[0], out_col, d_in[9], d_in[11], d_in[16],
            out_row, NROW, flags, 0, 9, 11, 16,
            wfprep + 0 * 16384, wfprep + 1 * 16384, cbuf, counts, zn);

        // ---- stage 2: row -> col ----
        fill_slots_packed<<<eblocks, 256, 0, stream>>>(dst_r2c, src_r2c,
            d_in[7], nE, counts, slots2, ovCnt, ovListA, out_col, flags, 7);
        segsum_ov<<<gblocksC + 64, 256, 0, stream>>>(cbuf, counts, slots2,
            out_col, NCOL, src_r2c, dst_r2c, d_in[7], ovListA, ovCnt,
            flags, 7, gblocksC);
        mlp_reg<true, false><<<mblocksC, 256, 0, stream>>>(
            d_in[1], out_col, d_in[13], d_in[15], d_in[17],
            out_col, NCOL, flags, 1, 13, 15, 17,
            wfprep + 2 * 16384, wfprep + 3 * 16384, nullptr, nullptr, 0);
    } else if (tierB0) {
        WPtrs P;
        P.W[0] = d_in[8];  P.fi[0] = 8;
        P.W[1] = d_in[10]; P.fi[1] = 10;
        P.W[2] = d_in[12]; P.fi[2] = 12;
        P.W[3] = d_in[14]; P.fi[3] = 14;
        prep_all<<<32, 256, 0, stream>>>(P, flags, wfprep,
            nullptr, nullptr, 0, -1, nullptr, 0, 0, 0);

        hipMemsetAsync(counts, 0, ((size_t)NROW + 8) * 4, stream);
        if (!tierB) hipMemsetAsync(out_col, 0, aggBytes, stream);
        fill_slots<<<eblocks, 256, 0, stream>>>(dst_c2r, nE, counts, slots,
            ovCnt, tierB ? ovListB : nullptr,
            d_in[1], src_c2r, d_in[4], out_col, flags, 1, 4);
        if (tierB) {
            segsum<true><<<gblocksR, 256, 0, stream>>>(d_in[1], src_c2r,
                d_in[4], counts, slots, out_col, NROW, flags, 1, 4);
            scatter_overflow<<<256, 256, 0, stream>>>(d_in[1], src_c2r,
                dst_c2r, d_in[4], ovListB, ovCnt, out_col, flags, 1, 4);
        } else {
            segsum<false><<<gblocksR, 256, 0, stream>>>(d_in[1], src_c2r,
                d_in[4], counts, slots, out_col, NROW, flags, 1, 4);
        }
        mlp_kernel<false, true><<<mblocksR, 256, 0, stream>>>(
            d_in[0], out_col, d_in[8], d_in[9], d_in[10], d_in[11], d_in[16],
            out_row, NROW, flags, 0, 8, 9, 10, 11, 16,
            wfprep + 0 * 16384, wfprep + 1 * 16384);

        hipMemsetAsync(counts, 0, ((size_t)NROW + 8) * 4, stream);
        if (!tierB) hipMemsetAsync(out_col, 0, aggBytes, stream);
        fill_slots<<<eblocks, 256, 0, stream>>>(dst_r2c, nE, counts, slots,
            ovCnt, tierB ? ovListB : nullptr,
            out_row, src_r2c, d_in[7], out_col, flags, -1, 7);
        if (tierB) {
            segsum<true><<<gblocksC, 256, 0, stream>>>(out_row, src_r2c,
                d_in[7], counts, slots, out_col, NCOL, flags, -1, 7);
            scatter_overflow<<<256, 256, 0, stream>>>(out_row, src_r2c,
                dst_r2c, d_in[7], ovListB, ovCnt, out_col, flags, -1, 7);
        } else {
            segsum<false><<<gblocksC, 256, 0, stream>>>(out_row, src_r2c,
                d_in[7], counts, slots, out_col, NCOL, flags, -1, 7);
        }
        residual_add<<<(NROW * DDIM / 4 + 255) / 256, 256, 0, stream>>>(
            out_row, d_in[0], NROW * DDIM / 4, flags, 0);
        mlp_kernel<true, true><<<mblocksC, 256, 0, stream>>>(
            d_in[1], out_col, d_in[12], d_in[13], d_in[14], d_in[15], d_in[17],
            out_col, NCOL, flags, 1, 12, 13, 14, 15, 17,
            wfprep + 2 * 16384, wfprep + 3 * 16384);
    } else {
        hipMemsetAsync(out_col, 0, aggBytes, stream);
        scatter_any<<<sblocks, 256, 0, stream>>>(d_in[1], src_c2r, dst_c2r,
            d_in[4], out_col, nE, flags, 1, 4);
        mlp_kernel<false, false><<<mblocksR, 256, 0, stream>>>(
            d_in[0], out_col, d_in[8], d_in[9], d_in[10], d_in[11], d_in[16],
            out_row, NROW, flags, 0, 8, 9, 10, 11, 16, nullptr, nullptr);

        hipMemsetAsync(out_col, 0, aggBytes, stream);
        scatter_any<<<sblocks, 256, 0, stream>>>(out_row, src_r2c, dst_r2c,
            d_in[7], out_col, nE, flags, -1, 7);
        residual_add<<<(NROW * DDIM / 4 + 255) / 256, 256, 0, stream>>>(
            out_row, d_in[0], NROW * DDIM / 4, flags, 0);
        mlp_kernel<true, false><<<mblocksC, 256, 0, stream>>>(
            d_in[1], out_col, d_in[12], d_in[13], d_in[14], d_in[15], d_in[17],
            out_col, NCOL, flags, 1, 12, 13, 14, 15, 17, nullptr, nullptr);
    }
}

// Round 5
// 326.197 us; speedup vs baseline: 1.2902x; 1.0423x over previous
//
#include <hip/hip_runtime.h>
#include <hip/hip_bf16.h>

#define NROW 50000
#define NCOL 50000
#define DDIM 128
#define CAP  32   // slots per destination row

typedef __bf16 bf16_t;
typedef __bf16 bf16x2 __attribute__((ext_vector_type(2)));
typedef __bf16 bf16x8 __attribute__((ext_vector_type(8)));
typedef float  f32x4  __attribute__((ext_vector_type(4)));

__device__ __forceinline__ float lrelu(float v) { return v >= 0.f ? v : 0.01f * v; }

__device__ __forceinline__ float ldf(const void* p, size_t i, bool f) {
    return f ? ((const float*)p)[i] : (float)((const bf16_t*)p)[i];
}

// fi: >=0 -> flags[fi]; -1 -> forced f32; -2 -> forced bf16
__device__ __forceinline__ bool dtf(const int* flags, int fi) {
    return (fi == -1) ? true : (fi == -2) ? false : (flags[fi] != 0);
}

// ---------------- D1: dtype detect (18 blocks) + zero counts ---------------
struct TensorTab { const void* p[18]; int n[18]; };

__global__ __launch_bounds__(256) void detect_zero(TensorTab T, int* flags,
                                                   int* z, int zn)
{
    const int tid = threadIdx.x;
    if (blockIdx.x >= 18) {                  // zero countsA|ovCntA|countsB|ovCntB
        int i = (blockIdx.x - 18) * 256 + tid;
        if (i < zn) z[i] = 0;
        return;
    }
    __shared__ int vb, vf;
    const int t = blockIdx.x;
    if (tid == 0) { vb = 0; vf = 0; }
    __syncthreads();
    const int n = T.n[t];
    const bool isFloatArr = (t != 2 && t != 3 && t != 5 && t != 6) && n >= 2;
    if (isFloatArr) {
        int nw = n / 2;
        int wi = (int)(((long long)tid * nw) >> 8);
        unsigned w = ((const unsigned*)T.p[t])[wi];
        unsigned low = w & 0xffffu;
        if (low) {
            int e = (int)((low >> 7) & 0xffu);
            if (e >= 90 && e <= 141) atomicAdd(&vb, 1);
            else                     atomicAdd(&vf, 1);
        }
    }
    __syncthreads();
    if (tid == 0) flags[t] = (isFloatArr && vf > vb) ? 1 : 0; // 1 = f32
}

// ---------------- shared fill routine (no agg touch) -----------------------
__device__ __forceinline__ void fill_edges(
    int e, const int* __restrict__ dst, const int* __restrict__ srcArr,
    const void* __restrict__ wArr, int nE, int* __restrict__ counts,
    int2* __restrict__ slots2, int* __restrict__ ovCnt,
    int* __restrict__ ovList, bool fW)
{
    if (e >= nE) return;
    int d = dst[e];
    int pos = atomicAdd(&counts[d], 1);
    if (pos < CAP) {
        int2 pk;
        pk.x = srcArr[e];
        pk.y = __float_as_int(ldf(wArr, e, fW));
        slots2[(size_t)d * CAP + pos] = pk;
    } else {
        int k = atomicAdd(ovCnt, 1);         // capacity == nE
        ovList[k] = e;
    }
}

// ---------------- D2: convert cbuf | weight prep | fillA (fused roles) ------
struct WPtrs { const void* W[4]; int fi[4]; };

__global__ __launch_bounds__(256) void prep_fill(
    WPtrs P, const int* __restrict__ flags, __bf16* __restrict__ wfp,
    const void* __restrict__ feat, __bf16* __restrict__ cbuf, int n8,
    int fiFeat, int cblocks,
    const int* __restrict__ f_dst, const int* __restrict__ f_src,
    const void* __restrict__ f_w, int f_nE, int* __restrict__ f_counts,
    int2* __restrict__ f_slots2, int* __restrict__ f_ovCnt,
    int* __restrict__ f_ovList, int f_fiW)
{
    const int b = blockIdx.x;
    const int tid = threadIdx.x;
    if (b < cblocks) {                       // convert feat table to bf16
        int i = b * 256 + tid;
        if (i >= n8) return;
        const bool f = dtf(flags, fiFeat);
        bf16x8 v;
        if (f) {
            f32x4 a = ((const f32x4*)feat)[i * 2];
            f32x4 c = ((const f32x4*)feat)[i * 2 + 1];
#pragma unroll
            for (int j = 0; j < 4; ++j) { v[j] = (__bf16)a[j]; v[j + 4] = (__bf16)c[j]; }
        } else {
            v = ((const bf16x8*)feat)[i];
        }
        ((bf16x8*)cbuf)[i] = v;
    } else if (b < cblocks + 32) {           // weight B-frag prep (4 matrices)
        int slot = (b - cblocks) * 256 + tid;   // 4 * 2048
        if (slot >= 4 * 2048) return;
        int m = slot >> 11, sIdx = slot & 2047;
        bool f = flags[P.fi[m]] != 0;
        int l = sIdx & 63, combo = sIdx >> 6;
        int ct = combo >> 2, kk = combo & 3;
        int col  = ct * 16 + (l & 15);
        int krow = kk * 32 + (l >> 4) * 8;
        bf16x8 v;
#pragma unroll
        for (int j = 0; j < 8; ++j)
            v[j] = (__bf16)ldf(P.W[m], (size_t)(krow + j) * DDIM + col, f);
        ((bf16x8*)wfp)[slot] = v;
    } else {                                 // fill stage-1 buckets
        int e = (b - cblocks - 32) * 256 + tid;
        fill_edges(e, f_dst, f_src, f_w, f_nE, f_counts, f_slots2,
                   f_ovCnt, f_ovList, dtf(flags, f_fiW));
    }
}

// ---------------- segment sum with inline overflow scan ---------------------
// One wave per row; lanes 0..31 read packed (src,w) in one 8B load; 4-deep
// gather pipeline. Rows with cnt > CAP scan the (rare, usually empty)
// overflow list for their own edges -> exact, no atomics, plain store.
__global__ __launch_bounds__(256) void segsum_scan(
    const __bf16* __restrict__ gsrc, const int* __restrict__ counts,
    const int2* __restrict__ slots2, float* __restrict__ agg, int nRows,
    const int* __restrict__ srcArr, const int* __restrict__ dstArr,
    const void* __restrict__ wArr, const int* __restrict__ ovList,
    const int* __restrict__ ovCount, const int* __restrict__ flags, int fiW)
{
    int row = blockIdx.x * 4 + (threadIdx.x >> 6);
    if (row >= nRows) return;
    int lane = threadIdx.x & 63;

    int cntRaw = counts[row];
    int cnt = cntRaw > CAP ? CAP : cntRaw;

    int sr = 0; float wv = 0.f;
    if (lane < cnt) {
        int2 pk = slots2[(size_t)row * CAP + lane];
        sr = pk.x;
        wv = __int_as_float(pk.y);
    }

    float2* ap = (float2*)(agg + (size_t)row * DDIM) + lane;
    float2 acc0 = {0.f, 0.f}, acc1 = {0.f, 0.f};

    const bf16x2* fb = (const bf16x2*)gsrc;
    int i = 0;
    for (; i + 4 <= cnt; i += 4) {
        int   a0 = __shfl(sr, i),     a1 = __shfl(sr, i + 1);
        int   a2 = __shfl(sr, i + 2), a3 = __shfl(sr, i + 3);
        float w0 = __shfl(wv, i),     w1 = __shfl(wv, i + 1);
        float w2 = __shfl(wv, i + 2), w3 = __shfl(wv, i + 3);
        bf16x2 v0 = fb[(size_t)a0 * 64 + lane];
        bf16x2 v1 = fb[(size_t)a1 * 64 + lane];
        bf16x2 v2 = fb[(size_t)a2 * 64 + lane];
        bf16x2 v3 = fb[(size_t)a3 * 64 + lane];
        acc0.x += (float)v0[0] * w0; acc0.y += (float)v0[1] * w0;
        acc1.x += (float)v1[0] * w1; acc1.y += (float)v1[1] * w1;
        acc0.x += (float)v2[0] * w2; acc0.y += (float)v2[1] * w2;
        acc1.x += (float)v3[0] * w3; acc1.y += (float)v3[1] * w3;
    }
    for (; i < cnt; ++i) {
        int   a0 = __shfl(sr, i);
        float w0 = __shfl(wv, i);
        bf16x2 v0 = fb[(size_t)a0 * 64 + lane];
        acc0.x += (float)v0[0] * w0; acc0.y += (float)v0[1] * w0;
    }
    if (cntRaw > CAP) {                      // rare: pick own edges from ovList
        const bool fW = dtf(flags, fiW);
        int nOv = *ovCount;
        for (int k = 0; k < nOv; ++k) {
            int e = ovList[k];
            if (dstArr[e] == row) {
                int s = srcArr[e];
                float wf = ldf(wArr, e, fW);
                bf16x2 v = fb[(size_t)s * 64 + lane];
                acc0.x += (float)v[0] * wf; acc0.y += (float)v[1] * wf;
            }
        }
    }
    acc0.x += acc1.x; acc0.y += acc1.y;
    *ap = acc0;
}

// ---------------- register-weight fused MLP (+optional fused fill role) -----
template <bool RESIDUAL, bool HOUT>
__global__ __launch_bounds__(256) void mlp_reg(
    const void* __restrict__ feat, const float* __restrict__ agg,
    const void* __restrict__ b1, const void* __restrict__ b2,
    const void* __restrict__ epsp, float* __restrict__ out, int N,
    const int* __restrict__ flags, int fiFeat, int fiB1, int fiB2, int fiEps,
    const __bf16* __restrict__ pW1, const __bf16* __restrict__ pW2,
    __bf16* __restrict__ hout, int* __restrict__ zc, int zn,
    int mblocks,
    const int* __restrict__ f_dst, const int* __restrict__ f_src,
    const void* __restrict__ f_w, int f_nE, int* __restrict__ f_counts,
    int2* __restrict__ f_slots2, int* __restrict__ f_ovCnt,
    int* __restrict__ f_ovList, int f_fiW)
{
    __shared__ alignas(16) __bf16 h1t[64 * 136];    // 17 KB, per-wave stripes

    const int tid  = threadIdx.x;
    if (f_dst && (int)blockIdx.x >= mblocks) {      // ---- fused fill role ----
        int e = ((int)blockIdx.x - mblocks) * 256 + tid;
        fill_edges(e, f_dst, f_src, f_w, f_nE, f_counts, f_slots2,
                   f_ovCnt, f_ovList, dtf(flags, f_fiW));
        return;
    }
    if (zc) {
        int gi = blockIdx.x * 256 + tid;
        if (gi < zn) zc[gi] = 0;
    }

    const bool fF  = flags[fiFeat] != 0;
    const bool fB1 = flags[fiB1] != 0;
    const bool fB2 = flags[fiB2] != 0;
    const bool fE  = flags[fiEps] != 0;

    const int lane = tid & 63;
    const int wave = tid >> 6;
    const int quad = lane >> 4;
    const int r    = lane & 15;
    const int rowBase = blockIdx.x * 64 + wave * 16;

    const bf16x8* pw1v = (const bf16x8*)pW1;
    bf16x8 w1f[32];
#pragma unroll
    for (int i = 0; i < 32; ++i) w1f[i] = pw1v[i * 64 + lane];

    float bias1[8];
#pragma unroll
    for (int ct = 0; ct < 8; ++ct) bias1[ct] = ldf(b1, ct * 16 + r, fB1);
    const float eps1 = 1.f + ldf(epsp, 0, fE);

    bf16x8 a[4];
    {
        int rowA = rowBase + r;
        if (rowA < N) {
            size_t fb = (size_t)rowA * DDIM + quad * 8;
            const f32x4* gp = (const f32x4*)(agg + fb);
            if (fF) {
                const f32x4* fp = (const f32x4*)((const float*)feat + fb);
#pragma unroll
                for (int kk = 0; kk < 4; ++kk) {
                    f32x4 f0 = fp[kk * 8], f1 = fp[kk * 8 + 1];
                    f32x4 g0 = gp[kk * 8], g1 = gp[kk * 8 + 1];
                    bf16x8 av;
#pragma unroll
                    for (int j = 0; j < 4; ++j) {
                        av[j]     = (__bf16)(f0[j] * eps1 + g0[j]);
                        av[j + 4] = (__bf16)(f1[j] * eps1 + g1[j]);
                    }
                    a[kk] = av;
                }
            } else {
                const bf16x8* fp = (const bf16x8*)((const bf16_t*)feat + fb);
#pragma unroll
                for (int kk = 0; kk < 4; ++kk) {
                    bf16x8 fv = fp[kk * 4];
                    f32x4 g0 = gp[kk * 8], g1 = gp[kk * 8 + 1];
                    bf16x8 av;
#pragma unroll
                    for (int j = 0; j < 4; ++j) {
                        av[j]     = (__bf16)((float)fv[j]     * eps1 + g0[j]);
                        av[j + 4] = (__bf16)((float)fv[j + 4] * eps1 + g1[j]);
                    }
                    a[kk] = av;
                }
            }
        } else {
#pragma unroll
            for (int kk = 0; kk < 4; ++kk)
#pragma unroll
                for (int j = 0; j < 8; ++j) a[kk][j] = (__bf16)0.f;
        }
    }

#pragma unroll
    for (int ct = 0; ct < 8; ++ct) {
        f32x4 acc = {0.f, 0.f, 0.f, 0.f};
#pragma unroll
        for (int kk = 0; kk < 4; ++kk)
            acc = __builtin_amdgcn_mfma_f32_16x16x32_bf16(
                a[kk], w1f[ct * 4 + kk], acc, 0, 0, 0);
#pragma unroll
        for (int gg = 0; gg < 4; ++gg)
            h1t[(wave * 16 + quad * 4 + gg) * 136 + ct * 16 + r] =
                (__bf16)lrelu(acc[gg] + bias1[ct]);
    }

    bf16x8 a2[4];
#pragma unroll
    for (int kk = 0; kk < 4; ++kk)
        a2[kk] = *(const bf16x8*)&h1t[(wave * 16 + r) * 136 + kk * 32 + quad * 8];

    const bf16x8* pw2v = (const bf16x8*)pW2;
    bf16x8 w2f[32];
#pragma unroll
    for (int i = 0; i < 32; ++i) w2f[i] = pw2v[i * 64 + lane];
    float bias2[8];
#pragma unroll
    for (int ct = 0; ct < 8; ++ct) bias2[ct] = ldf(b2, ct * 16 + r, fB2);

#pragma unroll
    for (int ct = 0; ct < 8; ++ct) {
        f32x4 acc = {0.f, 0.f, 0.f, 0.f};
#pragma unroll
        for (int kk = 0; kk < 4; ++kk)
            acc = __builtin_amdgcn_mfma_f32_16x16x32_bf16(
                a2[kk], w2f[ct * 4 + kk], acc, 0, 0, 0);
#pragma unroll
        for (int gg = 0; gg < 4; ++gg) {
            int row = rowBase + quad * 4 + gg;
            float v = lrelu(acc[gg] + bias2[ct]);
            if (HOUT)
                h1t[(wave * 16 + quad * 4 + gg) * 136 + ct * 16 + r] = (__bf16)v;
            if (row < N) {
                int col = ct * 16 + r;
                if (RESIDUAL) v += ldf(feat, (size_t)row * DDIM + col, fF);
                out[(size_t)row * DDIM + col] = v;
            }
        }
    }

    if (HOUT) {
        __syncthreads();
        const int blockBase = blockIdx.x * 64;
#pragma unroll
        for (int c = 0; c < 4; ++c) {
            int chunk = tid + c * 256;
            int row = chunk >> 4;
            int k   = (chunk & 15) * 8;
            if (blockBase + row < N) {
                bf16x8 v = *(const bf16x8*)&h1t[row * 136 + k];
                *(bf16x8*)&hout[(size_t)(blockBase + row) * DDIM + k] = v;
            }
        }
    }
}

// =================== round-4 tier-A fallback kernels (proven) ===============
__global__ __launch_bounds__(256) void prep_all(
    WPtrs P, const int* __restrict__ flags, __bf16* __restrict__ wfp,
    const void* __restrict__ feat, __bf16* __restrict__ cbuf, int n8, int fiFeat,
    int* __restrict__ zc, int zn, int cblocks, int zblocks)
{
    const int b = blockIdx.x;
    const int tid = threadIdx.x;
    if (b < cblocks) {
        int i = b * 256 + tid;
        if (i >= n8) return;
        const bool f = dtf(flags, fiFeat);
        bf16x8 v;
        if (f) {
            f32x4 a = ((const f32x4*)feat)[i * 2];
            f32x4 c = ((const f32x4*)feat)[i * 2 + 1];
#pragma unroll
            for (int j = 0; j < 4; ++j) { v[j] = (__bf16)a[j]; v[j + 4] = (__bf16)c[j]; }
        } else {
            v = ((const bf16x8*)feat)[i];
        }
        ((bf16x8*)cbuf)[i] = v;
    } else if (b < cblocks + zblocks) {
        int i = (b - cblocks) * 256 + tid;
        if (i < zn) zc[i] = 0;
    } else {
        int slot = (b - cblocks - zblocks) * 256 + tid;
        if (slot >= 4 * 2048) return;
        int m = slot >> 11, sIdx = slot & 2047;
        bool f = flags[P.fi[m]] != 0;
        int l = sIdx & 63, combo = sIdx >> 6;
        int ct = combo >> 2, kk = combo & 3;
        int col  = ct * 16 + (l & 15);
        int krow = kk * 32 + (l >> 4) * 8;
        bf16x8 v;
#pragma unroll
        for (int j = 0; j < 8; ++j)
            v[j] = (__bf16)ldf(P.W[m], (size_t)(krow + j) * DDIM + col, f);
        ((bf16x8*)wfp)[slot] = v;
    }
}

__global__ __launch_bounds__(256) void fill_slots_packed(
    const int* __restrict__ dst, const int* __restrict__ srcArr,
    const void* __restrict__ wArr, int nE, int* __restrict__ counts,
    int2* __restrict__ slots2, int* __restrict__ ovCount,
    int* __restrict__ ovList, float* __restrict__ agg,
    const int* __restrict__ flags, int fiW)
{
    int e = blockIdx.x * 256 + threadIdx.x;
    if (e >= nE) return;
    const bool fW = dtf(flags, fiW);
    int d = dst[e];
    int pos = atomicAdd(&counts[d], 1);
    if (pos < CAP) {
        int2 pk;
        pk.x = srcArr[e];
        pk.y = __float_as_int(ldf(wArr, e, fW));
        slots2[(size_t)d * CAP + pos] = pk;
    } else {
        if (pos == CAP) {
            f32x4 z = {0.f, 0.f, 0.f, 0.f};
            f32x4* rp = (f32x4*)(agg + (size_t)d * DDIM);
#pragma unroll 4
            for (int c = 0; c < DDIM / 4; ++c) rp[c] = z;
        }
        int k = atomicAdd(ovCount, 1);
        ovList[k] = e;
    }
}

__global__ __launch_bounds__(256) void segsum_ov(
    const __bf16* __restrict__ gsrc, const int* __restrict__ counts,
    const int2* __restrict__ slots2, float* __restrict__ agg, int nRows,
    const int* __restrict__ srcArr, const int* __restrict__ dstArr,
    const void* __restrict__ wArr, const int* __restrict__ ovList,
    const int* __restrict__ ovCount, const int* __restrict__ flags, int fiW,
    int gblocks)
{
    const int tid  = threadIdx.x;
    const int lane = tid & 63;

    if ((int)blockIdx.x >= gblocks) {
        const bool fW = dtf(flags, fiW);
        const int nOv = *ovCount;
        const int wv_ = tid >> 6;
        const int nWaves = 64 * 4;
        for (int k = (blockIdx.x - gblocks) * 4 + wv_; k < nOv; k += nWaves) {
            int e = ovList[k];
            int s = srcArr[e], d = dstArr[e];
            float wf = ldf(wArr, e, fW);
            bf16x2 v = ((const bf16x2*)gsrc)[(size_t)s * 64 + lane];
            float* ap = agg + (size_t)d * DDIM + lane * 2;
            unsafeAtomicAdd(ap + 0, (float)v[0] * wf);
            unsafeAtomicAdd(ap + 1, (float)v[1] * wf);
        }
        return;
    }

    int row = blockIdx.x * 4 + (tid >> 6);
    if (row >= nRows) return;

    int cntRaw = counts[row];
    int cnt = cntRaw > CAP ? CAP : cntRaw;

    int sr = 0; float wv = 0.f;
    if (lane < cnt) {
        int2 pk = slots2[(size_t)row * CAP + lane];
        sr = pk.x;
        wv = __int_as_float(pk.y);
    }

    float2* ap = (float2*)(agg + (size_t)row * DDIM) + lane;
    float2 acc0 = {0.f, 0.f}, acc1 = {0.f, 0.f};

    const bf16x2* fb = (const bf16x2*)gsrc;
    int i = 0;
    for (; i + 4 <= cnt; i += 4) {
        int   a0 = __shfl(sr, i),     a1 = __shfl(sr, i + 1);
        int   a2 = __shfl(sr, i + 2), a3 = __shfl(sr, i + 3);
        float w0 = __shfl(wv, i),     w1 = __shfl(wv, i + 1);
        float w2 = __shfl(wv, i + 2), w3 = __shfl(wv, i + 3);
        bf16x2 v0 = fb[(size_t)a0 * 64 + lane];
        bf16x2 v1 = fb[(size_t)a1 * 64 + lane];
        bf16x2 v2 = fb[(size_t)a2 * 64 + lane];
        bf16x2 v3 = fb[(size_t)a3 * 64 + lane];
        acc0.x += (float)v0[0] * w0; acc0.y += (float)v0[1] * w0;
        acc1.x += (float)v1[0] * w1; acc1.y += (float)v1[1] * w1;
        acc0.x += (float)v2[0] * w2; acc0.y += (float)v2[1] * w2;
        acc1.x += (float)v3[0] * w3; acc1.y += (float)v3[1] * w3;
    }
    for (; i < cnt; ++i) {
        int   a0 = __shfl(sr, i);
        float w0 = __shfl(wv, i);
        bf16x2 v0 = fb[(size_t)a0 * 64 + lane];
        acc0.x += (float)v0[0] * w0; acc0.y += (float)v0[1] * w0;
    }
    acc0.x += acc1.x; acc0.y += acc1.y;
    if (cntRaw > CAP) {
        unsafeAtomicAdd(&ap->x, acc0.x);
        unsafeAtomicAdd(&ap->y, acc0.y);
    } else {
        *ap = acc0;
    }
}

// ======================= legacy kernels (ws-too-small) ======================
__global__ __launch_bounds__(256) void scatter_any(
    const void* __restrict__ feat, const int* __restrict__ src,
    const int* __restrict__ dst, const void* __restrict__ w,
    float* __restrict__ agg, int nE,
    const int* __restrict__ flags, int fiFeat, int fiW)
{
    const bool fF = dtf(flags, fiFeat);
    const bool fW = dtf(flags, fiW);
    int g = blockIdx.x * 256 + threadIdx.x;
    int e = g >> 5;
    if (e >= nE) return;
    int c = (g & 31) << 2;
    int s = src[e], d = dst[e];
    float wf = ldf(w, e, fW);
    size_t base = (size_t)s * DDIM + c;
    float* ap = agg + (size_t)d * DDIM + c;
    unsafeAtomicAdd(ap + 0, ldf(feat, base + 0, fF) * wf);
    unsafeAtomicAdd(ap + 1, ldf(feat, base + 1, fF) * wf);
    unsafeAtomicAdd(ap + 2, ldf(feat, base + 2, fF) * wf);
    unsafeAtomicAdd(ap + 3, ldf(feat, base + 3, fF) * wf);
}

__global__ __launch_bounds__(256) void residual_add(
    float* __restrict__ out, const void* __restrict__ feat, int n4,
    const int* __restrict__ flags, int fiFeat)
{
    const bool fF = flags[fiFeat] != 0;
    int i = blockIdx.x * 256 + threadIdx.x;
    if (i >= n4) return;
    f32x4 o = ((const f32x4*)out)[i];
    f32x4 r;
#pragma unroll
    for (int j = 0; j < 4; ++j) r[j] = o[j] + ldf(feat, (size_t)i * 4 + j, fF);
    ((f32x4*)out)[i] = r;
}

__device__ __forceinline__ void fill_wfrag(const void* __restrict__ W, bool f,
                                           __bf16* wf, int tid)
{
#pragma unroll
    for (int i = 0; i < 8; ++i) {
        int sIdx  = tid + i * 256;
        int l     = sIdx & 63;
        int combo = sIdx >> 6;
        int ct = combo >> 2, kk = combo & 3;
        int col  = ct * 16 + (l & 15);
        int krow = kk * 32 + (l >> 4) * 8;
        __bf16* dp = wf + (size_t)sIdx * 8;
#pragma unroll
        for (int j = 0; j < 8; ++j)
            dp[j] = (__bf16)ldf(W, (size_t)(krow + j) * DDIM + col, f);
    }
}

template <bool RESIDUAL>
__global__ __launch_bounds__(256) void mlp_kernel(
    const void* __restrict__ feat, const float* __restrict__ agg,
    const void* __restrict__ W1, const void* __restrict__ b1,
    const void* __restrict__ W2, const void* __restrict__ b2,
    const void* __restrict__ epsp, float* __restrict__ out, int N,
    const int* __restrict__ flags,
    int fiFeat, int fiW1, int fiB1, int fiW2, int fiB2, int fiEps)
{
    __shared__ alignas(16) __bf16 wf[32 * 64 * 8];
    __shared__ alignas(16) __bf16 h1t[64 * 136];

    const bool fF  = flags[fiFeat] != 0;
    const bool fB1 = flags[fiB1] != 0;
    const bool fB2 = flags[fiB2] != 0;
    const bool fE  = flags[fiEps] != 0;

    const int tid  = threadIdx.x;
    const int lane = tid & 63;
    const int wave = tid >> 6;
    const int quad = lane >> 4;
    const int r    = lane & 15;

    fill_wfrag(W1, flags[fiW1] != 0, wf, tid);

    const float eps1 = 1.f + ldf(epsp, 0, fE);
    const int rowBase = blockIdx.x * 64 + wave * 16;

    bf16x8 a[4];
    {
        int rowA = rowBase + r;
        if (rowA < N) {
            size_t fb = (size_t)rowA * DDIM + quad * 8;
            const f32x4* gp = (const f32x4*)(agg + fb);
            if (fF) {
                const f32x4* fp = (const f32x4*)((const float*)feat + fb);
#pragma unroll
                for (int kk = 0; kk < 4; ++kk) {
                    f32x4 f0 = fp[kk * 8], f1 = fp[kk * 8 + 1];
                    f32x4 g0 = gp[kk * 8], g1 = gp[kk * 8 + 1];
                    bf16x8 av;
#pragma unroll
                    for (int j = 0; j < 4; ++j) {
                        av[j]     = (__bf16)(f0[j] * eps1 + g0[j]);
                        av[j + 4] = (__bf16)(f1[j] * eps1 + g1[j]);
                    }
                    a[kk] = av;
                }
            } else {
                const bf16x8* fp = (const bf16x8*)((const bf16_t*)feat + fb);
#pragma unroll
                for (int kk = 0; kk < 4; ++kk) {
                    bf16x8 fv = fp[kk * 4];
                    f32x4 g0 = gp[kk * 8], g1 = gp[kk * 8 + 1];
                    bf16x8 av;
#pragma unroll
                    for (int j = 0; j < 4; ++j) {
                        av[j]     = (__bf16)((float)fv[j]     * eps1 + g0[j]);
                        av[j + 4] = (__bf16)((float)fv[j + 4] * eps1 + g1[j]);
                    }
                    a[kk] = av;
                }
            }
        } else {
#pragma unroll
            for (int kk = 0; kk < 4; ++kk)
#pragma unroll
                for (int j = 0; j < 8; ++j) a[kk][j] = (__bf16)0.f;
        }
    }

    __syncthreads();

    const bf16x8* wv = (const bf16x8*)wf;
#pragma unroll
    for (int ct = 0; ct < 8; ++ct) {
        f32x4 acc = {0.f, 0.f, 0.f, 0.f};
#pragma unroll
        for (int kk = 0; kk < 4; ++kk)
            acc = __builtin_amdgcn_mfma_f32_16x16x32_bf16(
                a[kk], wv[(ct * 4 + kk) * 64 + lane], acc, 0, 0, 0);
        float bias = ldf(b1, ct * 16 + r, fB1);
#pragma unroll
        for (int gg = 0; gg < 4; ++gg)
            h1t[(wave * 16 + quad * 4 + gg) * 136 + ct * 16 + r] =
                (__bf16)lrelu(acc[gg] + bias);
    }
    __syncthreads();

    bf16x8 a2[4];
#pragma unroll
    for (int kk = 0; kk < 4; ++kk)
        a2[kk] = *(const bf16x8*)&h1t[(wave * 16 + r) * 136 + kk * 32 + quad * 8];

    fill_wfrag(W2, flags[fiW2] != 0, wf, tid);
    __syncthreads();

#pragma unroll
    for (int ct = 0; ct < 8; ++ct) {
        f32x4 acc = {0.f, 0.f, 0.f, 0.f};
#pragma unroll
        for (int kk = 0; kk < 4; ++kk)
            acc = __builtin_amdgcn_mfma_f32_16x16x32_bf16(
                a2[kk], wv[(ct * 4 + kk) * 64 + lane], acc, 0, 0, 0);
        float bias = ldf(b2, ct * 16 + r, fB2);
#pragma unroll
        for (int gg = 0; gg < 4; ++gg) {
            int row = rowBase + quad * 4 + gg;
            if (row < N) {
                int col = ct * 16 + r;
                float v = lrelu(acc[gg] + bias);
                if (RESIDUAL) v += ldf(feat, (size_t)row * DDIM + col, fF);
                out[(size_t)row * DDIM + col] = v;
            }
        }
    }
}

extern "C" void kernel_launch(void* const* d_in, const int* in_sizes, int n_in,
                              void* d_out, int out_size, void* d_ws, size_t ws_size,
                              hipStream_t stream)
{
    const int* src_c2r = (const int*)d_in[2];
    const int* dst_c2r = (const int*)d_in[3];
    const int* src_r2c = (const int*)d_in[5];
    const int* dst_r2c = (const int*)d_in[6];
    const int nE = in_sizes[2];

    // ---- workspace layouts ----
    char* wsb = (char*)d_ws;
    int*    flags  = (int*)wsb;
    __bf16* wfprep = (__bf16*)(wsb + 128);
    // A2 layout: countsA | ovCntA | countsB | ovCntB | slots2 | ovListA | ovListB | cbuf
    int*    countsA = (int*)(wsb + 128 + 131072);
    int*    ovCntA  = countsA + NROW;
    int*    countsB = countsA + NROW + 8;
    int*    ovCntB  = countsA + 2 * NROW + 8;
    size_t  ofsA2   = 128 + 131072 + ((size_t)2 * NROW + 16) * 4;
    ofsA2 = (ofsA2 + 15) & ~(size_t)15;
    int2*   slots2A2  = (int2*)(wsb + ofsA2);
    size_t  ofsOvA2   = ofsA2 + (size_t)NROW * CAP * 8;
    int*    ovListA2  = (int*)(wsb + ofsOvA2);
    int*    ovListB2  = ovListA2 + nE;
    size_t  ofsCbA2   = (ofsOvA2 + (size_t)nE * 8 + 15) & ~(size_t)15;
    __bf16* cbufA2    = (__bf16*)(wsb + ofsCbA2);
    const size_t NEED_A2 = ofsCbA2 + (size_t)NROW * DDIM * 2;

    // round-4 A layout: counts | ovCnt | slots2 | ovList | cbuf
    int*    counts = (int*)(wsb + 128 + 131072);
    int*    ovCnt  = counts + NROW;
    size_t  ofs    = 128 + 131072 + ((size_t)NROW + 8) * 4;
    ofs = (ofs + 15) & ~(size_t)15;
    int2*   slots2 = (int2*)(wsb + ofs);
    size_t  ofsOvA = ofs + (size_t)NROW * CAP * 8;
    int*    ovListA = (int*)(wsb + ofsOvA);
    size_t  ofsCb  = (ofsOvA + (size_t)nE * 4 + 15) & ~(size_t)15;
    __bf16* cbuf   = (__bf16*)(wsb + ofsCb);
    const size_t NEED_A = ofsCb + (size_t)NROW * DDIM * 2;

    const bool tierA2 = ws_size >= NEED_A2;
    const bool tierA  = ws_size >= NEED_A;

    TensorTab T;
    for (int i = 0; i < 18; ++i) { T.p[i] = d_in[i]; T.n[i] = in_sizes[i]; }

    float* out_row = (float*)d_out;
    float* out_col = out_row + (size_t)NROW * DDIM;
    const size_t aggBytes = (size_t)NROW * DDIM * sizeof(float);

    const int eblocks  = (nE + 255) / 256;
    const int sblocks  = (nE * 32 + 255) / 256;
    const int mblocksR = (NROW + 63) / 64;
    const int mblocksC = (NCOL + 63) / 64;
    const int gblocksR = (NROW + 3) / 4;
    const int gblocksC = (NCOL + 3) / 4;
    const int cblocks  = (NCOL * DDIM / 8 + 255) / 256;

    WPtrs P;
    P.W[0] = d_in[8];  P.fi[0] = 8;
    P.W[1] = d_in[10]; P.fi[1] = 10;
    P.W[2] = d_in[12]; P.fi[2] = 12;
    P.W[3] = d_in[14]; P.fi[3] = 14;

    if (tierA2) {
        const int zn2 = 2 * NROW + 16;
        const int zb2 = (zn2 + 255) / 256;
        // D1: detect dtypes || zero countsA/ovCntA/countsB/ovCntB
        detect_zero<<<18 + zb2, 256, 0, stream>>>(T, flags, countsA, zn2);
        // D2: cbuf convert || weight prep || fill stage-1
        prep_fill<<<cblocks + 32 + eblocks, 256, 0, stream>>>(
            P, flags, wfprep, d_in[1], cbufA2, NCOL * DDIM / 8, 1, cblocks,
            dst_c2r, src_c2r, d_in[4], nE, countsA, slots2A2, ovCntA,
            ovListA2, 4);
        // D3: segsum stage-1 (inline overflow scan)
        segsum_scan<<<gblocksR, 256, 0, stream>>>(cbufA2, countsA, slots2A2,
            out_col, NROW, src_c2r, dst_c2r, d_in[4], ovListA2, ovCntA,
            flags, 4);
        // D4: mlp stage-1 (out_row = h+feat, cbuf = h bf16) || fill stage-2
        mlp_reg<true, true><<<mblocksR + eblocks, 256, 0, stream>>>(
            d_in[0], out_col, d_in[9], d_in[11], d_in[16],
            out_row, NROW, flags, 0, 9, 11, 16,
            wfprep + 0 * 16384, wfprep + 1 * 16384, cbufA2, nullptr, 0,
            mblocksR, dst_r2c, src_r2c, d_in[7], nE, countsB, slots2A2,
            ovCntB, ovListB2, 7);
        // D5: segsum stage-2
        segsum_scan<<<gblocksC, 256, 0, stream>>>(cbufA2, countsB, slots2A2,
            out_col, NCOL, src_r2c, dst_r2c, d_in[7], ovListB2, ovCntB,
            flags, 7);
        // D6: mlp stage-2
        mlp_reg<true, false><<<mblocksC, 256, 0, stream>>>(
            d_in[1], out_col, d_in[13], d_in[15], d_in[17],
            out_col, NCOL, flags, 1, 13, 15, 17,
            wfprep + 2 * 16384, wfprep + 3 * 16384, nullptr, nullptr, 0,
            mblocksC, nullptr, nullptr, nullptr, 0, nullptr, nullptr,
            nullptr, nullptr, 0);
    } else if (tierA) {
        // round-4 proven path
        const int zblocks = ((NROW + 8) + 255) / 256;
        const int zn      = NROW + 8;
        detect_zero<<<18, 256, 0, stream>>>(T, flags, nullptr, 0);
        prep_all<<<cblocks + zblocks + 32, 256, 0, stream>>>(
            P, flags, wfprep, d_in[1], cbuf, NCOL * DDIM / 8, 1,
            counts, zn, cblocks, zblocks);
        fill_slots_packed<<<eblocks, 256, 0, stream>>>(dst_c2r, src_c2r,
            d_in[4], nE, counts, slots2, ovCnt, ovListA, out_col, flags, 4);
        segsum_ov<<<gblocksR + 64, 256, 0, stream>>>(cbuf, counts, slots2,
            out_col, NROW, src_c2r, dst_c2r, d_in[4], ovListA, ovCnt,
            flags, 4, gblocksR);
        mlp_reg<true, true><<<mblocksR, 256, 0, stream>>>(
            d_in[0], out_col, d_in[9], d_in[11], d_in[16],
            out_row, NROW, flags, 0, 9, 11, 16,
            wfprep + 0 * 16384, wfprep + 1 * 16384, cbuf, counts, zn,
            mblocksR, nullptr, nullptr, nullptr, 0, nullptr, nullptr,
            nullptr, nullptr, 0);
        fill_slots_packed<<<eblocks, 256, 0, stream>>>(dst_r2c, src_r2c,
            d_in[7], nE, counts, slots2, ovCnt, ovListA, out_col, flags, 7);
        segsum_ov<<<gblocksC + 64, 256, 0, stream>>>(cbuf, counts, slots2,
            out_col, NCOL, src_r2c, dst_r2c, d_in[7], ovListA, ovCnt,
            flags, 7, gblocksC);
        mlp_reg<true, false><<<mblocksC, 256, 0, stream>>>(
            d_in[1], out_col, d_in[13], d_in[15], d_in[17],
            out_col, NCOL, flags, 1, 13, 15, 17,
            wfprep + 2 * 16384, wfprep + 3 * 16384, nullptr, nullptr, 0,
            mblocksC, nullptr, nullptr, nullptr, 0, nullptr, nullptr,
            nullptr, nullptr, 0);
    } else {
        // legacy path
        detect_zero<<<18, 256, 0, stream>>>(T, flags, nullptr, 0);
        hipMemsetAsync(out_col, 0, aggBytes, stream);
        scatter_any<<<sblocks, 256, 0, stream>>>(d_in[1], src_c2r, dst_c2r,
            d_in[4], out_col, nE, flags, 1, 4);
        mlp_kernel<false><<<mblocksR, 256, 0, stream>>>(
            d_in[0], out_col, d_in[8], d_in[9], d_in[10], d_in[11], d_in[16],
            out_row, NROW, flags, 0, 8, 9, 10, 11, 16);

        hipMemsetAsync(out_col, 0, aggBytes, stream);
        scatter_any<<<sblocks, 256, 0, stream>>>(out_row, src_r2c, dst_r2c,
            d_in[7], out_col, nE, flags, -1, 7);
        residual_add<<<(NROW * DDIM / 4 + 255) / 256, 256, 0, stream>>>(
            out_row, d_in[0], NROW * DDIM / 4, flags, 0);
        mlp_kernel<true><<<mblocksC, 256, 0, stream>>>(
            d_in[1], out_col, d_in[12], d_in[13], d_in[14], d_in[15], d_in[17],
            out_col, NCOL, flags, 1, 12, 13, 14, 15, 17);
    }
}

// Round 7
// 309.524 us; speedup vs baseline: 1.3597x; 1.0539x over previous
//
#include <hip/hip_runtime.h>
#include <hip/hip_bf16.h>

#define NROW 50000
#define NCOL 50000
#define DDIM 128
#define CAP  32   // slots per destination row

typedef __bf16 bf16_t;
typedef __bf16 bf16x2 __attribute__((ext_vector_type(2)));
typedef __bf16 bf16x8 __attribute__((ext_vector_type(8)));
typedef float  f32x4  __attribute__((ext_vector_type(4)));

__device__ __forceinline__ float lrelu(float v) { return v >= 0.f ? v : 0.01f * v; }

__device__ __forceinline__ float ldf(const void* p, size_t i, bool f) {
    return f ? ((const float*)p)[i] : (float)((const bf16_t*)p)[i];
}

// fi: >=0 -> flags[fi]; -1 -> forced f32; -2 -> forced bf16
__device__ __forceinline__ bool dtf(const int* flags, int fi) {
    return (fi == -1) ? true : (fi == -2) ? false : (flags[fi] != 0);
}

// ---------------- D1: dtype detect (18 blocks) + zero counts ---------------
struct TensorTab { const void* p[18]; int n[18]; };

__global__ __launch_bounds__(256) void detect_zero(TensorTab T, int* flags,
                                                   int* z, int zn)
{
    const int tid = threadIdx.x;
    if (blockIdx.x >= 18) {                  // zero countsA|ovCntA|countsB|ovCntB
        int i = (blockIdx.x - 18) * 256 + tid;
        if (i < zn) z[i] = 0;
        return;
    }
    __shared__ int vb, vf;
    const int t = blockIdx.x;
    if (tid == 0) { vb = 0; vf = 0; }
    __syncthreads();
    const int n = T.n[t];
    const bool isFloatArr = (t != 2 && t != 3 && t != 5 && t != 6) && n >= 2;
    if (isFloatArr) {
        int nw = n / 2;
        int wi = (int)(((long long)tid * nw) >> 8);
        unsigned w = ((const unsigned*)T.p[t])[wi];
        unsigned low = w & 0xffffu;
        if (low) {
            int e = (int)((low >> 7) & 0xffu);
            if (e >= 90 && e <= 141) atomicAdd(&vb, 1);
            else                     atomicAdd(&vf, 1);
        }
    }
    __syncthreads();
    if (tid == 0) flags[t] = (isFloatArr && vf > vb) ? 1 : 0; // 1 = f32
}

// ---------------- shared fill routine (no agg touch) -----------------------
__device__ __forceinline__ void fill_edges(
    int e, const int* __restrict__ dst, const int* __restrict__ srcArr,
    const void* __restrict__ wArr, int nE, int* __restrict__ counts,
    int2* __restrict__ slots2, int* __restrict__ ovCnt,
    int* __restrict__ ovList, bool fW)
{
    if (e >= nE) return;
    int d = dst[e];
    int pos = atomicAdd(&counts[d], 1);
    if (pos < CAP) {
        int2 pk;
        pk.x = srcArr[e];
        pk.y = __float_as_int(ldf(wArr, e, fW));
        slots2[(size_t)d * CAP + pos] = pk;
    } else {
        int k = atomicAdd(ovCnt, 1);         // capacity == nE
        ovList[k] = e;
    }
}

// ---------------- D2: convert cbuf | weight prep | fillA (fused roles) ------
struct WPtrs { const void* W[4]; int fi[4]; };

__global__ __launch_bounds__(256) void prep_fill(
    WPtrs P, const int* __restrict__ flags, __bf16* __restrict__ wfp,
    const void* __restrict__ feat, __bf16* __restrict__ cbuf, int n8,
    int fiFeat, int cblocks,
    const int* __restrict__ f_dst, const int* __restrict__ f_src,
    const void* __restrict__ f_w, int f_nE, int* __restrict__ f_counts,
    int2* __restrict__ f_slots2, int* __restrict__ f_ovCnt,
    int* __restrict__ f_ovList, int f_fiW)
{
    const int b = blockIdx.x;
    const int tid = threadIdx.x;
    if (b < cblocks) {                       // convert feat table to bf16
        int i = b * 256 + tid;
        if (i >= n8) return;
        const bool f = dtf(flags, fiFeat);
        bf16x8 v;
        if (f) {
            f32x4 a = ((const f32x4*)feat)[i * 2];
            f32x4 c = ((const f32x4*)feat)[i * 2 + 1];
#pragma unroll
            for (int j = 0; j < 4; ++j) { v[j] = (__bf16)a[j]; v[j + 4] = (__bf16)c[j]; }
        } else {
            v = ((const bf16x8*)feat)[i];
        }
        ((bf16x8*)cbuf)[i] = v;
    } else if (b < cblocks + 32) {           // weight B-frag prep (4 matrices)
        int slot = (b - cblocks) * 256 + tid;   // 4 * 2048
        if (slot >= 4 * 2048) return;
        int m = slot >> 11, sIdx = slot & 2047;
        bool f = flags[P.fi[m]] != 0;
        int l = sIdx & 63, combo = sIdx >> 6;
        int ct = combo >> 2, kk = combo & 3;
        int col  = ct * 16 + (l & 15);
        int krow = kk * 32 + (l >> 4) * 8;
        bf16x8 v;
#pragma unroll
        for (int j = 0; j < 8; ++j)
            v[j] = (__bf16)ldf(P.W[m], (size_t)(krow + j) * DDIM + col, f);
        ((bf16x8*)wfp)[slot] = v;
    } else {                                 // fill stage-1 buckets
        int e = (b - cblocks - 32) * 256 + tid;
        fill_edges(e, f_dst, f_src, f_w, f_nE, f_counts, f_slots2,
                   f_ovCnt, f_ovList, dtf(flags, f_fiW));
    }
}

// ---------------- segment sum with inline overflow scan ---------------------
__global__ __launch_bounds__(256) void segsum_scan(
    const __bf16* __restrict__ gsrc, const int* __restrict__ counts,
    const int2* __restrict__ slots2, float* __restrict__ agg, int nRows,
    const int* __restrict__ srcArr, const int* __restrict__ dstArr,
    const void* __restrict__ wArr, const int* __restrict__ ovList,
    const int* __restrict__ ovCount, const int* __restrict__ flags, int fiW)
{
    int row = blockIdx.x * 4 + (threadIdx.x >> 6);
    if (row >= nRows) return;
    int lane = threadIdx.x & 63;

    int cntRaw = counts[row];
    int cnt = cntRaw > CAP ? CAP : cntRaw;

    int sr = 0; float wv = 0.f;
    if (lane < cnt) {
        int2 pk = slots2[(size_t)row * CAP + lane];
        sr = pk.x;
        wv = __int_as_float(pk.y);
    }

    float2* ap = (float2*)(agg + (size_t)row * DDIM) + lane;
    float2 acc0 = {0.f, 0.f}, acc1 = {0.f, 0.f};

    const bf16x2* fb = (const bf16x2*)gsrc;
    int i = 0;
    for (; i + 4 <= cnt; i += 4) {
        int   a0 = __shfl(sr, i),     a1 = __shfl(sr, i + 1);
        int   a2 = __shfl(sr, i + 2), a3 = __shfl(sr, i + 3);
        float w0 = __shfl(wv, i),     w1 = __shfl(wv, i + 1);
        float w2 = __shfl(wv, i + 2), w3 = __shfl(wv, i + 3);
        bf16x2 v0 = fb[(size_t)a0 * 64 + lane];
        bf16x2 v1 = fb[(size_t)a1 * 64 + lane];
        bf16x2 v2 = fb[(size_t)a2 * 64 + lane];
        bf16x2 v3 = fb[(size_t)a3 * 64 + lane];
        acc0.x += (float)v0[0] * w0; acc0.y += (float)v0[1] * w0;
        acc1.x += (float)v1[0] * w1; acc1.y += (float)v1[1] * w1;
        acc0.x += (float)v2[0] * w2; acc0.y += (float)v2[1] * w2;
        acc1.x += (float)v3[0] * w3; acc1.y += (float)v3[1] * w3;
    }
    for (; i < cnt; ++i) {
        int   a0 = __shfl(sr, i);
        float w0 = __shfl(wv, i);
        bf16x2 v0 = fb[(size_t)a0 * 64 + lane];
        acc0.x += (float)v0[0] * w0; acc0.y += (float)v0[1] * w0;
    }
    if (cntRaw > CAP) {                      // rare: pick own edges from ovList
        const bool fW = dtf(flags, fiW);
        int nOv = *ovCount;
        for (int k = 0; k < nOv; ++k) {
            int e = ovList[k];
            if (dstArr[e] == row) {
                int s = srcArr[e];
                float wf = ldf(wArr, e, fW);
                bf16x2 v = fb[(size_t)s * 64 + lane];
                acc0.x += (float)v[0] * wf; acc0.y += (float)v[1] * wf;
            }
        }
    }
    acc0.x += acc1.x; acc0.y += acc1.y;
    *ap = acc0;
}

// ---------------- column-split fused MLP (Tier A2) --------------------------
// Block = 4 waves x 16 rows. Wave w owns output cols [32w, 32w+32) for BOTH
// layers -> only 8 weight frags (32 VGPR) live per layer: all loads issue in
// one round trip (kills the serialized weight-load chain of mlp_reg).
// A-tile (16 rows x 128, bf16 of eps*feat+agg) built cooperatively in LDS;
// h1 exchanged through a second LDS tile across one sync.
// 4x the wave parallelism of mlp_reg (ceil(N/16) blocks x 4 waves).
template <bool RESIDUAL, bool HOUT>
__global__ __launch_bounds__(256) void mlp_cs(
    const void* __restrict__ feat, const float* __restrict__ agg,
    const void* __restrict__ b1, const void* __restrict__ b2,
    const void* __restrict__ epsp, float* __restrict__ out, int N,
    const int* __restrict__ flags, int fiFeat, int fiB1, int fiB2, int fiEps,
    const __bf16* __restrict__ pW1, const __bf16* __restrict__ pW2,
    __bf16* __restrict__ hout,
    int mblocks,
    const int* __restrict__ f_dst, const int* __restrict__ f_src,
    const void* __restrict__ f_w, int f_nE, int* __restrict__ f_counts,
    int2* __restrict__ f_slots2, int* __restrict__ f_ovCnt,
    int* __restrict__ f_ovList, int f_fiW)
{
    __shared__ alignas(16) __bf16 At[16 * 136];   // A tile (later: hout stage)
    __shared__ alignas(16) __bf16 H1[16 * 136];   // h1 exchange tile

    const int tid = threadIdx.x;
    if (f_dst && (int)blockIdx.x >= mblocks) {    // ---- fused fill role ----
        int e = ((int)blockIdx.x - mblocks) * 256 + tid;
        fill_edges(e, f_dst, f_src, f_w, f_nE, f_counts, f_slots2,
                   f_ovCnt, f_ovList, dtf(flags, f_fiW));
        return;
    }

    const bool fF  = flags[fiFeat] != 0;
    const bool fB1 = flags[fiB1] != 0;
    const bool fB2 = flags[fiB2] != 0;
    const bool fE  = flags[fiEps] != 0;

    const int lane = tid & 63;
    const int wave = tid >> 6;
    const int quad = lane >> 4;
    const int r    = lane & 15;
    const int rowBase = blockIdx.x * 16;
    const float eps1 = 1.f + ldf(epsp, 0, fE);

    // ---- Phase A: build A tile (16 rows x 128 bf16) cooperatively ----
    {
        int row = tid >> 4;                   // 0..15
        int k0  = (tid & 15) * 8;             // 0..120
        int g   = rowBase + row;
        bf16x8 av;
        if (g < N) {
            size_t base = (size_t)g * DDIM + k0;
            const f32x4* gp = (const f32x4*)(agg + base);
            f32x4 g0 = gp[0], g1 = gp[1];
            if (fF) {
                const f32x4* fp = (const f32x4*)((const float*)feat + base);
                f32x4 f0 = fp[0], f1 = fp[1];
#pragma unroll
                for (int j = 0; j < 4; ++j) {
                    av[j]     = (__bf16)(f0[j] * eps1 + g0[j]);
                    av[j + 4] = (__bf16)(f1[j] * eps1 + g1[j]);
                }
            } else {
                bf16x8 fv = *(const bf16x8*)((const bf16_t*)feat + base);
#pragma unroll
                for (int j = 0; j < 4; ++j) {
                    av[j]     = (__bf16)((float)fv[j]     * eps1 + g0[j]);
                    av[j + 4] = (__bf16)((float)fv[j + 4] * eps1 + g1[j]);
                }
            }
        } else {
#pragma unroll
            for (int j = 0; j < 8; ++j) av[j] = (__bf16)0.f;
        }
        *(bf16x8*)&At[row * 136 + k0] = av;
    }
    __syncthreads();

    // ---- A-frags from LDS (same 16 rows for all waves) ----
    bf16x8 a[4];
#pragma unroll
    for (int kk = 0; kk < 4; ++kk)
        a[kk] = *(const bf16x8*)&At[r * 136 + kk * 32 + quad * 8];

    const int ct0 = wave * 2, ct1 = ct0 + 1;

    // ---- W1 frags for this wave's two col-tiles (8 loads, parallel) ----
    const bf16x8* pw1v = (const bf16x8*)pW1;
    bf16x8 wfa[4], wfb[4];
#pragma unroll
    for (int kk = 0; kk < 4; ++kk) {
        wfa[kk] = pw1v[(ct0 * 4 + kk) * 64 + lane];
        wfb[kk] = pw1v[(ct1 * 4 + kk) * 64 + lane];
    }
    float b1a = ldf(b1, ct0 * 16 + r, fB1);
    float b1b = ldf(b1, ct1 * 16 + r, fB1);

    // ---- layer 1 -> H1 cols [ct0*16, ct1*16+16) ----
    {
        f32x4 acc = {0.f, 0.f, 0.f, 0.f};
#pragma unroll
        for (int kk = 0; kk < 4; ++kk)
            acc = __builtin_amdgcn_mfma_f32_16x16x32_bf16(a[kk], wfa[kk], acc, 0, 0, 0);
#pragma unroll
        for (int gg = 0; gg < 4; ++gg)
            H1[(quad * 4 + gg) * 136 + ct0 * 16 + r] = (__bf16)lrelu(acc[gg] + b1a);
    }
    {
        f32x4 acc = {0.f, 0.f, 0.f, 0.f};
#pragma unroll
        for (int kk = 0; kk < 4; ++kk)
            acc = __builtin_amdgcn_mfma_f32_16x16x32_bf16(a[kk], wfb[kk], acc, 0, 0, 0);
#pragma unroll
        for (int gg = 0; gg < 4; ++gg)
            H1[(quad * 4 + gg) * 136 + ct1 * 16 + r] = (__bf16)lrelu(acc[gg] + b1b);
    }
    __syncthreads();

    // ---- a2 from full h1 rows ----
    bf16x8 a2[4];
#pragma unroll
    for (int kk = 0; kk < 4; ++kk)
        a2[kk] = *(const bf16x8*)&H1[r * 136 + kk * 32 + quad * 8];

    // ---- W2 frags (regs of wfa/wfb reused) ----
    const bf16x8* pw2v = (const bf16x8*)pW2;
#pragma unroll
    for (int kk = 0; kk < 4; ++kk) {
        wfa[kk] = pw2v[(ct0 * 4 + kk) * 64 + lane];
        wfb[kk] = pw2v[(ct1 * 4 + kk) * 64 + lane];
    }
    float b2a = ldf(b2, ct0 * 16 + r, fB2);
    float b2b = ldf(b2, ct1 * 16 + r, fB2);

    // ---- layer 2 -> out (+residual); HOUT: stage bf16 h in At ----
#pragma unroll
    for (int cp = 0; cp < 2; ++cp) {
        const int ct = cp ? ct1 : ct0;
        f32x4 acc = {0.f, 0.f, 0.f, 0.f};
#pragma unroll
        for (int kk = 0; kk < 4; ++kk)
            acc = __builtin_amdgcn_mfma_f32_16x16x32_bf16(
                a2[kk], cp ? wfb[kk] : wfa[kk], acc, 0, 0, 0);
        float bias = cp ? b2b : b2a;
#pragma unroll
        for (int gg = 0; gg < 4; ++gg) {
            int row = rowBase + quad * 4 + gg;
            float v = lrelu(acc[gg] + bias);
            if (HOUT)
                At[(quad * 4 + gg) * 136 + ct * 16 + r] = (__bf16)v;
            if (row < N) {
                int col = ct * 16 + r;
                if (RESIDUAL) v += ldf(feat, (size_t)row * DDIM + col, fF);
                out[(size_t)row * DDIM + col] = v;
            }
        }
    }

    // ---- cooperative coalesced hout store ----
    if (HOUT) {
        __syncthreads();
        int row = tid >> 4;
        int k0  = (tid & 15) * 8;
        int g   = rowBase + row;
        if (g < N)
            *(bf16x8*)&hout[(size_t)g * DDIM + k0] =
                *(const bf16x8*)&At[row * 136 + k0];
    }
}

// =================== round-4 tier-A fallback kernels (proven) ===============
__global__ __launch_bounds__(256) void prep_all(
    WPtrs P, const int* __restrict__ flags, __bf16* __restrict__ wfp,
    const void* __restrict__ feat, __bf16* __restrict__ cbuf, int n8, int fiFeat,
    int* __restrict__ zc, int zn, int cblocks, int zblocks)
{
    const int b = blockIdx.x;
    const int tid = threadIdx.x;
    if (b < cblocks) {
        int i = b * 256 + tid;
        if (i >= n8) return;
        const bool f = dtf(flags, fiFeat);
        bf16x8 v;
        if (f) {
            f32x4 a = ((const f32x4*)feat)[i * 2];
            f32x4 c = ((const f32x4*)feat)[i * 2 + 1];
#pragma unroll
            for (int j = 0; j < 4; ++j) { v[j] = (__bf16)a[j]; v[j + 4] = (__bf16)c[j]; }
        } else {
            v = ((const bf16x8*)feat)[i];
        }
        ((bf16x8*)cbuf)[i] = v;
    } else if (b < cblocks + zblocks) {
        int i = (b - cblocks) * 256 + tid;
        if (i < zn) zc[i] = 0;
    } else {
        int slot = (b - cblocks - zblocks) * 256 + tid;
        if (slot >= 4 * 2048) return;
        int m = slot >> 11, sIdx = slot & 2047;
        bool f = flags[P.fi[m]] != 0;
        int l = sIdx & 63, combo = sIdx >> 6;
        int ct = combo >> 2, kk = combo & 3;
        int col  = ct * 16 + (l & 15);
        int krow = kk * 32 + (l >> 4) * 8;
        bf16x8 v;
#pragma unroll
        for (int j = 0; j < 8; ++j)
            v[j] = (__bf16)ldf(P.W[m], (size_t)(krow + j) * DDIM + col, f);
        ((bf16x8*)wfp)[slot] = v;
    }
}

__global__ __launch_bounds__(256) void fill_slots_packed(
    const int* __restrict__ dst, const int* __restrict__ srcArr,
    const void* __restrict__ wArr, int nE, int* __restrict__ counts,
    int2* __restrict__ slots2, int* __restrict__ ovCount,
    int* __restrict__ ovList, float* __restrict__ agg,
    const int* __restrict__ flags, int fiW)
{
    int e = blockIdx.x * 256 + threadIdx.x;
    if (e >= nE) return;
    const bool fW = dtf(flags, fiW);
    int d = dst[e];
    int pos = atomicAdd(&counts[d], 1);
    if (pos < CAP) {
        int2 pk;
        pk.x = srcArr[e];
        pk.y = __float_as_int(ldf(wArr, e, fW));
        slots2[(size_t)d * CAP + pos] = pk;
    } else {
        if (pos == CAP) {
            f32x4 z = {0.f, 0.f, 0.f, 0.f};
            f32x4* rp = (f32x4*)(agg + (size_t)d * DDIM);
#pragma unroll 4
            for (int c = 0; c < DDIM / 4; ++c) rp[c] = z;
        }
        int k = atomicAdd(ovCount, 1);
        ovList[k] = e;
    }
}

__global__ __launch_bounds__(256) void segsum_ov(
    const __bf16* __restrict__ gsrc, const int* __restrict__ counts,
    const int2* __restrict__ slots2, float* __restrict__ agg, int nRows,
    const int* __restrict__ srcArr, const int* __restrict__ dstArr,
    const void* __restrict__ wArr, const int* __restrict__ ovList,
    const int* __restrict__ ovCount, const int* __restrict__ flags, int fiW,
    int gblocks)
{
    const int tid  = threadIdx.x;
    const int lane = tid & 63;

    if ((int)blockIdx.x >= gblocks) {
        const bool fW = dtf(flags, fiW);
        const int nOv = *ovCount;
        const int wv_ = tid >> 6;
        const int nWaves = 64 * 4;
        for (int k = (blockIdx.x - gblocks) * 4 + wv_; k < nOv; k += nWaves) {
            int e = ovList[k];
            int s = srcArr[e], d = dstArr[e];
            float wf = ldf(wArr, e, fW);
            bf16x2 v = ((const bf16x2*)gsrc)[(size_t)s * 64 + lane];
            float* ap = agg + (size_t)d * DDIM + lane * 2;
            unsafeAtomicAdd(ap + 0, (float)v[0] * wf);
            unsafeAtomicAdd(ap + 1, (float)v[1] * wf);
        }
        return;
    }

    int row = blockIdx.x * 4 + (tid >> 6);
    if (row >= nRows) return;

    int cntRaw = counts[row];
    int cnt = cntRaw > CAP ? CAP : cntRaw;

    int sr = 0; float wv = 0.f;
    if (lane < cnt) {
        int2 pk = slots2[(size_t)row * CAP + lane];
        sr = pk.x;
        wv = __int_as_float(pk.y);
    }

    float2* ap = (float2*)(agg + (size_t)row * DDIM) + lane;
    float2 acc0 = {0.f, 0.f}, acc1 = {0.f, 0.f};

    const bf16x2* fb = (const bf16x2*)gsrc;
    int i = 0;
    for (; i + 4 <= cnt; i += 4) {
        int   a0 = __shfl(sr, i),     a1 = __shfl(sr, i + 1);
        int   a2 = __shfl(sr, i + 2), a3 = __shfl(sr, i + 3);
        float w0 = __shfl(wv, i),     w1 = __shfl(wv, i + 1);
        float w2 = __shfl(wv, i + 2), w3 = __shfl(wv, i + 3);
        bf16x2 v0 = fb[(size_t)a0 * 64 + lane];
        bf16x2 v1 = fb[(size_t)a1 * 64 + lane];
        bf16x2 v2 = fb[(size_t)a2 * 64 + lane];
        bf16x2 v3 = fb[(size_t)a3 * 64 + lane];
        acc0.x += (float)v0[0] * w0; acc0.y += (float)v0[1] * w0;
        acc1.x += (float)v1[0] * w1; acc1.y += (float)v1[1] * w1;
        acc0.x += (float)v2[0] * w2; acc0.y += (float)v2[1] * w2;
        acc1.x += (float)v3[0] * w3; acc1.y += (float)v3[1] * w3;
    }
    for (; i < cnt; ++i) {
        int   a0 = __shfl(sr, i);
        float w0 = __shfl(wv, i);
        bf16x2 v0 = fb[(size_t)a0 * 64 + lane];
        acc0.x += (float)v0[0] * w0; acc0.y += (float)v0[1] * w0;
    }
    acc0.x += acc1.x; acc0.y += acc1.y;
    if (cntRaw > CAP) {
        unsafeAtomicAdd(&ap->x, acc0.x);
        unsafeAtomicAdd(&ap->y, acc0.y);
    } else {
        *ap = acc0;
    }
}

// round-4 register-weight MLP (tier-A fallback)
template <bool RESIDUAL, bool HOUT>
__global__ __launch_bounds__(256) void mlp_reg(
    const void* __restrict__ feat, const float* __restrict__ agg,
    const void* __restrict__ b1, const void* __restrict__ b2,
    const void* __restrict__ epsp, float* __restrict__ out, int N,
    const int* __restrict__ flags, int fiFeat, int fiB1, int fiB2, int fiEps,
    const __bf16* __restrict__ pW1, const __bf16* __restrict__ pW2,
    __bf16* __restrict__ hout, int* __restrict__ zc, int zn)
{
    __shared__ alignas(16) __bf16 h1t[64 * 136];

    const int tid  = threadIdx.x;
    if (zc) {
        int gi = blockIdx.x * 256 + tid;
        if (gi < zn) zc[gi] = 0;
    }

    const bool fF  = flags[fiFeat] != 0;
    const bool fB1 = flags[fiB1] != 0;
    const bool fB2 = flags[fiB2] != 0;
    const bool fE  = flags[fiEps] != 0;

    const int lane = tid & 63;
    const int wave = tid >> 6;
    const int quad = lane >> 4;
    const int r    = lane & 15;
    const int rowBase = blockIdx.x * 64 + wave * 16;

    const bf16x8* pw1v = (const bf16x8*)pW1;
    bf16x8 w1f[32];
#pragma unroll
    for (int i = 0; i < 32; ++i) w1f[i] = pw1v[i * 64 + lane];

    float bias1[8];
#pragma unroll
    for (int ct = 0; ct < 8; ++ct) bias1[ct] = ldf(b1, ct * 16 + r, fB1);
    const float eps1 = 1.f + ldf(epsp, 0, fE);

    bf16x8 a[4];
    {
        int rowA = rowBase + r;
        if (rowA < N) {
            size_t fb = (size_t)rowA * DDIM + quad * 8;
            const f32x4* gp = (const f32x4*)(agg + fb);
            if (fF) {
                const f32x4* fp = (const f32x4*)((const float*)feat + fb);
#pragma unroll
                for (int kk = 0; kk < 4; ++kk) {
                    f32x4 f0 = fp[kk * 8], f1 = fp[kk * 8 + 1];
                    f32x4 g0 = gp[kk * 8], g1 = gp[kk * 8 + 1];
                    bf16x8 av;
#pragma unroll
                    for (int j = 0; j < 4; ++j) {
                        av[j]     = (__bf16)(f0[j] * eps1 + g0[j]);
                        av[j + 4] = (__bf16)(f1[j] * eps1 + g1[j]);
                    }
                    a[kk] = av;
                }
            } else {
                const bf16x8* fp = (const bf16x8*)((const bf16_t*)feat + fb);
#pragma unroll
                for (int kk = 0; kk < 4; ++kk) {
                    bf16x8 fv = fp[kk * 4];
                    f32x4 g0 = gp[kk * 8], g1 = gp[kk * 8 + 1];
                    bf16x8 av;
#pragma unroll
                    for (int j = 0; j < 4; ++j) {
                        av[j]     = (__bf16)((float)fv[j]     * eps1 + g0[j]);
                        av[j + 4] = (__bf16)((float)fv[j + 4] * eps1 + g1[j]);
                    }
                    a[kk] = av;
                }
            }
        } else {
#pragma unroll
            for (int kk = 0; kk < 4; ++kk)
#pragma unroll
                for (int j = 0; j < 8; ++j) a[kk][j] = (__bf16)0.f;
        }
    }

#pragma unroll
    for (int ct = 0; ct < 8; ++ct) {
        f32x4 acc = {0.f, 0.f, 0.f, 0.f};
#pragma unroll
        for (int kk = 0; kk < 4; ++kk)
            acc = __builtin_amdgcn_mfma_f32_16x16x32_bf16(
                a[kk], w1f[ct * 4 + kk], acc, 0, 0, 0);
#pragma unroll
        for (int gg = 0; gg < 4; ++gg)
            h1t[(wave * 16 + quad * 4 + gg) * 136 + ct * 16 + r] =
                (__bf16)lrelu(acc[gg] + bias1[ct]);
    }

    bf16x8 a2[4];
#pragma unroll
    for (int kk = 0; kk < 4; ++kk)
        a2[kk] = *(const bf16x8*)&h1t[(wave * 16 + r) * 136 + kk * 32 + quad * 8];

    const bf16x8* pw2v = (const bf16x8*)pW2;
    bf16x8 w2f[32];
#pragma unroll
    for (int i = 0; i < 32; ++i) w2f[i] = pw2v[i * 64 + lane];
    float bias2[8];
#pragma unroll
    for (int ct = 0; ct < 8; ++ct) bias2[ct] = ldf(b2, ct * 16 + r, fB2);

#pragma unroll
    for (int ct = 0; ct < 8; ++ct) {
        f32x4 acc = {0.f, 0.f, 0.f, 0.f};
#pragma unroll
        for (int kk = 0; kk < 4; ++kk)
            acc = __builtin_amdgcn_mfma_f32_16x16x32_bf16(
                a2[kk], w2f[ct * 4 + kk], acc, 0, 0, 0);
#pragma unroll
        for (int gg = 0; gg < 4; ++gg) {
            int row = rowBase + quad * 4 + gg;
            float v = lrelu(acc[gg] + bias2[ct]);
            if (HOUT)
                h1t[(wave * 16 + quad * 4 + gg) * 136 + ct * 16 + r] = (__bf16)v;
            if (row < N) {
                int col = ct * 16 + r;
                if (RESIDUAL) v += ldf(feat, (size_t)row * DDIM + col, fF);
                out[(size_t)row * DDIM + col] = v;
            }
        }
    }

    if (HOUT) {
        __syncthreads();
        const int blockBase = blockIdx.x * 64;
#pragma unroll
        for (int c = 0; c < 4; ++c) {
            int chunk = tid + c * 256;
            int row = chunk >> 4;
            int k   = (chunk & 15) * 8;
            if (blockBase + row < N) {
                bf16x8 v = *(const bf16x8*)&h1t[row * 136 + k];
                *(bf16x8*)&hout[(size_t)(blockBase + row) * DDIM + k] = v;
            }
        }
    }
}

// ======================= legacy kernels (ws-too-small) ======================
__global__ __launch_bounds__(256) void scatter_any(
    const void* __restrict__ feat, const int* __restrict__ src,
    const int* __restrict__ dst, const void* __restrict__ w,
    float* __restrict__ agg, int nE,
    const int* __restrict__ flags, int fiFeat, int fiW)
{
    const bool fF = dtf(flags, fiFeat);
    const bool fW = dtf(flags, fiW);
    int g = blockIdx.x * 256 + threadIdx.x;
    int e = g >> 5;
    if (e >= nE) return;
    int c = (g & 31) << 2;
    int s = src[e], d = dst[e];
    float wf = ldf(w, e, fW);
    size_t base = (size_t)s * DDIM + c;
    float* ap = agg + (size_t)d * DDIM + c;
    unsafeAtomicAdd(ap + 0, ldf(feat, base + 0, fF) * wf);
    unsafeAtomicAdd(ap + 1, ldf(feat, base + 1, fF) * wf);
    unsafeAtomicAdd(ap + 2, ldf(feat, base + 2, fF) * wf);
    unsafeAtomicAdd(ap + 3, ldf(feat, base + 3, fF) * wf);
}

__global__ __launch_bounds__(256) void residual_add(
    float* __restrict__ out, const void* __restrict__ feat, int n4,
    const int* __restrict__ flags, int fiFeat)
{
    const bool fF = flags[fiFeat] != 0;
    int i = blockIdx.x * 256 + threadIdx.x;
    if (i >= n4) return;
    f32x4 o = ((const f32x4*)out)[i];
    f32x4 r;
#pragma unroll
    for (int j = 0; j < 4; ++j) r[j] = o[j] + ldf(feat, (size_t)i * 4 + j, fF);
    ((f32x4*)out)[i] = r;
}

__device__ __forceinline__ void fill_wfrag(const void* __restrict__ W, bool f,
                                           __bf16* wf, int tid)
{
#pragma unroll
    for (int i = 0; i < 8; ++i) {
        int sIdx  = tid + i * 256;
        int l     = sIdx & 63;
        int combo = sIdx >> 6;
        int ct = combo >> 2, kk = combo & 3;
        int col  = ct * 16 + (l & 15);
        int krow = kk * 32 + (l >> 4) * 8;
        __bf16* dp = wf + (size_t)sIdx * 8;
#pragma unroll
        for (int j = 0; j < 8; ++j)
            dp[j] = (__bf16)ldf(W, (size_t)(krow + j) * DDIM + col, f);
    }
}

template <bool RESIDUAL>
__global__ __launch_bounds__(256) void mlp_kernel(
    const void* __restrict__ feat, const float* __restrict__ agg,
    const void* __restrict__ W1, const void* __restrict__ b1,
    const void* __restrict__ W2, const void* __restrict__ b2,
    const void* __restrict__ epsp, float* __restrict__ out, int N,
    const int* __restrict__ flags,
    int fiFeat, int fiW1, int fiB1, int fiW2, int fiB2, int fiEps)
{
    __shared__ alignas(16) __bf16 wf[32 * 64 * 8];
    __shared__ alignas(16) __bf16 h1t[64 * 136];

    const bool fF  = flags[fiFeat] != 0;
    const bool fB1 = flags[fiB1] != 0;
    const bool fB2 = flags[fiB2] != 0;
    const bool fE  = flags[fiEps] != 0;

    const int tid  = threadIdx.x;
    const int lane = tid & 63;
    const int wave = tid >> 6;
    const int quad = lane >> 4;
    const int r    = lane & 15;

    fill_wfrag(W1, flags[fiW1] != 0, wf, tid);

    const float eps1 = 1.f + ldf(epsp, 0, fE);
    const int rowBase = blockIdx.x * 64 + wave * 16;

    bf16x8 a[4];
    {
        int rowA = rowBase + r;
        if (rowA < N) {
            size_t fb = (size_t)rowA * DDIM + quad * 8;
            const f32x4* gp = (const f32x4*)(agg + fb);
            if (fF) {
                const f32x4* fp = (const f32x4*)((const float*)feat + fb);
#pragma unroll
                for (int kk = 0; kk < 4; ++kk) {
                    f32x4 f0 = fp[kk * 8], f1 = fp[kk * 8 + 1];
                    f32x4 g0 = gp[kk * 8], g1 = gp[kk * 8 + 1];
                    bf16x8 av;
#pragma unroll
                    for (int j = 0; j < 4; ++j) {
                        av[j]     = (__bf16)(f0[j] * eps1 + g0[j]);
                        av[j + 4] = (__bf16)(f1[j] * eps1 + g1[j]);
                    }
                    a[kk] = av;
                }
            } else {
                const bf16x8* fp = (const bf16x8*)((const bf16_t*)feat + fb);
#pragma unroll
                for (int kk = 0; kk < 4; ++kk) {
                    bf16x8 fv = fp[kk * 4];
                    f32x4 g0 = gp[kk * 8], g1 = gp[kk * 8 + 1];
                    bf16x8 av;
#pragma unroll
                    for (int j = 0; j < 4; ++j) {
                        av[j]     = (__bf16)((float)fv[j]     * eps1 + g0[j]);
                        av[j + 4] = (__bf16)((float)fv[j + 4] * eps1 + g1[j]);
                    }
                    a[kk] = av;
                }
            }
        } else {
#pragma unroll
            for (int kk = 0; kk < 4; ++kk)
#pragma unroll
                for (int j = 0; j < 8; ++j) a[kk][j] = (__bf16)0.f;
        }
    }

    __syncthreads();

    const bf16x8* wv = (const bf16x8*)wf;
#pragma unroll
    for (int ct = 0; ct < 8; ++ct) {
        f32x4 acc = {0.f, 0.f, 0.f, 0.f};
#pragma unroll
        for (int kk = 0; kk < 4; ++kk)
            acc = __builtin_amdgcn_mfma_f32_16x16x32_bf16(
                a[kk], wv[(ct * 4 + kk) * 64 + lane], acc, 0, 0, 0);
        float bias = ldf(b1, ct * 16 + r, fB1);
#pragma unroll
        for (int gg = 0; gg < 4; ++gg)
            h1t[(wave * 16 + quad * 4 + gg) * 136 + ct * 16 + r] =
                (__bf16)lrelu(acc[gg] + bias);
    }
    __syncthreads();

    bf16x8 a2[4];
#pragma unroll
    for (int kk = 0; kk < 4; ++kk)
        a2[kk] = *(const bf16x8*)&h1t[(wave * 16 + r) * 136 + kk * 32 + quad * 8];

    fill_wfrag(W2, flags[fiW2] != 0, wf, tid);
    __syncthreads();

#pragma unroll
    for (int ct = 0; ct < 8; ++ct) {
        f32x4 acc = {0.f, 0.f, 0.f, 0.f};
#pragma unroll
        for (int kk = 0; kk < 4; ++kk)
            acc = __builtin_amdgcn_mfma_f32_16x16x32_bf16(
                a2[kk], wv[(ct * 4 + kk) * 64 + lane], acc, 0, 0, 0);
        float bias = ldf(b2, ct * 16 + r, fB2);
#pragma unroll
        for (int gg = 0; gg < 4; ++gg) {
            int row = rowBase + quad * 4 + gg;
            if (row < N) {
                int col = ct * 16 + r;
                float v = lrelu(acc[gg] + bias);
                if (RESIDUAL) v += ldf(feat, (size_t)row * DDIM + col, fF);
                out[(size_t)row * DDIM + col] = v;
            }
        }
    }
}

extern "C" void kernel_launch(void* const* d_in, const int* in_sizes, int n_in,
                              void* d_out, int out_size, void* d_ws, size_t ws_size,
                              hipStream_t stream)
{
    const int* src_c2r = (const int*)d_in[2];
    const int* dst_c2r = (const int*)d_in[3];
    const int* src_r2c = (const int*)d_in[5];
    const int* dst_r2c = (const int*)d_in[6];
    const int nE = in_sizes[2];

    // ---- workspace layouts ----
    char* wsb = (char*)d_ws;
    int*    flags  = (int*)wsb;
    __bf16* wfprep = (__bf16*)(wsb + 128);
    // A2 layout: countsA | ovCntA | countsB | ovCntB | slots2 | ovListA | ovListB | cbuf
    int*    countsA = (int*)(wsb + 128 + 131072);
    int*    ovCntA  = countsA + NROW;
    int*    countsB = countsA + NROW + 8;
    int*    ovCntB  = countsA + 2 * NROW + 8;
    size_t  ofsA2   = 128 + 131072 + ((size_t)2 * NROW + 16) * 4;
    ofsA2 = (ofsA2 + 15) & ~(size_t)15;
    int2*   slots2A2  = (int2*)(wsb + ofsA2);
    size_t  ofsOvA2   = ofsA2 + (size_t)NROW * CAP * 8;
    int*    ovListA2  = (int*)(wsb + ofsOvA2);
    int*    ovListB2  = ovListA2 + nE;
    size_t  ofsCbA2   = (ofsOvA2 + (size_t)nE * 8 + 15) & ~(size_t)15;
    __bf16* cbufA2    = (__bf16*)(wsb + ofsCbA2);
    const size_t NEED_A2 = ofsCbA2 + (size_t)NROW * DDIM * 2;

    // round-4 A layout: counts | ovCnt | slots2 | ovList | cbuf
    int*    counts = (int*)(wsb + 128 + 131072);
    int*    ovCnt  = counts + NROW;
    size_t  ofs    = 128 + 131072 + ((size_t)NROW + 8) * 4;
    ofs = (ofs + 15) & ~(size_t)15;
    int2*   slots2 = (int2*)(wsb + ofs);
    size_t  ofsOvA = ofs + (size_t)NROW * CAP * 8;
    int*    ovListA = (int*)(wsb + ofsOvA);
    size_t  ofsCb  = (ofsOvA + (size_t)nE * 4 + 15) & ~(size_t)15;
    __bf16* cbuf   = (__bf16*)(wsb + ofsCb);
    const size_t NEED_A = ofsCb + (size_t)NROW * DDIM * 2;

    const bool tierA2 = ws_size >= NEED_A2;
    const bool tierA  = ws_size >= NEED_A;

    TensorTab T;
    for (int i = 0; i < 18; ++i) { T.p[i] = d_in[i]; T.n[i] = in_sizes[i]; }

    float* out_row = (float*)d_out;
    float* out_col = out_row + (size_t)NROW * DDIM;
    const size_t aggBytes = (size_t)NROW * DDIM * sizeof(float);

    const int eblocks  = (nE + 255) / 256;
    const int sblocks  = (nE * 32 + 255) / 256;
    const int mblocksR = (NROW + 63) / 64;
    const int mblocksC = (NCOL + 63) / 64;
    const int csR      = (NROW + 15) / 16;
    const int csC      = (NCOL + 15) / 16;
    const int gblocksR = (NROW + 3) / 4;
    const int gblocksC = (NCOL + 3) / 4;
    const int cblocks  = (NCOL * DDIM / 8 + 255) / 256;

    WPtrs P;
    P.W[0] = d_in[8];  P.fi[0] = 8;
    P.W[1] = d_in[10]; P.fi[1] = 10;
    P.W[2] = d_in[12]; P.fi[2] = 12;
    P.W[3] = d_in[14]; P.fi[3] = 14;

    if (tierA2) {
        const int zn2 = 2 * NROW + 16;
        const int zb2 = (zn2 + 255) / 256;
        // D1: detect dtypes || zero countsA/ovCntA/countsB/ovCntB
        detect_zero<<<18 + zb2, 256, 0, stream>>>(T, flags, countsA, zn2);
        // D2: cbuf convert || weight prep || fill stage-1
        prep_fill<<<cblocks + 32 + eblocks, 256, 0, stream>>>(
            P, flags, wfprep, d_in[1], cbufA2, NCOL * DDIM / 8, 1, cblocks,
            dst_c2r, src_c2r, d_in[4], nE, countsA, slots2A2, ovCntA,
            ovListA2, 4);
        // D3: segsum stage-1 (inline overflow scan)
        segsum_scan<<<gblocksR, 256, 0, stream>>>(cbufA2, countsA, slots2A2,
            out_col, NROW, src_c2r, dst_c2r, d_in[4], ovListA2, ovCntA,
            flags, 4);
        // D4: col-split mlp stage-1 (out_row = h+feat, cbuf = h bf16) || fill stage-2
        mlp_cs<true, true><<<csR + eblocks, 256, 0, stream>>>(
            d_in[0], out_col, d_in[9], d_in[11], d_in[16],
            out_row, NROW, flags, 0, 9, 11, 16,
            wfprep + 0 * 16384, wfprep + 1 * 16384, cbufA2,
            csR, dst_r2c, src_r2c, d_in[7], nE, countsB, slots2A2,
            ovCntB, ovListB2, 7);
        // D5: segsum stage-2
        segsum_scan<<<gblocksC, 256, 0, stream>>>(cbufA2, countsB, slots2A2,
            out_col, NCOL, src_r2c, dst_r2c, d_in[7], ovListB2, ovCntB,
            flags, 7);
        // D6: col-split mlp stage-2
        mlp_cs<true, false><<<csC, 256, 0, stream>>>(
            d_in[1], out_col, d_in[13], d_in[15], d_in[17],
            out_col, NCOL, flags, 1, 13, 15, 17,
            wfprep + 2 * 16384, wfprep + 3 * 16384, nullptr,
            csC, nullptr, nullptr, nullptr, 0, nullptr, nullptr,
            nullptr, nullptr, 0);
    } else if (tierA) {
        // round-4 proven path
        const int zblocks = ((NROW + 8) + 255) / 256;
        const int zn      = NROW + 8;
        detect_zero<<<18, 256, 0, stream>>>(T, flags, nullptr, 0);
        prep_all<<<cblocks + zblocks + 32, 256, 0, stream>>>(
            P, flags, wfprep, d_in[1], cbuf, NCOL * DDIM / 8, 1,
            counts, zn, cblocks, zblocks);
        fill_slots_packed<<<eblocks, 256, 0, stream>>>(dst_c2r, src_c2r,
            d_in[4], nE, counts, slots2, ovCnt, ovListA, out_col, flags, 4);
        segsum_ov<<<gblocksR + 64, 256, 0, stream>>>(cbuf, counts, slots2,
            out_col, NROW, src_c2r, dst_c2r, d_in[4], ovListA, ovCnt,
            flags, 4, gblocksR);
        mlp_reg<true, true><<<mblocksR, 256, 0, stream>>>(
            d_in[0], out_col, d_in[9], d_in[11], d_in[16],
            out_row, NROW, flags, 0, 9, 11, 16,
            wfprep + 0 * 16384, wfprep + 1 * 16384, cbuf, counts, zn);
        fill_slots_packed<<<eblocks, 256, 0, stream>>>(dst_r2c, src_r2c,
            d_in[7], nE, counts, slots2, ovCnt, ovListA, out_col, flags, 7);
        segsum_ov<<<gblocksC + 64, 256, 0, stream>>>(cbuf, counts, slots2,
            out_col, NCOL, src_r2c, dst_r2c, d_in[7], ovListA, ovCnt,
            flags, 7, gblocksC);
        mlp_reg<true, false><<<mblocksC, 256, 0, stream>>>(
            d_in[1], out_col, d_in[13], d_in[15], d_in[17],
            out_col, NCOL, flags, 1, 13, 15, 17,
            wfprep + 2 * 16384, wfprep + 3 * 16384, nullptr, nullptr, 0);
    } else {
        // legacy path
        detect_zero<<<18, 256, 0, stream>>>(T, flags, nullptr, 0);
        hipMemsetAsync(out_col, 0, aggBytes, stream);
        scatter_any<<<sblocks, 256, 0, stream>>>(d_in[1], src_c2r, dst_c2r,
            d_in[4], out_col, nE, flags, 1, 4);
        mlp_kernel<false><<<mblocksR, 256, 0, stream>>>(
            d_in[0], out_col, d_in[8], d_in[9], d_in[10], d_in[11], d_in[16],
            out_row, NROW, flags, 0, 8, 9, 10, 11, 16);

        hipMemsetAsync(out_col, 0, aggBytes, stream);
        scatter_any<<<sblocks, 256, 0, stream>>>(out_row, src_r2c, dst_r2c,
            d_in[7], out_col, nE, flags, -1, 7);
        residual_add<<<(NROW * DDIM / 4 + 255) / 256, 256, 0, stream>>>(
            out_row, d_in[0], NROW * DDIM / 4, flags, 0);
        mlp_kernel<true><<<mblocksC, 256, 0, stream>>>(
            d_in[1], out_col, d_in[12], d_in[13], d_in[14], d_in[15], d_in[17],
            out_col, NCOL, flags, 1, 12, 13, 14, 15, 17);
    }
}

// Round 8
// 306.625 us; speedup vs baseline: 1.3726x; 1.0095x over previous
//
#include <hip/hip_runtime.h>
#include <hip/hip_bf16.h>

#define NROW 50000
#define NCOL 50000
#define DDIM 128
#define CAP  32   // slots per destination row

typedef __bf16 bf16_t;
typedef __bf16 bf16x2 __attribute__((ext_vector_type(2)));
typedef __bf16 bf16x8 __attribute__((ext_vector_type(8)));
typedef float  f32x4  __attribute__((ext_vector_type(4)));

__device__ __forceinline__ float lrelu(float v) { return v >= 0.f ? v : 0.01f * v; }

__device__ __forceinline__ float ldf(const void* p, size_t i, bool f) {
    return f ? ((const float*)p)[i] : (float)((const bf16_t*)p)[i];
}

// fi: >=0 -> flags[fi]; -1 -> forced f32; -2 -> forced bf16
__device__ __forceinline__ bool dtf(const int* flags, int fi) {
    return (fi == -1) ? true : (fi == -2) ? false : (flags[fi] != 0);
}

// ---------------- D1: dtype detect (18 blocks) + zero counts ---------------
struct TensorTab { const void* p[18]; int n[18]; };

__global__ __launch_bounds__(256) void detect_zero(TensorTab T, int* flags,
                                                   int* z, int zn)
{
    const int tid = threadIdx.x;
    if (blockIdx.x >= 18) {                  // zero countsA|ovCntA|countsB|ovCntB
        int i = (blockIdx.x - 18) * 256 + tid;
        if (i < zn) z[i] = 0;
        return;
    }
    __shared__ int vb, vf;
    const int t = blockIdx.x;
    if (tid == 0) { vb = 0; vf = 0; }
    __syncthreads();
    const int n = T.n[t];
    const bool isFloatArr = (t != 2 && t != 3 && t != 5 && t != 6) && n >= 2;
    if (isFloatArr) {
        int nw = n / 2;
        int wi = (int)(((long long)tid * nw) >> 8);
        unsigned w = ((const unsigned*)T.p[t])[wi];
        unsigned low = w & 0xffffu;
        if (low) {
            int e = (int)((low >> 7) & 0xffu);
            if (e >= 90 && e <= 141) atomicAdd(&vb, 1);
            else                     atomicAdd(&vf, 1);
        }
    }
    __syncthreads();
    if (tid == 0) flags[t] = (isFloatArr && vf > vb) ? 1 : 0; // 1 = f32
}

// ---------------- shared fill routine (no agg touch) -----------------------
__device__ __forceinline__ void fill_edges(
    int e, const int* __restrict__ dst, const int* __restrict__ srcArr,
    const void* __restrict__ wArr, int nE, int* __restrict__ counts,
    int2* __restrict__ slots2, int* __restrict__ ovCnt,
    int* __restrict__ ovList, bool fW)
{
    if (e >= nE) return;
    int d = dst[e];
    int pos = atomicAdd(&counts[d], 1);
    if (pos < CAP) {
        int2 pk;
        pk.x = srcArr[e];
        pk.y = __float_as_int(ldf(wArr, e, fW));
        slots2[(size_t)d * CAP + pos] = pk;
    } else {
        int k = atomicAdd(ovCnt, 1);         // capacity == nE
        ovList[k] = e;
    }
}

struct WPtrs { const void* W[4]; int fi[4]; };

__device__ __forceinline__ void prep_one(WPtrs P, const int* flags,
                                         __bf16* wfp, int slot)
{
    if (slot >= 4 * 2048) return;
    int m = slot >> 11, sIdx = slot & 2047;
    bool f = flags[P.fi[m]] != 0;
    int l = sIdx & 63, combo = sIdx >> 6;
    int ct = combo >> 2, kk = combo & 3;
    int col  = ct * 16 + (l & 15);
    int krow = kk * 32 + (l >> 4) * 8;
    bf16x8 v;
#pragma unroll
    for (int j = 0; j < 8; ++j)
        v[j] = (__bf16)ldf(P.W[m], (size_t)(krow + j) * DDIM + col, f);
    ((bf16x8*)wfp)[slot] = v;
}

__device__ __forceinline__ void convert_one(const void* __restrict__ feat,
                                            __bf16* __restrict__ cbuf,
                                            int i, int n8, bool f)
{
    if (i >= n8) return;
    bf16x8 v;
    if (f) {
        f32x4 a = ((const f32x4*)feat)[i * 2];
        f32x4 c = ((const f32x4*)feat)[i * 2 + 1];
#pragma unroll
        for (int j = 0; j < 4; ++j) { v[j] = (__bf16)a[j]; v[j + 4] = (__bf16)c[j]; }
    } else {
        v = ((const bf16x8*)feat)[i];
    }
    ((bf16x8*)cbuf)[i] = v;
}

// ---------------- D2 (A3): convert || fillA interleaved 4:3, prep at tail ---
__global__ __launch_bounds__(256) void prep_fill_i(
    WPtrs P, const int* __restrict__ flags, __bf16* __restrict__ wfp,
    const void* __restrict__ feat, __bf16* __restrict__ cbuf, int n8,
    int fiFeat, int cb, int eb, int K7,
    const int* __restrict__ f_dst, const int* __restrict__ f_src,
    const void* __restrict__ f_w, int f_nE, int* __restrict__ f_counts,
    int2* __restrict__ f_slots2, int* __restrict__ f_ovCnt,
    int* __restrict__ f_ovList, int f_fiW)
{
    const int g = blockIdx.x;
    const int tid = threadIdx.x;
    if (g >= K7) {                            // weight B-frag prep
        prep_one(P, flags, wfp, (g - K7) * 256 + tid);
        return;
    }
    int grp = g / 7, rem = g % 7;
    if (rem < 4) {                            // convert feat table to bf16
        int b = grp * 4 + rem;
        if (b >= cb) return;
        convert_one(feat, cbuf, b * 256 + tid, n8, dtf(flags, fiFeat));
    } else {                                  // fill stage-1 buckets
        int b = grp * 3 + (rem - 4);
        if (b >= eb) return;
        fill_edges(b * 256 + tid, f_dst, f_src, f_w, f_nE, f_counts,
                   f_slots2, f_ovCnt, f_ovList, dtf(flags, f_fiW));
    }
}

// ---------------- A3: fused segsum + column-split MLP (+interleaved fill) ---
// mlp role: block owns 16 rows. Phase S: each wave computes the weighted
// gather for its 4 rows (64-lane 256B row reads, 4-deep pipeline, identical
// accumulation order to segsum_scan) + eps*feat, writes bf16 A-tile in LDS.
// Then column-split 2-layer MLP (round-7 proven structure).
// fill role (interleaved 4:3 so both are co-resident): bucket-fill for the
// NEXT stage's edges.
template <bool RESIDUAL, bool HOUT>
__global__ __launch_bounds__(256) void mlp_fused(
    const __bf16* __restrict__ gsrc, const int* __restrict__ counts,
    const int2* __restrict__ slots2, const int* __restrict__ srcArr,
    const int* __restrict__ dstArr, const void* __restrict__ wArr,
    const int* __restrict__ ovList, const int* __restrict__ ovCount, int fiW,
    const void* __restrict__ feat, const void* __restrict__ b1,
    const void* __restrict__ b2, const void* __restrict__ epsp,
    float* __restrict__ out, int N, const int* __restrict__ flags,
    int fiFeat, int fiB1, int fiB2, int fiEps,
    const __bf16* __restrict__ pW1, const __bf16* __restrict__ pW2,
    __bf16* __restrict__ hout,
    int mlpBlocks, int fillBlocks,
    const int* __restrict__ f_dst, const int* __restrict__ f_src,
    const void* __restrict__ f_w, int f_nE, int* __restrict__ f_counts,
    int2* __restrict__ f_slots2, int* __restrict__ f_ovCnt,
    int* __restrict__ f_ovList, int f_fiW)
{
    __shared__ alignas(16) __bf16 At[16 * 136];   // A tile (later: hout stage)
    __shared__ alignas(16) __bf16 H1[16 * 136];   // h1 exchange tile

    const int tid = threadIdx.x;
    int bid;
    if (f_dst) {                              // interleaved roles, 4 mlp : 3 fill
        int grp = (int)blockIdx.x / 7, rem = (int)blockIdx.x % 7;
        if (rem >= 4) {
            int b = grp * 3 + (rem - 4);
            if (b < fillBlocks)
                fill_edges(b * 256 + tid, f_dst, f_src, f_w, f_nE, f_counts,
                           f_slots2, f_ovCnt, f_ovList, dtf(flags, f_fiW));
            return;
        }
        bid = grp * 4 + rem;
        if (bid >= mlpBlocks) return;
    } else {
        bid = blockIdx.x;
        if (bid >= mlpBlocks) return;
    }

    const bool fF  = flags[fiFeat] != 0;
    const bool fB1 = flags[fiB1] != 0;
    const bool fB2 = flags[fiB2] != 0;
    const bool fE  = flags[fiEps] != 0;

    const int lane = tid & 63;
    const int wave = tid >> 6;
    const int quad = lane >> 4;
    const int r    = lane & 15;
    const int rowBase = bid * 16;
    const float eps1 = 1.f + ldf(epsp, 0, fE);

    // ---- Phase S: fused segment-sum into A tile (wave -> 4 rows) ----
    {
        const bf16x2* fb = (const bf16x2*)gsrc;
        for (int j = 0; j < 4; ++j) {
            int lrow = wave * 4 + j;
            int row  = rowBase + lrow;
            bf16x2 o;
            if (row < N) {
                int cntRaw = counts[row];
                int cnt = cntRaw > CAP ? CAP : cntRaw;
                int sr = 0; float wv = 0.f;
                if (lane < cnt) {
                    int2 pk = slots2[(size_t)row * CAP + lane];
                    sr = pk.x;
                    wv = __int_as_float(pk.y);
                }
                float2 acc0 = {0.f, 0.f}, acc1 = {0.f, 0.f};
                int i = 0;
                for (; i + 4 <= cnt; i += 4) {
                    int   a0 = __shfl(sr, i),     a1 = __shfl(sr, i + 1);
                    int   a2 = __shfl(sr, i + 2), a3 = __shfl(sr, i + 3);
                    float w0 = __shfl(wv, i),     w1 = __shfl(wv, i + 1);
                    float w2 = __shfl(wv, i + 2), w3 = __shfl(wv, i + 3);
                    bf16x2 v0 = fb[(size_t)a0 * 64 + lane];
                    bf16x2 v1 = fb[(size_t)a1 * 64 + lane];
                    bf16x2 v2 = fb[(size_t)a2 * 64 + lane];
                    bf16x2 v3 = fb[(size_t)a3 * 64 + lane];
                    acc0.x += (float)v0[0] * w0; acc0.y += (float)v0[1] * w0;
                    acc1.x += (float)v1[0] * w1; acc1.y += (float)v1[1] * w1;
                    acc0.x += (float)v2[0] * w2; acc0.y += (float)v2[1] * w2;
                    acc1.x += (float)v3[0] * w3; acc1.y += (float)v3[1] * w3;
                }
                for (; i < cnt; ++i) {
                    int   a0 = __shfl(sr, i);
                    float w0 = __shfl(wv, i);
                    bf16x2 v0 = fb[(size_t)a0 * 64 + lane];
                    acc0.x += (float)v0[0] * w0; acc0.y += (float)v0[1] * w0;
                }
                if (cntRaw > CAP) {           // rare: exact overflow scan
                    const bool fW = dtf(flags, fiW);
                    int nOv = *ovCount;
                    for (int k = 0; k < nOv; ++k) {
                        int e = ovList[k];
                        if (dstArr[e] == row) {
                            int s = srcArr[e];
                            float wf = ldf(wArr, e, fW);
                            bf16x2 v = fb[(size_t)s * 64 + lane];
                            acc0.x += (float)v[0] * wf;
                            acc0.y += (float)v[1] * wf;
                        }
                    }
                }
                float ax = acc0.x + acc1.x, ay = acc0.y + acc1.y;
                float f0, f1;
                if (fF) {
                    float2 fv = ((const float2*)((const float*)feat +
                                 (size_t)row * DDIM))[lane];
                    f0 = fv.x; f1 = fv.y;
                } else {
                    bf16x2 fv = ((const bf16x2*)((const bf16_t*)feat +
                                 (size_t)row * DDIM))[lane];
                    f0 = (float)fv[0]; f1 = (float)fv[1];
                }
                o[0] = (__bf16)(f0 * eps1 + ax);
                o[1] = (__bf16)(f1 * eps1 + ay);
            } else {
                o[0] = (__bf16)0.f; o[1] = (__bf16)0.f;
            }
            *(bf16x2*)&At[lrow * 136 + lane * 2] = o;
        }
    }
    __syncthreads();

    // ---- A-frags from LDS (same 16 rows for all waves) ----
    bf16x8 a[4];
#pragma unroll
    for (int kk = 0; kk < 4; ++kk)
        a[kk] = *(const bf16x8*)&At[r * 136 + kk * 32 + quad * 8];

    const int ct0 = wave * 2, ct1 = ct0 + 1;

    // ---- W1 frags for this wave's two col-tiles (8 loads, parallel) ----
    const bf16x8* pw1v = (const bf16x8*)pW1;
    bf16x8 wfa[4], wfb[4];
#pragma unroll
    for (int kk = 0; kk < 4; ++kk) {
        wfa[kk] = pw1v[(ct0 * 4 + kk) * 64 + lane];
        wfb[kk] = pw1v[(ct1 * 4 + kk) * 64 + lane];
    }
    float b1a = ldf(b1, ct0 * 16 + r, fB1);
    float b1b = ldf(b1, ct1 * 16 + r, fB1);

    // ---- layer 1 -> H1 ----
    {
        f32x4 acc = {0.f, 0.f, 0.f, 0.f};
#pragma unroll
        for (int kk = 0; kk < 4; ++kk)
            acc = __builtin_amdgcn_mfma_f32_16x16x32_bf16(a[kk], wfa[kk], acc, 0, 0, 0);
#pragma unroll
        for (int gg = 0; gg < 4; ++gg)
            H1[(quad * 4 + gg) * 136 + ct0 * 16 + r] = (__bf16)lrelu(acc[gg] + b1a);
    }
    {
        f32x4 acc = {0.f, 0.f, 0.f, 0.f};
#pragma unroll
        for (int kk = 0; kk < 4; ++kk)
            acc = __builtin_amdgcn_mfma_f32_16x16x32_bf16(a[kk], wfb[kk], acc, 0, 0, 0);
#pragma unroll
        for (int gg = 0; gg < 4; ++gg)
            H1[(quad * 4 + gg) * 136 + ct1 * 16 + r] = (__bf16)lrelu(acc[gg] + b1b);
    }
    __syncthreads();

    // ---- a2 from full h1 rows ----
    bf16x8 a2[4];
#pragma unroll
    for (int kk = 0; kk < 4; ++kk)
        a2[kk] = *(const bf16x8*)&H1[r * 136 + kk * 32 + quad * 8];

    // ---- W2 frags (regs reused) ----
    const bf16x8* pw2v = (const bf16x8*)pW2;
#pragma unroll
    for (int kk = 0; kk < 4; ++kk) {
        wfa[kk] = pw2v[(ct0 * 4 + kk) * 64 + lane];
        wfb[kk] = pw2v[(ct1 * 4 + kk) * 64 + lane];
    }
    float b2a = ldf(b2, ct0 * 16 + r, fB2);
    float b2b = ldf(b2, ct1 * 16 + r, fB2);

    // ---- layer 2 -> out (+residual); HOUT: stage bf16 h in At ----
#pragma unroll
    for (int cp = 0; cp < 2; ++cp) {
        const int ct = cp ? ct1 : ct0;
        f32x4 acc = {0.f, 0.f, 0.f, 0.f};
#pragma unroll
        for (int kk = 0; kk < 4; ++kk)
            acc = __builtin_amdgcn_mfma_f32_16x16x32_bf16(
                a2[kk], cp ? wfb[kk] : wfa[kk], acc, 0, 0, 0);
        float bias = cp ? b2b : b2a;
#pragma unroll
        for (int gg = 0; gg < 4; ++gg) {
            int row = rowBase + quad * 4 + gg;
            float v = lrelu(acc[gg] + bias);
            if (HOUT)
                At[(quad * 4 + gg) * 136 + ct * 16 + r] = (__bf16)v;
            if (row < N) {
                int col = ct * 16 + r;
                if (RESIDUAL) v += ldf(feat, (size_t)row * DDIM + col, fF);
                out[(size_t)row * DDIM + col] = v;
            }
        }
    }

    // ---- cooperative coalesced hout store ----
    if (HOUT) {
        __syncthreads();
        int row = tid >> 4;
        int k0  = (tid & 15) * 8;
        int g   = rowBase + row;
        if (g < N)
            *(bf16x8*)&hout[(size_t)g * DDIM + k0] =
                *(const bf16x8*)&At[row * 136 + k0];
    }
}

// =================== round-7 tier-A2 fallback kernels (proven) ==============
__global__ __launch_bounds__(256) void prep_fill(
    WPtrs P, const int* __restrict__ flags, __bf16* __restrict__ wfp,
    const void* __restrict__ feat, __bf16* __restrict__ cbuf, int n8,
    int fiFeat, int cblocks,
    const int* __restrict__ f_dst, const int* __restrict__ f_src,
    const void* __restrict__ f_w, int f_nE, int* __restrict__ f_counts,
    int2* __restrict__ f_slots2, int* __restrict__ f_ovCnt,
    int* __restrict__ f_ovList, int f_fiW)
{
    const int b = blockIdx.x;
    const int tid = threadIdx.x;
    if (b < cblocks) {
        convert_one(feat, cbuf, b * 256 + tid, n8, dtf(flags, fiFeat));
    } else if (b < cblocks + 32) {
        prep_one(P, flags, wfp, (b - cblocks) * 256 + tid);
    } else {
        int e = (b - cblocks - 32) * 256 + tid;
        fill_edges(e, f_dst, f_src, f_w, f_nE, f_counts, f_slots2,
                   f_ovCnt, f_ovList, dtf(flags, f_fiW));
    }
}

__global__ __launch_bounds__(256) void segsum_scan(
    const __bf16* __restrict__ gsrc, const int* __restrict__ counts,
    const int2* __restrict__ slots2, float* __restrict__ agg, int nRows,
    const int* __restrict__ srcArr, const int* __restrict__ dstArr,
    const void* __restrict__ wArr, const int* __restrict__ ovList,
    const int* __restrict__ ovCount, const int* __restrict__ flags, int fiW)
{
    int row = blockIdx.x * 4 + (threadIdx.x >> 6);
    if (row >= nRows) return;
    int lane = threadIdx.x & 63;

    int cntRaw = counts[row];
    int cnt = cntRaw > CAP ? CAP : cntRaw;

    int sr = 0; float wv = 0.f;
    if (lane < cnt) {
        int2 pk = slots2[(size_t)row * CAP + lane];
        sr = pk.x;
        wv = __int_as_float(pk.y);
    }

    float2* ap = (float2*)(agg + (size_t)row * DDIM) + lane;
    float2 acc0 = {0.f, 0.f}, acc1 = {0.f, 0.f};

    const bf16x2* fb = (const bf16x2*)gsrc;
    int i = 0;
    for (; i + 4 <= cnt; i += 4) {
        int   a0 = __shfl(sr, i),     a1 = __shfl(sr, i + 1);
        int   a2 = __shfl(sr, i + 2), a3 = __shfl(sr, i + 3);
        float w0 = __shfl(wv, i),     w1 = __shfl(wv, i + 1);
        float w2 = __shfl(wv, i + 2), w3 = __shfl(wv, i + 3);
        bf16x2 v0 = fb[(size_t)a0 * 64 + lane];
        bf16x2 v1 = fb[(size_t)a1 * 64 + lane];
        bf16x2 v2 = fb[(size_t)a2 * 64 + lane];
        bf16x2 v3 = fb[(size_t)a3 * 64 + lane];
        acc0.x += (float)v0[0] * w0; acc0.y += (float)v0[1] * w0;
        acc1.x += (float)v1[0] * w1; acc1.y += (float)v1[1] * w1;
        acc0.x += (float)v2[0] * w2; acc0.y += (float)v2[1] * w2;
        acc1.x += (float)v3[0] * w3; acc1.y += (float)v3[1] * w3;
    }
    for (; i < cnt; ++i) {
        int   a0 = __shfl(sr, i);
        float w0 = __shfl(wv, i);
        bf16x2 v0 = fb[(size_t)a0 * 64 + lane];
        acc0.x += (float)v0[0] * w0; acc0.y += (float)v0[1] * w0;
    }
    if (cntRaw > CAP) {
        const bool fW = dtf(flags, fiW);
        int nOv = *ovCount;
        for (int k = 0; k < nOv; ++k) {
            int e = ovList[k];
            if (dstArr[e] == row) {
                int s = srcArr[e];
                float wf = ldf(wArr, e, fW);
                bf16x2 v = fb[(size_t)s * 64 + lane];
                acc0.x += (float)v[0] * wf; acc0.y += (float)v[1] * wf;
            }
        }
    }
    acc0.x += acc1.x; acc0.y += acc1.y;
    *ap = acc0;
}

template <bool RESIDUAL, bool HOUT>
__global__ __launch_bounds__(256) void mlp_cs(
    const void* __restrict__ feat, const float* __restrict__ agg,
    const void* __restrict__ b1, const void* __restrict__ b2,
    const void* __restrict__ epsp, float* __restrict__ out, int N,
    const int* __restrict__ flags, int fiFeat, int fiB1, int fiB2, int fiEps,
    const __bf16* __restrict__ pW1, const __bf16* __restrict__ pW2,
    __bf16* __restrict__ hout,
    int mblocks,
    const int* __restrict__ f_dst, const int* __restrict__ f_src,
    const void* __restrict__ f_w, int f_nE, int* __restrict__ f_counts,
    int2* __restrict__ f_slots2, int* __restrict__ f_ovCnt,
    int* __restrict__ f_ovList, int f_fiW)
{
    __shared__ alignas(16) __bf16 At[16 * 136];
    __shared__ alignas(16) __bf16 H1[16 * 136];

    const int tid = threadIdx.x;
    if (f_dst && (int)blockIdx.x >= mblocks) {
        int e = ((int)blockIdx.x - mblocks) * 256 + tid;
        fill_edges(e, f_dst, f_src, f_w, f_nE, f_counts, f_slots2,
                   f_ovCnt, f_ovList, dtf(flags, f_fiW));
        return;
    }

    const bool fF  = flags[fiFeat] != 0;
    const bool fB1 = flags[fiB1] != 0;
    const bool fB2 = flags[fiB2] != 0;
    const bool fE  = flags[fiEps] != 0;

    const int lane = tid & 63;
    const int wave = tid >> 6;
    const int quad = lane >> 4;
    const int r    = lane & 15;
    const int rowBase = blockIdx.x * 16;
    const float eps1 = 1.f + ldf(epsp, 0, fE);

    {
        int row = tid >> 4;
        int k0  = (tid & 15) * 8;
        int g   = rowBase + row;
        bf16x8 av;
        if (g < N) {
            size_t base = (size_t)g * DDIM + k0;
            const f32x4* gp = (const f32x4*)(agg + base);
            f32x4 g0 = gp[0], g1 = gp[1];
            if (fF) {
                const f32x4* fp = (const f32x4*)((const float*)feat + base);
                f32x4 f0 = fp[0], f1 = fp[1];
#pragma unroll
                for (int j = 0; j < 4; ++j) {
                    av[j]     = (__bf16)(f0[j] * eps1 + g0[j]);
                    av[j + 4] = (__bf16)(f1[j] * eps1 + g1[j]);
                }
            } else {
                bf16x8 fv = *(const bf16x8*)((const bf16_t*)feat + base);
#pragma unroll
                for (int j = 0; j < 4; ++j) {
                    av[j]     = (__bf16)((float)fv[j]     * eps1 + g0[j]);
                    av[j + 4] = (__bf16)((float)fv[j + 4] * eps1 + g1[j]);
                }
            }
        } else {
#pragma unroll
            for (int j = 0; j < 8; ++j) av[j] = (__bf16)0.f;
        }
        *(bf16x8*)&At[row * 136 + k0] = av;
    }
    __syncthreads();

    bf16x8 a[4];
#pragma unroll
    for (int kk = 0; kk < 4; ++kk)
        a[kk] = *(const bf16x8*)&At[r * 136 + kk * 32 + quad * 8];

    const int ct0 = wave * 2, ct1 = ct0 + 1;

    const bf16x8* pw1v = (const bf16x8*)pW1;
    bf16x8 wfa[4], wfb[4];
#pragma unroll
    for (int kk = 0; kk < 4; ++kk) {
        wfa[kk] = pw1v[(ct0 * 4 + kk) * 64 + lane];
        wfb[kk] = pw1v[(ct1 * 4 + kk) * 64 + lane];
    }
    float b1a = ldf(b1, ct0 * 16 + r, fB1);
    float b1b = ldf(b1, ct1 * 16 + r, fB1);

    {
        f32x4 acc = {0.f, 0.f, 0.f, 0.f};
#pragma unroll
        for (int kk = 0; kk < 4; ++kk)
            acc = __builtin_amdgcn_mfma_f32_16x16x32_bf16(a[kk], wfa[kk], acc, 0, 0, 0);
#pragma unroll
        for (int gg = 0; gg < 4; ++gg)
            H1[(quad * 4 + gg) * 136 + ct0 * 16 + r] = (__bf16)lrelu(acc[gg] + b1a);
    }
    {
        f32x4 acc = {0.f, 0.f, 0.f, 0.f};
#pragma unroll
        for (int kk = 0; kk < 4; ++kk)
            acc = __builtin_amdgcn_mfma_f32_16x16x32_bf16(a[kk], wfb[kk], acc, 0, 0, 0);
#pragma unroll
        for (int gg = 0; gg < 4; ++gg)
            H1[(quad * 4 + gg) * 136 + ct1 * 16 + r] = (__bf16)lrelu(acc[gg] + b1b);
    }
    __syncthreads();

    bf16x8 a2[4];
#pragma unroll
    for (int kk = 0; kk < 4; ++kk)
        a2[kk] = *(const bf16x8*)&H1[r * 136 + kk * 32 + quad * 8];

    const bf16x8* pw2v = (const bf16x8*)pW2;
#pragma unroll
    for (int kk = 0; kk < 4; ++kk) {
        wfa[kk] = pw2v[(ct0 * 4 + kk) * 64 + lane];
        wfb[kk] = pw2v[(ct1 * 4 + kk) * 64 + lane];
    }
    float b2a = ldf(b2, ct0 * 16 + r, fB2);
    float b2b = ldf(b2, ct1 * 16 + r, fB2);

#pragma unroll
    for (int cp = 0; cp < 2; ++cp) {
        const int ct = cp ? ct1 : ct0;
        f32x4 acc = {0.f, 0.f, 0.f, 0.f};
#pragma unroll
        for (int kk = 0; kk < 4; ++kk)
            acc = __builtin_amdgcn_mfma_f32_16x16x32_bf16(
                a2[kk], cp ? wfb[kk] : wfa[kk], acc, 0, 0, 0);
        float bias = cp ? b2b : b2a;
#pragma unroll
        for (int gg = 0; gg < 4; ++gg) {
            int row = rowBase + quad * 4 + gg;
            float v = lrelu(acc[gg] + bias);
            if (HOUT)
                At[(quad * 4 + gg) * 136 + ct * 16 + r] = (__bf16)v;
            if (row < N) {
                int col = ct * 16 + r;
                if (RESIDUAL) v += ldf(feat, (size_t)row * DDIM + col, fF);
                out[(size_t)row * DDIM + col] = v;
            }
        }
    }

    if (HOUT) {
        __syncthreads();
        int row = tid >> 4;
        int k0  = (tid & 15) * 8;
        int g   = rowBase + row;
        if (g < N)
            *(bf16x8*)&hout[(size_t)g * DDIM + k0] =
                *(const bf16x8*)&At[row * 136 + k0];
    }
}

// ======================= legacy kernels (ws-too-small) ======================
__global__ __launch_bounds__(256) void scatter_any(
    const void* __restrict__ feat, const int* __restrict__ src,
    const int* __restrict__ dst, const void* __restrict__ w,
    float* __restrict__ agg, int nE,
    const int* __restrict__ flags, int fiFeat, int fiW)
{
    const bool fF = dtf(flags, fiFeat);
    const bool fW = dtf(flags, fiW);
    int g = blockIdx.x * 256 + threadIdx.x;
    int e = g >> 5;
    if (e >= nE) return;
    int c = (g & 31) << 2;
    int s = src[e], d = dst[e];
    float wf = ldf(w, e, fW);
    size_t base = (size_t)s * DDIM + c;
    float* ap = agg + (size_t)d * DDIM + c;
    unsafeAtomicAdd(ap + 0, ldf(feat, base + 0, fF) * wf);
    unsafeAtomicAdd(ap + 1, ldf(feat, base + 1, fF) * wf);
    unsafeAtomicAdd(ap + 2, ldf(feat, base + 2, fF) * wf);
    unsafeAtomicAdd(ap + 3, ldf(feat, base + 3, fF) * wf);
}

__global__ __launch_bounds__(256) void residual_add(
    float* __restrict__ out, const void* __restrict__ feat, int n4,
    const int* __restrict__ flags, int fiFeat)
{
    const bool fF = flags[fiFeat] != 0;
    int i = blockIdx.x * 256 + threadIdx.x;
    if (i >= n4) return;
    f32x4 o = ((const f32x4*)out)[i];
    f32x4 r;
#pragma unroll
    for (int j = 0; j < 4; ++j) r[j] = o[j] + ldf(feat, (size_t)i * 4 + j, fF);
    ((f32x4*)out)[i] = r;
}

__device__ __forceinline__ void fill_wfrag(const void* __restrict__ W, bool f,
                                           __bf16* wf, int tid)
{
#pragma unroll
    for (int i = 0; i < 8; ++i) {
        int sIdx  = tid + i * 256;
        int l     = sIdx & 63;
        int combo = sIdx >> 6;
        int ct = combo >> 2, kk = combo & 3;
        int col  = ct * 16 + (l & 15);
        int krow = kk * 32 + (l >> 4) * 8;
        __bf16* dp = wf + (size_t)sIdx * 8;
#pragma unroll
        for (int j = 0; j < 8; ++j)
            dp[j] = (__bf16)ldf(W, (size_t)(krow + j) * DDIM + col, f);
    }
}

template <bool RESIDUAL>
__global__ __launch_bounds__(256) void mlp_kernel(
    const void* __restrict__ feat, const float* __restrict__ agg,
    const void* __restrict__ W1, const void* __restrict__ b1,
    const void* __restrict__ W2, const void* __restrict__ b2,
    const void* __restrict__ epsp, float* __restrict__ out, int N,
    const int* __restrict__ flags,
    int fiFeat, int fiW1, int fiB1, int fiW2, int fiB2, int fiEps)
{
    __shared__ alignas(16) __bf16 wf[32 * 64 * 8];
    __shared__ alignas(16) __bf16 h1t[64 * 136];

    const bool fF  = flags[fiFeat] != 0;
    const bool fB1 = flags[fiB1] != 0;
    const bool fB2 = flags[fiB2] != 0;
    const bool fE  = flags[fiEps] != 0;

    const int tid  = threadIdx.x;
    const int lane = tid & 63;
    const int wave = tid >> 6;
    const int quad = lane >> 4;
    const int r    = lane & 15;

    fill_wfrag(W1, flags[fiW1] != 0, wf, tid);

    const float eps1 = 1.f + ldf(epsp, 0, fE);
    const int rowBase = blockIdx.x * 64 + wave * 16;

    bf16x8 a[4];
    {
        int rowA = rowBase + r;
        if (rowA < N) {
            size_t fb = (size_t)rowA * DDIM + quad * 8;
            const f32x4* gp = (const f32x4*)(agg + fb);
            if (fF) {
                const f32x4* fp = (const f32x4*)((const float*)feat + fb);
#pragma unroll
                for (int kk = 0; kk < 4; ++kk) {
                    f32x4 f0 = fp[kk * 8], f1 = fp[kk * 8 + 1];
                    f32x4 g0 = gp[kk * 8], g1 = gp[kk * 8 + 1];
                    bf16x8 av;
#pragma unroll
                    for (int j = 0; j < 4; ++j) {
                        av[j]     = (__bf16)(f0[j] * eps1 + g0[j]);
                        av[j + 4] = (__bf16)(f1[j] * eps1 + g1[j]);
                    }
                    a[kk] = av;
                }
            } else {
                const bf16x8* fp = (const bf16x8*)((const bf16_t*)feat + fb);
#pragma unroll
                for (int kk = 0; kk < 4; ++kk) {
                    bf16x8 fv = fp[kk * 4];
                    f32x4 g0 = gp[kk * 8], g1 = gp[kk * 8 + 1];
                    bf16x8 av;
#pragma unroll
                    for (int j = 0; j < 4; ++j) {
                        av[j]     = (__bf16)((float)fv[j]     * eps1 + g0[j]);
                        av[j + 4] = (__bf16)((float)fv[j + 4] * eps1 + g1[j]);
                    }
                    a[kk] = av;
                }
            }
        } else {
#pragma unroll
            for (int kk = 0; kk < 4; ++kk)
#pragma unroll
                for (int j = 0; j < 8; ++j) a[kk][j] = (__bf16)0.f;
        }
    }

    __syncthreads();

    const bf16x8* wv = (const bf16x8*)wf;
#pragma unroll
    for (int ct = 0; ct < 8; ++ct) {
        f32x4 acc = {0.f, 0.f, 0.f, 0.f};
#pragma unroll
        for (int kk = 0; kk < 4; ++kk)
            acc = __builtin_amdgcn_mfma_f32_16x16x32_bf16(
                a[kk], wv[(ct * 4 + kk) * 64 + lane], acc, 0, 0, 0);
        float bias = ldf(b1, ct * 16 + r, fB1);
#pragma unroll
        for (int gg = 0; gg < 4; ++gg)
            h1t[(wave * 16 + quad * 4 + gg) * 136 + ct * 16 + r] =
                (__bf16)lrelu(acc[gg] + bias);
    }
    __syncthreads();

    bf16x8 a2[4];
#pragma unroll
    for (int kk = 0; kk < 4; ++kk)
        a2[kk] = *(const bf16x8*)&h1t[(wave * 16 + r) * 136 + kk * 32 + quad * 8];

    fill_wfrag(W2, flags[fiW2] != 0, wf, tid);
    __syncthreads();

#pragma unroll
    for (int ct = 0; ct < 8; ++ct) {
        f32x4 acc = {0.f, 0.f, 0.f, 0.f};
#pragma unroll
        for (int kk = 0; kk < 4; ++kk)
            acc = __builtin_amdgcn_mfma_f32_16x16x32_bf16(
                a2[kk], wv[(ct * 4 + kk) * 64 + lane], acc, 0, 0, 0);
        float bias = ldf(b2, ct * 16 + r, fB2);
#pragma unroll
        for (int gg = 0; gg < 4; ++gg) {
            int row = rowBase + quad * 4 + gg;
            if (row < N) {
                int col = ct * 16 + r;
                float v = lrelu(acc[gg] + bias);
                if (RESIDUAL) v += ldf(feat, (size_t)row * DDIM + col, fF);
                out[(size_t)row * DDIM + col] = v;
            }
        }
    }
}

extern "C" void kernel_launch(void* const* d_in, const int* in_sizes, int n_in,
                              void* d_out, int out_size, void* d_ws, size_t ws_size,
                              hipStream_t stream)
{
    const int* src_c2r = (const int*)d_in[2];
    const int* dst_c2r = (const int*)d_in[3];
    const int* src_r2c = (const int*)d_in[5];
    const int* dst_r2c = (const int*)d_in[6];
    const int nE = in_sizes[2];

    char* wsb = (char*)d_ws;
    int*    flags  = (int*)wsb;
    __bf16* wfprep = (__bf16*)(wsb + 128);

    // ---- A3 layout: countsA|ovCntA|countsB|ovCntB|slots2A|slots2B|
    //                 ovListA|ovListB|cbufX|cbufH ----
    int*    cntA   = (int*)(wsb + 128 + 131072);
    int*    ovCntA = cntA + NROW;
    int*    cntB   = cntA + NROW + 8;
    int*    ovCntB = cntA + 2 * NROW + 8;
    size_t  o3 = 128 + 131072 + ((size_t)2 * NROW + 16) * 4;
    o3 = (o3 + 15) & ~(size_t)15;
    int2*   sl2A = (int2*)(wsb + o3);  o3 += (size_t)NROW * CAP * 8;
    int2*   sl2B = (int2*)(wsb + o3);  o3 += (size_t)NROW * CAP * 8;
    int*    ovLA = (int*)(wsb + o3);   o3 += (size_t)nE * 4;
    int*    ovLB = (int*)(wsb + o3);   o3 += (size_t)nE * 4;
    o3 = (o3 + 15) & ~(size_t)15;
    __bf16* cbX  = (__bf16*)(wsb + o3); o3 += (size_t)NCOL * DDIM * 2;
    __bf16* cbH  = (__bf16*)(wsb + o3); o3 += (size_t)NROW * DDIM * 2;
    const size_t NEED_A3 = o3;

    // ---- A2 (round-7) layout: countsA|ovCntA|countsB|ovCntB|slots2|ovLA|ovLB|cbuf
    size_t  ofsA2   = 128 + 131072 + ((size_t)2 * NROW + 16) * 4;
    ofsA2 = (ofsA2 + 15) & ~(size_t)15;
    int2*   slots2A2  = (int2*)(wsb + ofsA2);
    size_t  ofsOvA2   = ofsA2 + (size_t)NROW * CAP * 8;
    int*    ovListA2  = (int*)(wsb + ofsOvA2);
    int*    ovListB2  = ovListA2 + nE;
    size_t  ofsCbA2   = (ofsOvA2 + (size_t)nE * 8 + 15) & ~(size_t)15;
    __bf16* cbufA2    = (__bf16*)(wsb + ofsCbA2);
    const size_t NEED_A2 = ofsCbA2 + (size_t)NROW * DDIM * 2;

    const bool tierA3 = ws_size >= NEED_A3;
    const bool tierA2 = ws_size >= NEED_A2;

    TensorTab T;
    for (int i = 0; i < 18; ++i) { T.p[i] = d_in[i]; T.n[i] = in_sizes[i]; }

    float* out_row = (float*)d_out;
    float* out_col = out_row + (size_t)NROW * DDIM;
    const size_t aggBytes = (size_t)NROW * DDIM * sizeof(float);

    const int eblocks  = (nE + 255) / 256;
    const int sblocks  = (nE * 32 + 255) / 256;
    const int mblocksR = (NROW + 63) / 64;
    const int mblocksC = (NCOL + 63) / 64;
    const int csR      = (NROW + 15) / 16;
    const int csC      = (NCOL + 15) / 16;
    const int gblocksR = (NROW + 3) / 4;
    const int gblocksC = (NCOL + 3) / 4;
    const int cblocks  = (NCOL * DDIM / 8 + 255) / 256;
    const int zn2      = 2 * NROW + 16;
    const int zb2      = (zn2 + 255) / 256;

    WPtrs P;
    P.W[0] = d_in[8];  P.fi[0] = 8;
    P.W[1] = d_in[10]; P.fi[1] = 10;
    P.W[2] = d_in[12]; P.fi[2] = 12;
    P.W[3] = d_in[14]; P.fi[3] = 14;

    if (tierA3) {
        // D1: detect dtypes || zero countsA/ovCntA/countsB/ovCntB
        detect_zero<<<18 + zb2, 256, 0, stream>>>(T, flags, cntA, zn2);
        // D2: convert cbufX || fillA, interleaved 4:3; weight prep at tail
        {
            int ka = (cblocks + 3) / 4, kb = (eblocks + 2) / 3;
            int K = ka > kb ? ka : kb;
            prep_fill_i<<<7 * K + 32, 256, 0, stream>>>(
                P, flags, wfprep, d_in[1], cbX, NCOL * DDIM / 8, 1,
                cblocks, eblocks, 7 * K,
                dst_c2r, src_c2r, d_in[4], nE, cntA, sl2A, ovCntA, ovLA, 4);
        }
        // D3: fused segsumA + mlp1 (out_row = h+feat, cbufH = h bf16)
        //     || fillB, interleaved 4:3
        {
            int ka = (csR + 3) / 4, kb = (eblocks + 2) / 3;
            int K = ka > kb ? ka : kb;
            mlp_fused<true, true><<<7 * K, 256, 0, stream>>>(
                cbX, cntA, sl2A, src_c2r, dst_c2r, d_in[4], ovLA, ovCntA, 4,
                d_in[0], d_in[9], d_in[11], d_in[16],
                out_row, NROW, flags, 0, 9, 11, 16,
                wfprep + 0 * 16384, wfprep + 1 * 16384, cbH,
                csR, eblocks, dst_r2c, src_r2c, d_in[7], nE, cntB, sl2B,
                ovCntB, ovLB, 7);
        }
        // D4: fused segsumB + mlp2 -> out_col
        mlp_fused<true, false><<<csC, 256, 0, stream>>>(
            cbH, cntB, sl2B, src_r2c, dst_r2c, d_in[7], ovLB, ovCntB, 7,
            d_in[1], d_in[13], d_in[15], d_in[17],
            out_col, NCOL, flags, 1, 13, 15, 17,
            wfprep + 2 * 16384, wfprep + 3 * 16384, nullptr,
            csC, 0, nullptr, nullptr, nullptr, 0, nullptr, nullptr,
            nullptr, nullptr, 0);
    } else if (tierA2) {
        // round-7 proven path
        detect_zero<<<18 + zb2, 256, 0, stream>>>(T, flags, cntA, zn2);
        prep_fill<<<cblocks + 32 + eblocks, 256, 0, stream>>>(
            P, flags, wfprep, d_in[1], cbufA2, NCOL * DDIM / 8, 1, cblocks,
            dst_c2r, src_c2r, d_in[4], nE, cntA, slots2A2, ovCntA,
            ovListA2, 4);
        segsum_scan<<<gblocksR, 256, 0, stream>>>(cbufA2, cntA, slots2A2,
            out_col, NROW, src_c2r, dst_c2r, d_in[4], ovListA2, ovCntA,
            flags, 4);
        mlp_cs<true, true><<<csR + eblocks, 256, 0, stream>>>(
            d_in[0], out_col, d_in[9], d_in[11], d_in[16],
            out_row, NROW, flags, 0, 9, 11, 16,
            wfprep + 0 * 16384, wfprep + 1 * 16384, cbufA2,
            csR, dst_r2c, src_r2c, d_in[7], nE, cntB, slots2A2,
            ovCntB, ovListB2, 7);
        segsum_scan<<<gblocksC, 256, 0, stream>>>(cbufA2, cntB, slots2A2,
            out_col, NCOL, src_r2c, dst_r2c, d_in[7], ovListB2, ovCntB,
            flags, 7);
        mlp_cs<true, false><<<csC, 256, 0, stream>>>(
            d_in[1], out_col, d_in[13], d_in[15], d_in[17],
            out_col, NCOL, flags, 1, 13, 15, 17,
            wfprep + 2 * 16384, wfprep + 3 * 16384, nullptr,
            csC, nullptr, nullptr, nullptr, 0, nullptr, nullptr,
            nullptr, nullptr, 0);
    } else {
        // legacy path
        detect_zero<<<18, 256, 0, stream>>>(T, flags, nullptr, 0);
        hipMemsetAsync(out_col, 0, aggBytes, stream);
        scatter_any<<<sblocks, 256, 0, stream>>>(d_in[1], src_c2r, dst_c2r,
            d_in[4], out_col, nE, flags, 1, 4);
        mlp_kernel<false><<<mblocksR, 256, 0, stream>>>(
            d_in[0], out_col, d_in[8], d_in[9], d_in[10], d_in[11], d_in[16],
            out_row, NROW, flags, 0, 8, 9, 10, 11, 16);

        hipMemsetAsync(out_col, 0, aggBytes, stream);
        scatter_any<<<sblocks, 256, 0, stream>>>(out_row, src_r2c, dst_r2c,
            d_in[7], out_col, nE, flags, -1, 7);
        residual_add<<<(NROW * DDIM / 4 + 255) / 256, 256, 0, stream>>>(
            out_row, d_in[0], NROW * DDIM / 4, flags, 0);
        mlp_kernel<true><<<mblocksC, 256, 0, stream>>>(
            d_in[1], out_col, d_in[12], d_in[13], d_in[14], d_in[15], d_in[17],
            out_col, NCOL, flags, 1, 12, 13, 14, 15, 17);
    }
}